// Round 22
// baseline (4874.199 us; speedup 1.0000x reference)
//
#include <hip/hip_runtime.h>
#include <hip/hip_bf16.h>

#define B_ 8
#define T_ 16
#define S_ 257
#define D_ 512
#define FFN_ 2048
#define NH_ 8
#define HD_ 64
#define PTD_ 192
#define NTOK (B_*T_*S_)        // 32896
#define CH 4112                // 16 frames * 257 rows per chunk
#define PCH 8224               // chunk pair rows
#define WSCALE 64.0f
#define WINV 0.015625f

typedef unsigned int uint;
typedef unsigned short ushort;
typedef __attribute__((ext_vector_type(8))) _Float16 half8;
typedef __attribute__((ext_vector_type(4))) float f32x4;

__device__ __forceinline__ float warp_rsum(float v){
#pragma unroll
  for (int m = 32; m >= 1; m >>= 1) v += __shfl_xor(v, m);
  return v;
}
__device__ __forceinline__ float gelu_f(float x){
  float x3 = x*x*x;
  return 0.5f*x*(1.0f + tanhf(0.7978845608028654f*(x + 0.044715f*x3)));
}
// split fp32 -> f16 hi + f16 lo (RNE).
__device__ __forceinline__ void split_f16(float f, ushort& h, ushort& l){
  _Float16 hh = (_Float16)f;
  float hf = (float)hh;
  _Float16 ll = (_Float16)(f - hf);
  h = __builtin_bit_cast(ushort, hh);
  l = __builtin_bit_cast(ushort, ll);
}
__device__ __forceinline__ ushort to_f16u(float f){
  return __builtin_bit_cast(ushort, (_Float16)f);
}
__device__ __forceinline__ float from_f16u(ushort u){
  return (float)__builtin_bit_cast(_Float16, u);
}
// async global->LDS 16B (lane-linear LDS dest, per-lane global src)
__device__ __forceinline__ void gload16(const ushort* g, ushort* l){
  __builtin_amdgcn_global_load_lds(
      (const __attribute__((address_space(1))) void*)(g),
      (__attribute__((address_space(3))) void*)(l),
      16, 0, 0);
}

// ---------------- fused LN + single-f16 cast:  aH[row][512] = f16(LN(x[row]))
__global__ __launch_bounds__(256) void ln_single(
    const float* __restrict__ x, const float* __restrict__ g,
    const float* __restrict__ bb, ushort* __restrict__ aH)
{
  int row = blockIdx.x * 4 + (threadIdx.x >> 6);
  int lane = threadIdx.x & 63;
  const float* xr = x + (long)row * D_;
  float4 u0 = *(const float4*)(xr + lane * 8);
  float4 u1 = *(const float4*)(xr + lane * 8 + 4);
  float s = u0.x + u0.y + u0.z + u0.w + u1.x + u1.y + u1.z + u1.w;
  s = warp_rsum(s);
  float mean = s * (1.0f / 512.0f);
  float d[8] = {u0.x - mean, u0.y - mean, u0.z - mean, u0.w - mean,
                u1.x - mean, u1.y - mean, u1.z - mean, u1.w - mean};
  float ss = 0.f;
#pragma unroll
  for (int i = 0; i < 8; i++) ss = fmaf(d[i], d[i], ss);
  ss = warp_rsum(ss);
  float rstd = rsqrtf(ss * (1.0f / 512.0f) + 1e-5f);
  int c = lane * 8;
  float4 g0 = *(const float4*)(g + c), g1 = *(const float4*)(g + c + 4);
  float4 b0 = *(const float4*)(bb + c), b1 = *(const float4*)(bb + c + 4);
  float y[8] = {d[0]*rstd*g0.x + b0.x, d[1]*rstd*g0.y + b0.y,
                d[2]*rstd*g0.z + b0.z, d[3]*rstd*g0.w + b0.w,
                d[4]*rstd*g1.x + b1.x, d[5]*rstd*g1.y + b1.y,
                d[6]*rstd*g1.z + b1.z, d[7]*rstd*g1.w + b1.w};
  ushort h[8];
#pragma unroll
  for (int i = 0; i < 8; i++) h[i] = to_f16u(y[i]);
  uint4 hv = make_uint4((uint)h[0] | ((uint)h[1] << 16), (uint)h[2] | ((uint)h[3] << 16),
                        (uint)h[4] | ((uint)h[5] << 16), (uint)h[6] | ((uint)h[7] << 16));
  *(uint4*)(aH + (long)row * 512 + c) = hv;
}

// ---------------- weight transpose + split:  W[K][N] f32 -> (W*64) as Whi[N][K], Wlo[N][K] f16
__global__ __launch_bounds__(256) void convert_w(
    const float* __restrict__ W, ushort* __restrict__ Whi, ushort* __restrict__ Wlo,
    int N, int K)
{
  __shared__ float Tt[64][65];
  const int tid = threadIdx.x;
  const int k0 = blockIdx.x << 6, n0 = blockIdx.y << 6;
  {
    int kk = tid >> 2, nb = (tid & 3) << 4;
#pragma unroll
    for (int q = 0; q < 4; q++) {
      float4 v = *(const float4*)(W + (long)(k0 + kk) * N + n0 + nb + 4 * q);
      Tt[kk][nb + 4*q + 0] = v.x; Tt[kk][nb + 4*q + 1] = v.y;
      Tt[kk][nb + 4*q + 2] = v.z; Tt[kk][nb + 4*q + 3] = v.w;
    }
  }
  __syncthreads();
  {
    int nn = tid >> 2, kb = (tid & 3) << 4;
    uint hw[8], lw[8];
#pragma unroll
    for (int q = 0; q < 8; q++) {
      float a = Tt[kb + 2*q][nn] * WSCALE, b = Tt[kb + 2*q + 1][nn] * WSCALE;
      ushort ha, la, hb, lb;
      split_f16(a, ha, la); split_f16(b, hb, lb);
      hw[q] = (uint)ha | ((uint)hb << 16); lw[q] = (uint)la | ((uint)lb << 16);
    }
    ushort* dh = Whi + (long)(n0 + nn) * K + k0 + kb;
    ushort* dl = Wlo + (long)(n0 + nn) * K + k0 + kb;
    ((uint4*)dh)[0] = make_uint4(hw[0], hw[1], hw[2], hw[3]);
    ((uint4*)dh)[1] = make_uint4(hw[4], hw[5], hw[6], hw[7]);
    ((uint4*)dl)[0] = make_uint4(lw[0], lw[1], lw[2], lw[3]);
    ((uint4*)dl)[1] = make_uint4(lw[4], lw[5], lw[6], lw[7]);
  }
}

// ---------------- split-f16 MFMA GEMM.
// AMODE 0: BM=128, BK=32, 256 threads, 3-buffer gload_lds pipeline (issue distance 2),
//          ONE barrier per iteration, no lgkm drain (compiler-scheduled ds_read->MFMA),
//          counted vmcnt(4); XCD-chunked bijective remap.
// AMODE 1: BM=128, fused patchify (legacy single-buffer, pitch-32 layout).
// LDS per buffer: [rows][4 chunks of 16B], phys chunk = c ^ ((row>>1)&3), pitch 32.
// SOUT 0: fp32 C (opt RESID).  2: single-f16 out.  3: qkv single-f16 out.
template<int BN, int TM, int TN, int AMODE, bool ASPLIT, bool BSPLIT, bool BIAS, bool GELU, bool RESID, int SOUT>
__global__ __launch_bounds__(256) void gemm_mfma(
    const ushort* __restrict__ aHp, const ushort* __restrict__ aLp, int lda,
    const ushort* __restrict__ wtH, const ushort* __restrict__ wtL, int ldb,
    const float* __restrict__ bias, float* __restrict__ C,
    ushort* __restrict__ coH, ushort* __restrict__ vOut,
    const float* __restrict__ videos, const float* __restrict__ atok,
    int M, int N, int K)
{
  constexpr int NWC = BN / (TN * 16);
  constexpr int NBUF = (AMODE == 0) ? 3 : 1;
  __shared__ __align__(16) ushort sAh[NBUF * 128 * 32];
  __shared__ __align__(16) ushort sAl[(AMODE == 1) ? 128 * 32 : 8];
  __shared__ __align__(16) ushort sBh[NBUF * BN * 32];
  __shared__ __align__(16) ushort sBl[BSPLIT ? NBUF * BN * 32 : 8];
  const int tid = threadIdx.x;
  int m0, n0;
  if (AMODE == 0) {
    // bijective XCD-chunked remap (m204): o%8 = XCD under round-robin dispatch
    const int gx = gridDim.x, gy = gridDim.y;
    const int nwg = gx * gy;
    const int o = blockIdx.y * gx + blockIdx.x;
    const int q = nwg >> 3, r = nwg & 7;
    const int xcd = o & 7, idx = o >> 3;
    const int wgid = (xcd < r ? xcd * (q + 1) : r * (q + 1) + (xcd - r) * q) + idx;
    const int mi = wgid / gy, ni = wgid - mi * gy;
    m0 = mi * 128; n0 = ni * BN;
  } else {
    m0 = blockIdx.x * 128; n0 = blockIdx.y * BN;
  }
  const int wid = tid >> 6, lane = tid & 63;
  const int lrow = lane & 15, lkg = lane >> 4;
  const int wr = wid / NWC, wc = wid % NWC;
  const int wrb = wr * TM * 16, wcb = wc * TN * 16;
  f32x4 acc[TM][TN];
#pragma unroll
  for (int mi = 0; mi < TM; mi++)
#pragma unroll
    for (int ni = 0; ni < TN; ni++) acc[mi][ni] = (f32x4){0.f, 0.f, 0.f, 0.f};

  if (AMODE == 0) {
    // ---- 3-buffer pipeline, one barrier per iteration
    const int chunkA0 = tid, chunkA1 = tid + 256;
    auto stage = [&](int k0, int d) {
      {
        int row = chunkA0 >> 2, cp = chunkA0 & 3;
        int csrc = cp ^ ((row >> 1) & 3);
        int ar = m0 + row; if (ar > M - 1) ar = M - 1;
        gload16(aHp + (long)ar * lda + k0 + csrc * 8, &sAh[d * 4096 + chunkA0 * 8]);
      }
      {
        int row = chunkA1 >> 2, cp = chunkA1 & 3;
        int csrc = cp ^ ((row >> 1) & 3);
        int ar = m0 + row; if (ar > M - 1) ar = M - 1;
        gload16(aHp + (long)ar * lda + k0 + csrc * 8, &sAh[d * 4096 + chunkA1 * 8]);
      }
      if (BN == 128) {
#pragma unroll
        for (int i = 0; i < 2; i++) {
          int chunk = tid + 256 * i;
          int row = chunk >> 2, cp = chunk & 3;
          int csrc = cp ^ ((row >> 1) & 3);
          gload16(wtH + (long)(n0 + row) * ldb + k0 + csrc * 8, &sBh[d * 4096 + chunk * 8]);
        }
      } else {
        int chunk = tid;
        int row = chunk >> 2, cp = chunk & 3;
        int csrc = cp ^ ((row >> 1) & 3);
        gload16(wtH + (long)(n0 + row) * ldb + k0 + csrc * 8, &sBh[d * 2048 + chunk * 8]);
        if (BSPLIT)
          gload16(wtL + (long)(n0 + row) * ldb + k0 + csrc * 8, &sBl[d * 2048 + chunk * 8]);
      }
    };
    const int nt = K >> 5;
    stage(0, 0);
    if (nt > 1) stage(32, 1);
    for (int t = 0; t < nt; t++) {
      const int cur = t % 3;
      if (t + 1 < nt) {
        asm volatile("s_waitcnt vmcnt(4)" ::: "memory");
      } else {
        asm volatile("s_waitcnt vmcnt(0)" ::: "memory");
      }
      __builtin_amdgcn_s_barrier();
      // buffer (t+2)%3 == (t-1)%3 was fully consumed before this barrier -> safe to fill
      if (t + 2 < nt) stage((t + 2) << 5, (t + 2) % 3);
      const int aBase = cur * 4096;
      const int bBase = cur * ((BN == 128) ? 4096 : 2048);
      __builtin_amdgcn_s_setprio(1);
      half8 aHf[TM];
#pragma unroll
      for (int mi = 0; mi < TM; mi++) {
        int ar = wrb + mi * 16 + lrow;
        int ac = (ar * 4 + (lkg ^ ((ar >> 1) & 3))) * 8;
        aHf[mi] = *(const half8*)&sAh[aBase + ac];
      }
#pragma unroll
      for (int ni = 0; ni < TN; ni++) {
        int br = wcb + ni * 16 + lrow;
        int bc = (br * 4 + (lkg ^ ((br >> 1) & 3))) * 8;
        if (BSPLIT) {
          half8 bL = *(const half8*)&sBl[bBase + bc];
#pragma unroll
          for (int mi = 0; mi < TM; mi++)
            acc[mi][ni] = __builtin_amdgcn_mfma_f32_16x16x32_f16(aHf[mi], bL, acc[mi][ni], 0, 0, 0);
        }
        half8 bH = *(const half8*)&sBh[bBase + bc];
#pragma unroll
        for (int mi = 0; mi < TM; mi++)
          acc[mi][ni] = __builtin_amdgcn_mfma_f32_16x16x32_f16(aHf[mi], bH, acc[mi][ni], 0, 0, 0);
      }
      __builtin_amdgcn_s_setprio(0);
      __builtin_amdgcn_sched_barrier(0);
    }
  } else {
    // ---- legacy single-buffer path (fused patchify embed GEMM)
    const int rowa = tid >> 1, kba = (tid & 1) << 4;
    const int cb0 = (tid & 1) * 2;
    const int swa = (rowa >> 1) & 3;
    int bt_p = 0, s_p = 0;
    { int ar = m0 + rowa; bt_p = ar / 257; s_p = ar - bt_p * 257; }
    for (int k0 = 0; k0 < K; k0 += 32) {
      float4 vr[4];
#pragma unroll
      for (int q = 0; q < 4; q++) vr[q] = make_float4(0.f, 0.f, 0.f, 0.f);
#pragma unroll
      for (int q = 0; q < 4; q++) {
        int e4 = k0 + kba + 4 * q;
        if (s_p == 0) {
          vr[q] = *(const float4*)(atok + e4);
        } else {
          int p = s_p - 1, ph = p >> 4, pw = p & 15;
          int iq = e4 / 24, jc = e4 - iq * 24;
          vr[q] = *(const float4*)(videos + (long)bt_p * 49152 +
                                   (long)(ph * 8 + iq) * 384 + pw * 24 + jc);
        }
      }
      uint hw[8], lw[8];
#pragma unroll
      for (int q = 0; q < 4; q++) {
        ushort h0,l0,h1,l1,h2,l2,h3,l3;
        split_f16(vr[q].x, h0, l0); split_f16(vr[q].y, h1, l1);
        split_f16(vr[q].z, h2, l2); split_f16(vr[q].w, h3, l3);
        hw[2*q]   = (uint)h0 | ((uint)h1 << 16); lw[2*q]   = (uint)l0 | ((uint)l1 << 16);
        hw[2*q+1] = (uint)h2 | ((uint)h3 << 16); lw[2*q+1] = (uint)l2 | ((uint)l3 << 16);
      }
      *(uint4*)&sAh[(rowa * 4 + (cb0 ^ swa)) * 8]       = make_uint4(hw[0], hw[1], hw[2], hw[3]);
      *(uint4*)&sAh[(rowa * 4 + ((cb0 + 1) ^ swa)) * 8] = make_uint4(hw[4], hw[5], hw[6], hw[7]);
      *(uint4*)&sAl[(rowa * 4 + (cb0 ^ swa)) * 8]       = make_uint4(lw[0], lw[1], lw[2], lw[3]);
      *(uint4*)&sAl[(rowa * 4 + ((cb0 + 1) ^ swa)) * 8] = make_uint4(lw[4], lw[5], lw[6], lw[7]);
      {
#pragma unroll
        for (int i = 0; i < 2; i++) {
          int chunk = tid + 256 * i;
          int row = chunk >> 2, cp = chunk & 3;
          int csrc = cp ^ ((row >> 1) & 3);
          gload16(wtH + (long)(n0 + row) * ldb + k0 + csrc * 8, &sBh[chunk * 8]);
          if (BSPLIT)
            gload16(wtL + (long)(n0 + row) * ldb + k0 + csrc * 8, &sBl[chunk * 8]);
        }
      }
      __syncthreads();
      half8 aHf[TM], aLf[TM];
#pragma unroll
      for (int mi = 0; mi < TM; mi++) {
        int ar = wrb + mi * 16 + lrow;
        int ac = (ar * 4 + (lkg ^ ((ar >> 1) & 3))) * 8;
        aHf[mi] = *(const half8*)&sAh[ac];
        if (ASPLIT) aLf[mi] = *(const half8*)&sAl[ac];
      }
#pragma unroll
      for (int ni = 0; ni < TN; ni++) {
        int br = wcb + ni * 16 + lrow;
        int bc = (br * 4 + (lkg ^ ((br >> 1) & 3))) * 8;
        half8 bH = *(const half8*)&sBh[bc];
#pragma unroll
        for (int mi = 0; mi < TM; mi++) {
          if (ASPLIT)
            acc[mi][ni] = __builtin_amdgcn_mfma_f32_16x16x32_f16(aLf[mi], bH, acc[mi][ni], 0, 0, 0);
        }
        if (BSPLIT) {
          half8 bL = *(const half8*)&sBl[bc];
#pragma unroll
          for (int mi = 0; mi < TM; mi++)
            acc[mi][ni] = __builtin_amdgcn_mfma_f32_16x16x32_f16(aHf[mi], bL, acc[mi][ni], 0, 0, 0);
        }
#pragma unroll
        for (int mi = 0; mi < TM; mi++)
          acc[mi][ni] = __builtin_amdgcn_mfma_f32_16x16x32_f16(aHf[mi], bH, acc[mi][ni], 0, 0, 0);
      }
      __syncthreads();
    }
  }
  // ---- epilogue
#pragma unroll
  for (int mi = 0; mi < TM; mi++) {
    int rowg = m0 + wrb + mi * 16 + lkg * 4;
#pragma unroll
    for (int j = 0; j < 4; j++) {
      int r = rowg + j;
      if (r < M) {
#pragma unroll
        for (int ni = 0; ni < TN; ni++) {
          int cg = n0 + wcb + ni * 16 + lrow;
          float v = acc[mi][ni][j] * WINV;
          if (BIAS) v += bias[cg];
          if (GELU) v = gelu_f(v);
          if (SOUT == 2) {
            coH[(long)r * N + cg] = to_f16u(v);
          } else if (SOUT == 3) {
            if (cg < 1024) coH[(long)r * 1024 + cg] = to_f16u(v);
            else           vOut[(long)r * 512 + (cg - 1024)] = to_f16u(v);
          } else {
            long idx = (long)r * N + cg;
            if (RESID) C[idx] += v; else C[idx] = v;
          }
        }
      }
    }
  }
}

// ---------------- fused flash spatial attention over a chunk PAIR (32 frames).
__global__ __launch_bounds__(256) void flash_spatial(
    const ushort* __restrict__ qk, const ushort* __restrict__ v2,
    ushort* __restrict__ ctxc)
{
  __shared__ __align__(16) ushort sQ[64*72];
  __shared__ __align__(16) ushort sK[64*72];
  __shared__ __align__(16) ushort sV[64*72];               // V^T: [d][k]
  __shared__ __align__(16) ushort sP[64*72];
  const int tid = threadIdx.x;
  const int wid = tid >> 6, lane = tid & 63;
  const int lr = lane & 15, lg = lane >> 4;
  const int fh = blockIdx.y;                  // 0..255 (32 frames x 8 heads)
  const int fl = fh >> 3, hh = fh & 7;
  const int q0 = blockIdx.x * 64;
  const long rbase = (long)fl * S_;
  const int srow = tid >> 2, sc0 = (tid & 3) << 4;

  {
    int gr = q0 + srow;
    uint4 h0 = make_uint4(0,0,0,0), h1 = h0;
    if (gr < S_) {
      const ushort* sh = qk + (rbase + gr) * 1024 + hh * HD_ + sc0;
      h0 = ((const uint4*)sh)[0]; h1 = ((const uint4*)sh)[1];
    }
    uint4* dh = (uint4*)&sQ[srow*72 + sc0];
    dh[0] = h0; dh[1] = h1;
  }
  __syncthreads();
  half8 qH[2];
  {
    int qrl = wid * 16 + lr;
#pragma unroll
    for (int s = 0; s < 2; s++)
      qH[s] = *(const half8*)&sQ[qrl*72 + s*32 + lg*8];
  }
  f32x4 accS[5][4];
#pragma unroll
  for (int t = 0; t < 5; t++)
#pragma unroll
    for (int kc = 0; kc < 4; kc++) accS[t][kc] = (f32x4){0.f,0.f,0.f,0.f};

#pragma unroll
  for (int t = 0; t < 5; t++) {
    __syncthreads();
    {
      int gr = t*64 + srow;
      uint4 h0 = make_uint4(0,0,0,0), h1 = h0;
      if (gr < S_) {
        const ushort* sh = qk + (rbase + gr) * 1024 + 512 + hh * HD_ + sc0;
        h0 = ((const uint4*)sh)[0]; h1 = ((const uint4*)sh)[1];
      }
      uint4* dh = (uint4*)&sK[srow*72 + sc0];
      dh[0] = h0; dh[1] = h1;
    }
    __syncthreads();
#pragma unroll
    for (int s = 0; s < 2; s++) {
#pragma unroll
      for (int kc = 0; kc < 4; kc++) {
        int off = (kc*16 + lr)*72 + s*32 + lg*8;
        half8 bH = *(const half8*)&sK[off];
        accS[t][kc] = __builtin_amdgcn_mfma_f32_16x16x32_f16(qH[s], bH, accS[t][kc], 0,0,0);
      }
    }
  }

  float m[4] = {-3.0e38f, -3.0e38f, -3.0e38f, -3.0e38f};
#pragma unroll
  for (int t = 0; t < 5; t++)
#pragma unroll
    for (int kc = 0; kc < 4; kc++) {
      int kcol = t*64 + kc*16 + lr;
      if (kcol < S_) {
#pragma unroll
        for (int j = 0; j < 4; j++) m[j] = fmaxf(m[j], accS[t][kc][j] * 0.125f);
      }
    }
#pragma unroll
  for (int mk = 8; mk >= 1; mk >>= 1)
#pragma unroll
    for (int j = 0; j < 4; j++) m[j] = fmaxf(m[j], __shfl_xor(m[j], mk));
  float l[4] = {0.f, 0.f, 0.f, 0.f};
#pragma unroll
  for (int t = 0; t < 5; t++)
#pragma unroll
    for (int kc = 0; kc < 4; kc++) {
      int kcol = t*64 + kc*16 + lr;
#pragma unroll
      for (int j = 0; j < 4; j++) {
        float p = (kcol < S_) ? expf(accS[t][kc][j]*0.125f - m[j]) : 0.f;
        accS[t][kc][j] = p;
        l[j] += p;
      }
    }
#pragma unroll
  for (int mk = 8; mk >= 1; mk >>= 1)
#pragma unroll
    for (int j = 0; j < 4; j++) l[j] += __shfl_xor(l[j], mk);

  f32x4 accO[4];
#pragma unroll
  for (int dc = 0; dc < 4; dc++) accO[dc] = (f32x4){0.f,0.f,0.f,0.f};
#pragma unroll
  for (int t = 0; t < 5; t++) {
#pragma unroll
    for (int kc = 0; kc < 4; kc++)
#pragma unroll
      for (int j = 0; j < 4; j++) {
        int addr = (wid*16 + lg*4 + j)*72 + kc*16 + lr;
        sP[addr] = to_f16u(accS[t][kc][j]);
      }
    __syncthreads();
    {
      int gr = t*64 + srow;
      ushort tmp[16];
      uint4 a = make_uint4(0,0,0,0), b = a;
      if (gr < S_) {
        const ushort* src = v2 + (rbase + gr) * 512 + hh * HD_ + sc0;
        a = ((const uint4*)src)[0]; b = ((const uint4*)src)[1];
      }
      *(uint4*)&tmp[0] = a; *(uint4*)&tmp[8] = b;
#pragma unroll
      for (int e = 0; e < 16; e++) sV[(sc0 + e)*72 + srow] = tmp[e];
    }
    __syncthreads();
#pragma unroll
    for (int s = 0; s < 2; s++) {
      int poff = (wid*16 + lr)*72 + s*32 + lg*8;
      half8 pH = *(const half8*)&sP[poff];
#pragma unroll
      for (int dc = 0; dc < 4; dc++) {
        int voff = (dc*16 + lr)*72 + s*32 + lg*8;
        half8 vH = *(const half8*)&sV[voff];
        accO[dc] = __builtin_amdgcn_mfma_f32_16x16x32_f16(pH, vH, accO[dc], 0,0,0);
      }
    }
  }
#pragma unroll
  for (int j = 0; j < 4; j++) {
    int grow = q0 + wid*16 + lg*4 + j;
    if (grow < S_) {
      float inv = 1.0f / l[j];
#pragma unroll
      for (int dc = 0; dc < 4; dc++) {
        float o = accO[dc][j] * inv;
        long idx = (rbase + grow) * 512 + hh*64 + dc*16 + lr;
        ctxc[idx] = to_f16u(o);
      }
    }
  }
}

// ---------------- temporal causal attention over a chunk pair (2 batches), single-f16 qkv
__global__ __launch_bounds__(64) void temporal_attn(
    const ushort* __restrict__ qk, const ushort* __restrict__ v2,
    ushort* __restrict__ ctxc)
{
  const int gid = blockIdx.x;           // b2*2056 + s*8+h
  const int b2 = gid / (S_ * NH_);
  const int rem = gid - b2 * S_ * NH_;
  const int hh = rem & 7;
  const int s = rem >> 3;
  const int lane = threadIdx.x;
  __shared__ float Qs[16][65];
  __shared__ float Ks[16][65];
  __shared__ float Pm[16][17];
  float v[16];
  const long rbase = (long)b2 * CH + s;
#pragma unroll
  for (int t = 0; t < 16; t++) {
    long row = rbase + (long)t * S_;
    long qoff = row * 1024 + hh * HD_ + lane;
    Qs[t][lane] = from_f16u(qk[qoff]);
    Ks[t][lane] = from_f16u(qk[qoff + 512]);
    v[t] = from_f16u(v2[row * 512 + hh * HD_ + lane]);
  }
  __syncthreads();
  const int rq = lane >> 2, c0 = lane & 3;
  float sc[4];
#pragma unroll
  for (int j = 0; j < 4; j++) {
    int c = c0 + (j << 2);
    if (c <= rq) {
      float d = 0.f;
#pragma unroll
      for (int k = 0; k < 64; k++) d = fmaf(Qs[rq][k], Ks[c][k], d);
      sc[j] = d * 0.125f;
    } else sc[j] = -3.0e38f;
  }
  float mx = fmaxf(fmaxf(sc[0], sc[1]), fmaxf(sc[2], sc[3]));
  mx = fmaxf(mx, __shfl_xor(mx, 1));
  mx = fmaxf(mx, __shfl_xor(mx, 2));
  float sum = 0.f;
#pragma unroll
  for (int j = 0; j < 4; j++) { sc[j] = expf(sc[j] - mx); sum += sc[j]; }
  sum += __shfl_xor(sum, 1);
  sum += __shfl_xor(sum, 2);
  float inv = 1.0f / sum;
#pragma unroll
  for (int j = 0; j < 4; j++) Pm[rq][c0 + (j << 2)] = sc[j] * inv;
  __syncthreads();
#pragma unroll
  for (int t = 0; t < 16; t++) {
    float o = 0.f;
#pragma unroll
    for (int k = 0; k < 16; k++) o = fmaf(Pm[t][k], v[k], o);
    long idx = (rbase + (long)t * S_) * 512 + hh * HD_ + lane;
    ctxc[idx] = to_f16u(o);
  }
}

// ---------------- final LN + projection + VQ argmin + action head
__global__ __launch_bounds__(256) void final_vq(
    const float* __restrict__ tok, const float* __restrict__ lnf_g,
    const float* __restrict__ lnf_b, const float* __restrict__ out_w,
    const float* __restrict__ codebook, const float* __restrict__ action_w,
    float* __restrict__ out)
{
  __shared__ float xs[512];
  __shared__ float red[256];
  __shared__ float zs[64];
  __shared__ float bd[256];
  __shared__ int   bi[256];
  const int b = blockIdx.x / 15, tm = blockIdx.x % 15;
  const int tid = threadIdx.x;
  const float* xr = tok + ((long)(b * T_ + tm + 1) * S_) * D_;   // s = 0
  xs[tid] = xr[tid]; xs[tid + 256] = xr[tid + 256];
  red[tid] = xs[tid] + xs[tid + 256];
  __syncthreads();
  for (int off = 128; off >= 1; off >>= 1) {
    if (tid < off) red[tid] += red[tid + off];
    __syncthreads();
  }
  float mean = red[0] * (1.0f / 512.0f);
  __syncthreads();
  float d0 = xs[tid] - mean, d1 = xs[tid + 256] - mean;
  red[tid] = d0 * d0 + d1 * d1;
  __syncthreads();
  for (int off = 128; off >= 1; off >>= 1) {
    if (tid < off) red[tid] += red[tid + off];
    __syncthreads();
  }
  float rs = rsqrtf(red[0] * (1.0f / 512.0f) + 1e-5f);
  __syncthreads();
  xs[tid]       = d0 * rs * lnf_g[tid]       + lnf_b[tid];
  xs[tid + 256] = d1 * rs * lnf_g[tid + 256] + lnf_b[tid + 256];
  __syncthreads();
  if (tid < 64) {
    float z = 0.f;
    for (int d = 0; d < 512; d++) z = fmaf(xs[d], out_w[d * 64 + tid], z);
    zs[tid] = z;
  }
  __syncthreads();
  float best = 3.0e38f; int bidx = 0;
  for (int c = tid; c < 4096; c += 256) {
    const float* cp = codebook + (long)c * 64;
    float dot = 0.f, cn = 0.f;
#pragma unroll 8
    for (int k = 0; k < 64; k++) { float w = cp[k]; dot = fmaf(zs[k], w, dot); cn = fmaf(w, w, cn); }
    float dist = cn - 2.0f * dot;
    if (dist < best) { best = dist; bidx = c; }
  }
  bd[tid] = best; bi[tid] = bidx;
  __syncthreads();
  for (int off = 128; off >= 1; off >>= 1) {
    if (tid < off) {
      if (bd[tid + off] < bd[tid] || (bd[tid + off] == bd[tid] && bi[tid + off] < bi[tid])) {
        bd[tid] = bd[tid + off]; bi[tid] = bi[tid + off];
      }
    }
    __syncthreads();
  }
  int idx = bi[0];
  if (tid < 16) {
    const float* cp = codebook + (long)idx * 64;
    float o = 0.f;
#pragma unroll
    for (int k = 0; k < 64; k++) o = fmaf(cp[k], action_w[k * 16 + tid], o);
    out[((long)(b * 15 + tm)) * 16 + tid] = o;
  }
}

extern "C" void kernel_launch(void* const* d_in, const int* in_sizes, int n_in,
                              void* d_out, int out_size, void* d_ws, size_t ws_size,
                              hipStream_t stream)
{
  const float* videos       = (const float*)d_in[0];
  const float* patch_w      = (const float*)d_in[1];
  const float* patch_b      = (const float*)d_in[2];
  const float* action_token = (const float*)d_in[3];
  const float* ln1_g  = (const float*)d_in[4];
  const float* ln1_b  = (const float*)d_in[5];
  const float* wqkv_s = (const float*)d_in[6];
  const float* wo_s   = (const float*)d_in[7];
  const float* ln2_g  = (const float*)d_in[8];
  const float* ln2_b  = (const float*)d_in[9];
  const float* wqkv_t = (const float*)d_in[10];
  const float* wo_t   = (const float*)d_in[11];
  const float* ln3_g  = (const float*)d_in[12];
  const float* ln3_b  = (const float*)d_in[13];
  const float* mlp_w1 = (const float*)d_in[14];
  const float* mlp_b1 = (const float*)d_in[15];
  const float* mlp_w2 = (const float*)d_in[16];
  const float* mlp_b2 = (const float*)d_in[17];
  const float* lnf_g  = (const float*)d_in[18];
  const float* lnf_b  = (const float*)d_in[19];
  const float* out_w  = (const float*)d_in[20];
  const float* codebook = (const float*)d_in[21];
  const float* action_w = (const float*)d_in[22];
  float* out = (float*)d_out;

  // ---- workspace layout (floats), total 29,466,624 f = 117.9 MB (< proven 135)
  float* ws    = (float*)d_ws;
  float* tok   = ws;                                  // 16,842,752
  ushort* wt1h = (ushort*)(ws + 16842752);            // 1,048,576 f-eq (hi+lo)
  ushort* wt1l = wt1h + 1048576;
  ushort* wt2h = (ushort*)(ws + 17891328);            // 1,048,576 f-eq
  ushort* wt2l = wt2h + 1048576;
  ushort* aH   = (ushort*)(ws + 18939904);            // PCH x 512 single f16 = 2,105,344 f-eq
  ushort* qk   = (ushort*)(ws + 21045248);            // PCH x 1024 single = 4,210,688 f-eq
  ushort* v2   = (ushort*)(ws + 25255936);            // PCH x 512 single  = 2,105,344 f-eq
  ushort* ctx  = (ushort*)(ws + 27361280);            // PCH x 512 single  = 2,105,344 f-eq
  ushort* mid  = qk;                                  // MLP mid (PCH x 2048) spans qk+v2+ctx

  // ---- patchify fused into embed GEMM (full 3-MFMA, legacy path)
  convert_w<<<dim3(3, 8), 256, 0, stream>>>(patch_w, wt1h, wt1l, 512, 192);
  gemm_mfma<128,4,4,1,true,true,true,false,false,0><<<dim3(257, 4), 256, 0, stream>>>(
      nullptr, nullptr, 0, wt1h, wt1l, 192, patch_b, tok, nullptr, nullptr,
      videos, action_token, NTOK, 512, 192);

  for (int L = 0; L < 4; L++) {
    // ================= spatial attention (4 chunk pairs) =================
    convert_w<<<dim3(8, 24), 256, 0, stream>>>(wqkv_s + (long)L*512*1536, wt1h, wt1l, 1536, 512);
    convert_w<<<dim3(8, 8),  256, 0, stream>>>(wo_s   + (long)L*512*512,  wt2h, wt2l, 512, 512);
    for (int pr = 0; pr < 4; pr++) {
      long r0 = (long)pr * PCH;
      ln_single<<<PCH / 4, 256, 0, stream>>>(tok + r0 * D_, ln1_g + L*512, ln1_b + L*512, aH);
      gemm_mfma<128,4,4,0,false,false,false,false,false,3><<<dim3(65, 12), 256, 0, stream>>>(
          aH, nullptr, 512, wt1h, wt1l, 512, nullptr, nullptr,
          qk, v2, nullptr, nullptr, PCH, 1536, 512);
      flash_spatial<<<dim3(5, 256), 256, 0, stream>>>(qk, v2, ctx);
      gemm_mfma<64,2,4,0,false,true,false,false,true,0><<<dim3(65, 8), 256, 0, stream>>>(
          ctx, nullptr, 512, wt2h, wt2l, 512, nullptr, tok + r0 * D_,
          nullptr, nullptr, nullptr, nullptr, PCH, 512, 512);
    }
    // ================= temporal attention (4 chunk pairs) =================
    convert_w<<<dim3(8, 24), 256, 0, stream>>>(wqkv_t + (long)L*512*1536, wt1h, wt1l, 1536, 512);
    convert_w<<<dim3(8, 8),  256, 0, stream>>>(wo_t   + (long)L*512*512,  wt2h, wt2l, 512, 512);
    for (int pr = 0; pr < 4; pr++) {
      long r0 = (long)pr * PCH;
      ln_single<<<PCH / 4, 256, 0, stream>>>(tok + r0 * D_, ln2_g + L*512, ln2_b + L*512, aH);
      gemm_mfma<128,4,4,0,false,false,false,false,false,3><<<dim3(65, 12), 256, 0, stream>>>(
          aH, nullptr, 512, wt1h, wt1l, 512, nullptr, nullptr,
          qk, v2, nullptr, nullptr, PCH, 1536, 512);
      temporal_attn<<<2 * S_ * NH_, 64, 0, stream>>>(qk, v2, ctx);
      gemm_mfma<64,2,4,0,false,true,false,false,true,0><<<dim3(65, 8), 256, 0, stream>>>(
          ctx, nullptr, 512, wt2h, wt2l, 512, nullptr, tok + r0 * D_,
          nullptr, nullptr, nullptr, nullptr, PCH, 512, 512);
    }
    // ================= MLP (4 M-chunks of 8224 rows) =================
    convert_w<<<dim3(8, 32), 256, 0, stream>>>(mlp_w1 + (long)L*512*2048, wt1h, wt1l, 2048, 512);
    convert_w<<<dim3(32, 8), 256, 0, stream>>>(mlp_w2 + (long)L*2048*512, wt2h, wt2l, 512, 2048);
    for (int c = 0; c < 4; c++) {
      long m0r = (long)c * PCH;
      ln_single<<<PCH / 4, 256, 0, stream>>>(tok + m0r * D_, ln3_g + L*512, ln3_b + L*512, aH);
      gemm_mfma<128,4,4,0,false,false,true,true,false,2><<<dim3(65, 16), 256, 0, stream>>>(
          aH, nullptr, 512, wt1h, wt1l, 512, mlp_b1 + (long)L*2048, nullptr, mid, nullptr,
          nullptr, nullptr, PCH, FFN_, 512);
      gemm_mfma<64,2,4,0,false,true,true,false,true,0><<<dim3(65, 8), 256, 0, stream>>>(
          mid, nullptr, 2048, wt2h, wt2l, 2048, mlp_b2 + (long)L*512, tok + m0r * D_,
          nullptr, nullptr, nullptr, nullptr, PCH, 512, 2048);
    }
  }

  final_vq<<<B_ * (T_ - 1), 256, 0, stream>>>(tok, lnf_g, lnf_b, out_w, codebook, action_w, out);
}

// Round 23
// 4509.275 us; speedup vs baseline: 1.0809x; 1.0809x over previous
//
#include <hip/hip_runtime.h>
#include <hip/hip_bf16.h>

#define B_ 8
#define T_ 16
#define S_ 257
#define D_ 512
#define FFN_ 2048
#define NH_ 8
#define HD_ 64
#define PTD_ 192
#define NTOK (B_*T_*S_)        // 32896
#define CH 4112                // 16 frames * 257 rows per chunk
#define PCH 8224               // chunk pair rows
#define WSCALE 64.0f
#define WINV 0.015625f

typedef unsigned int uint;
typedef unsigned short ushort;
typedef __attribute__((ext_vector_type(8))) _Float16 half8;
typedef __attribute__((ext_vector_type(4))) float f32x4;

__device__ __forceinline__ float warp_rsum(float v){
#pragma unroll
  for (int m = 32; m >= 1; m >>= 1) v += __shfl_xor(v, m);
  return v;
}
__device__ __forceinline__ float gelu_f(float x){
  float x3 = x*x*x;
  return 0.5f*x*(1.0f + tanhf(0.7978845608028654f*(x + 0.044715f*x3)));
}
// split fp32 -> f16 hi + f16 lo (RNE).
__device__ __forceinline__ void split_f16(float f, ushort& h, ushort& l){
  _Float16 hh = (_Float16)f;
  float hf = (float)hh;
  _Float16 ll = (_Float16)(f - hf);
  h = __builtin_bit_cast(ushort, hh);
  l = __builtin_bit_cast(ushort, ll);
}
__device__ __forceinline__ ushort to_f16u(float f){
  return __builtin_bit_cast(ushort, (_Float16)f);
}
__device__ __forceinline__ float from_f16u(ushort u){
  return (float)__builtin_bit_cast(_Float16, u);
}
// async global->LDS 16B (lane-linear LDS dest, per-lane global src)
__device__ __forceinline__ void gload16(const ushort* g, ushort* l){
  __builtin_amdgcn_global_load_lds(
      (const __attribute__((address_space(1))) void*)(g),
      (__attribute__((address_space(3))) void*)(l),
      16, 0, 0);
}

// ---------------- fused LN + single-f16 cast:  aH[row][512] = f16(LN(x[row]))
__global__ __launch_bounds__(256) void ln_single(
    const float* __restrict__ x, const float* __restrict__ g,
    const float* __restrict__ bb, ushort* __restrict__ aH)
{
  int row = blockIdx.x * 4 + (threadIdx.x >> 6);
  int lane = threadIdx.x & 63;
  const float* xr = x + (long)row * D_;
  float4 u0 = *(const float4*)(xr + lane * 8);
  float4 u1 = *(const float4*)(xr + lane * 8 + 4);
  float s = u0.x + u0.y + u0.z + u0.w + u1.x + u1.y + u1.z + u1.w;
  s = warp_rsum(s);
  float mean = s * (1.0f / 512.0f);
  float d[8] = {u0.x - mean, u0.y - mean, u0.z - mean, u0.w - mean,
                u1.x - mean, u1.y - mean, u1.z - mean, u1.w - mean};
  float ss = 0.f;
#pragma unroll
  for (int i = 0; i < 8; i++) ss = fmaf(d[i], d[i], ss);
  ss = warp_rsum(ss);
  float rstd = rsqrtf(ss * (1.0f / 512.0f) + 1e-5f);
  int c = lane * 8;
  float4 g0 = *(const float4*)(g + c), g1 = *(const float4*)(g + c + 4);
  float4 b0 = *(const float4*)(bb + c), b1 = *(const float4*)(bb + c + 4);
  float y[8] = {d[0]*rstd*g0.x + b0.x, d[1]*rstd*g0.y + b0.y,
                d[2]*rstd*g0.z + b0.z, d[3]*rstd*g0.w + b0.w,
                d[4]*rstd*g1.x + b1.x, d[5]*rstd*g1.y + b1.y,
                d[6]*rstd*g1.z + b1.z, d[7]*rstd*g1.w + b1.w};
  ushort h[8];
#pragma unroll
  for (int i = 0; i < 8; i++) h[i] = to_f16u(y[i]);
  uint4 hv = make_uint4((uint)h[0] | ((uint)h[1] << 16), (uint)h[2] | ((uint)h[3] << 16),
                        (uint)h[4] | ((uint)h[5] << 16), (uint)h[6] | ((uint)h[7] << 16));
  *(uint4*)(aH + (long)row * 512 + c) = hv;
}

// ---------------- weight transpose + split:  W[K][N] f32 -> (W*64) as Whi[N][K], Wlo[N][K] f16
__global__ __launch_bounds__(256) void convert_w(
    const float* __restrict__ W, ushort* __restrict__ Whi, ushort* __restrict__ Wlo,
    int N, int K)
{
  __shared__ float Tt[64][65];
  const int tid = threadIdx.x;
  const int k0 = blockIdx.x << 6, n0 = blockIdx.y << 6;
  {
    int kk = tid >> 2, nb = (tid & 3) << 4;
#pragma unroll
    for (int q = 0; q < 4; q++) {
      float4 v = *(const float4*)(W + (long)(k0 + kk) * N + n0 + nb + 4 * q);
      Tt[kk][nb + 4*q + 0] = v.x; Tt[kk][nb + 4*q + 1] = v.y;
      Tt[kk][nb + 4*q + 2] = v.z; Tt[kk][nb + 4*q + 3] = v.w;
    }
  }
  __syncthreads();
  {
    int nn = tid >> 2, kb = (tid & 3) << 4;
    uint hw[8], lw[8];
#pragma unroll
    for (int q = 0; q < 8; q++) {
      float a = Tt[kb + 2*q][nn] * WSCALE, b = Tt[kb + 2*q + 1][nn] * WSCALE;
      ushort ha, la, hb, lb;
      split_f16(a, ha, la); split_f16(b, hb, lb);
      hw[q] = (uint)ha | ((uint)hb << 16); lw[q] = (uint)la | ((uint)lb << 16);
    }
    ushort* dh = Whi + (long)(n0 + nn) * K + k0 + kb;
    ushort* dl = Wlo + (long)(n0 + nn) * K + k0 + kb;
    ((uint4*)dh)[0] = make_uint4(hw[0], hw[1], hw[2], hw[3]);
    ((uint4*)dh)[1] = make_uint4(hw[4], hw[5], hw[6], hw[7]);
    ((uint4*)dl)[0] = make_uint4(lw[0], lw[1], lw[2], lw[3]);
    ((uint4*)dl)[1] = make_uint4(lw[4], lw[5], lw[6], lw[7]);
  }
}

// ---------------- split-f16 MFMA GEMM.
// AMODE 0: BM=128, BK=32, 256 threads, 2-deep gload_lds pipeline with EARLY second
//          barrier: {vmcnt(4); bar; ds_read frags -> regs; lgkmcnt(0); bar;
//          stage(t+2 into freed buf); MFMA on regs}.  XCD-chunked bijective remap.
// AMODE 1: BM=128, fused patchify (legacy single-buffer, pitch-32 layout).
// LDS per buffer: [rows][4 chunks of 16B], phys chunk = c ^ ((row>>1)&3), pitch 32.
// SOUT 0: fp32 C (opt RESID).  2: single-f16 out.  3: qkv single-f16 out.
template<int BN, int TM, int TN, int AMODE, bool ASPLIT, bool BSPLIT, bool BIAS, bool GELU, bool RESID, int SOUT>
__global__ __launch_bounds__(256) void gemm_mfma(
    const ushort* __restrict__ aHp, const ushort* __restrict__ aLp, int lda,
    const ushort* __restrict__ wtH, const ushort* __restrict__ wtL, int ldb,
    const float* __restrict__ bias, float* __restrict__ C,
    ushort* __restrict__ coH, ushort* __restrict__ vOut,
    const float* __restrict__ videos, const float* __restrict__ atok,
    int M, int N, int K)
{
  constexpr int NWC = BN / (TN * 16);
  constexpr int NBUF = (AMODE == 0) ? 2 : 1;
  __shared__ __align__(16) ushort sAh[NBUF * 128 * 32];
  __shared__ __align__(16) ushort sAl[(AMODE == 1) ? 128 * 32 : 8];
  __shared__ __align__(16) ushort sBh[NBUF * BN * 32];
  __shared__ __align__(16) ushort sBl[BSPLIT ? NBUF * BN * 32 : 8];
  const int tid = threadIdx.x;
  int m0, n0;
  if (AMODE == 0) {
    // bijective XCD-chunked remap (m204): o%8 = XCD under round-robin dispatch
    const int gx = gridDim.x, gy = gridDim.y;
    const int nwg = gx * gy;
    const int o = blockIdx.y * gx + blockIdx.x;
    const int q = nwg >> 3, r = nwg & 7;
    const int xcd = o & 7, idx = o >> 3;
    const int wgid = (xcd < r ? xcd * (q + 1) : r * (q + 1) + (xcd - r) * q) + idx;
    const int mi = wgid / gy, ni = wgid - mi * gy;
    m0 = mi * 128; n0 = ni * BN;
  } else {
    m0 = blockIdx.x * 128; n0 = blockIdx.y * BN;
  }
  const int wid = tid >> 6, lane = tid & 63;
  const int lrow = lane & 15, lkg = lane >> 4;
  const int wr = wid / NWC, wc = wid % NWC;
  const int wrb = wr * TM * 16, wcb = wc * TN * 16;
  f32x4 acc[TM][TN];
#pragma unroll
  for (int mi = 0; mi < TM; mi++)
#pragma unroll
    for (int ni = 0; ni < TN; ni++) acc[mi][ni] = (f32x4){0.f, 0.f, 0.f, 0.f};

  if (AMODE == 0) {
    // ---- 2-deep pipeline, early-barrier register-fragment consume
    const int chunkA0 = tid, chunkA1 = tid + 256;
    auto stage = [&](int k0, int d) {
      {
        int row = chunkA0 >> 2, cp = chunkA0 & 3;
        int csrc = cp ^ ((row >> 1) & 3);
        int ar = m0 + row; if (ar > M - 1) ar = M - 1;
        gload16(aHp + (long)ar * lda + k0 + csrc * 8, &sAh[d * 4096 + chunkA0 * 8]);
      }
      {
        int row = chunkA1 >> 2, cp = chunkA1 & 3;
        int csrc = cp ^ ((row >> 1) & 3);
        int ar = m0 + row; if (ar > M - 1) ar = M - 1;
        gload16(aHp + (long)ar * lda + k0 + csrc * 8, &sAh[d * 4096 + chunkA1 * 8]);
      }
      if (BN == 128) {
#pragma unroll
        for (int i = 0; i < 2; i++) {
          int chunk = tid + 256 * i;
          int row = chunk >> 2, cp = chunk & 3;
          int csrc = cp ^ ((row >> 1) & 3);
          gload16(wtH + (long)(n0 + row) * ldb + k0 + csrc * 8, &sBh[d * 4096 + chunk * 8]);
        }
      } else {
        int chunk = tid;
        int row = chunk >> 2, cp = chunk & 3;
        int csrc = cp ^ ((row >> 1) & 3);
        gload16(wtH + (long)(n0 + row) * ldb + k0 + csrc * 8, &sBh[d * 2048 + chunk * 8]);
        if (BSPLIT)
          gload16(wtL + (long)(n0 + row) * ldb + k0 + csrc * 8, &sBl[d * 2048 + chunk * 8]);
      }
    };
    const int nt = K >> 5;
    stage(0, 0);
    if (nt > 1) stage(32, 1);
    for (int t = 0; t < nt; t++) {
      const int cur = t & 1;
      if (t + 1 < nt) {
        asm volatile("s_waitcnt vmcnt(4)" ::: "memory");
      } else {
        asm volatile("s_waitcnt vmcnt(0)" ::: "memory");
      }
      __builtin_amdgcn_s_barrier();
      const int aBase = cur * 4096;
      const int bBase = cur * ((BN == 128) ? 4096 : 2048);
      // ---- read all fragments into registers
      half8 aHf[TM], bHf[TN], bLf[BSPLIT ? TN : 1];
#pragma unroll
      for (int mi = 0; mi < TM; mi++) {
        int ar = wrb + mi * 16 + lrow;
        int ac = (ar * 4 + (lkg ^ ((ar >> 1) & 3))) * 8;
        aHf[mi] = *(const half8*)&sAh[aBase + ac];
      }
#pragma unroll
      for (int ni = 0; ni < TN; ni++) {
        int br = wcb + ni * 16 + lrow;
        int bc = (br * 4 + (lkg ^ ((br >> 1) & 3))) * 8;
        bHf[ni] = *(const half8*)&sBh[bBase + bc];
        if (BSPLIT) bLf[ni] = *(const half8*)&sBl[bBase + bc];
      }
      asm volatile("s_waitcnt lgkmcnt(0)" ::: "memory");
      __builtin_amdgcn_sched_barrier(0);
      __builtin_amdgcn_s_barrier();
      // ---- buffer freed: issue tile t+2 into it NOW (2-iteration issue distance)
      if (t + 2 < nt) stage((t + 2) << 5, cur);
      // ---- MFMA purely on registers (overlaps the in-flight loads)
      __builtin_amdgcn_s_setprio(1);
#pragma unroll
      for (int ni = 0; ni < TN; ni++) {
        if (BSPLIT) {
#pragma unroll
          for (int mi = 0; mi < TM; mi++)
            acc[mi][ni] = __builtin_amdgcn_mfma_f32_16x16x32_f16(aHf[mi], bLf[ni], acc[mi][ni], 0, 0, 0);
        }
#pragma unroll
        for (int mi = 0; mi < TM; mi++)
          acc[mi][ni] = __builtin_amdgcn_mfma_f32_16x16x32_f16(aHf[mi], bHf[ni], acc[mi][ni], 0, 0, 0);
      }
      __builtin_amdgcn_s_setprio(0);
      __builtin_amdgcn_sched_barrier(0);
    }
  } else {
    // ---- legacy single-buffer path (fused patchify embed GEMM)
    const int rowa = tid >> 1, kba = (tid & 1) << 4;
    const int cb0 = (tid & 1) * 2;
    const int swa = (rowa >> 1) & 3;
    int bt_p = 0, s_p = 0;
    { int ar = m0 + rowa; bt_p = ar / 257; s_p = ar - bt_p * 257; }
    for (int k0 = 0; k0 < K; k0 += 32) {
      float4 vr[4];
#pragma unroll
      for (int q = 0; q < 4; q++) vr[q] = make_float4(0.f, 0.f, 0.f, 0.f);
#pragma unroll
      for (int q = 0; q < 4; q++) {
        int e4 = k0 + kba + 4 * q;
        if (s_p == 0) {
          vr[q] = *(const float4*)(atok + e4);
        } else {
          int p = s_p - 1, ph = p >> 4, pw = p & 15;
          int iq = e4 / 24, jc = e4 - iq * 24;
          vr[q] = *(const float4*)(videos + (long)bt_p * 49152 +
                                   (long)(ph * 8 + iq) * 384 + pw * 24 + jc);
        }
      }
      uint hw[8], lw[8];
#pragma unroll
      for (int q = 0; q < 4; q++) {
        ushort h0,l0,h1,l1,h2,l2,h3,l3;
        split_f16(vr[q].x, h0, l0); split_f16(vr[q].y, h1, l1);
        split_f16(vr[q].z, h2, l2); split_f16(vr[q].w, h3, l3);
        hw[2*q]   = (uint)h0 | ((uint)h1 << 16); lw[2*q]   = (uint)l0 | ((uint)l1 << 16);
        hw[2*q+1] = (uint)h2 | ((uint)h3 << 16); lw[2*q+1] = (uint)l2 | ((uint)l3 << 16);
      }
      *(uint4*)&sAh[(rowa * 4 + (cb0 ^ swa)) * 8]       = make_uint4(hw[0], hw[1], hw[2], hw[3]);
      *(uint4*)&sAh[(rowa * 4 + ((cb0 + 1) ^ swa)) * 8] = make_uint4(hw[4], hw[5], hw[6], hw[7]);
      *(uint4*)&sAl[(rowa * 4 + (cb0 ^ swa)) * 8]       = make_uint4(lw[0], lw[1], lw[2], lw[3]);
      *(uint4*)&sAl[(rowa * 4 + ((cb0 + 1) ^ swa)) * 8] = make_uint4(lw[4], lw[5], lw[6], lw[7]);
      {
#pragma unroll
        for (int i = 0; i < 2; i++) {
          int chunk = tid + 256 * i;
          int row = chunk >> 2, cp = chunk & 3;
          int csrc = cp ^ ((row >> 1) & 3);
          gload16(wtH + (long)(n0 + row) * ldb + k0 + csrc * 8, &sBh[chunk * 8]);
          if (BSPLIT)
            gload16(wtL + (long)(n0 + row) * ldb + k0 + csrc * 8, &sBl[chunk * 8]);
        }
      }
      __syncthreads();
      half8 aHf[TM], aLf[TM];
#pragma unroll
      for (int mi = 0; mi < TM; mi++) {
        int ar = wrb + mi * 16 + lrow;
        int ac = (ar * 4 + (lkg ^ ((ar >> 1) & 3))) * 8;
        aHf[mi] = *(const half8*)&sAh[ac];
        if (ASPLIT) aLf[mi] = *(const half8*)&sAl[ac];
      }
#pragma unroll
      for (int ni = 0; ni < TN; ni++) {
        int br = wcb + ni * 16 + lrow;
        int bc = (br * 4 + (lkg ^ ((br >> 1) & 3))) * 8;
        half8 bH = *(const half8*)&sBh[bc];
#pragma unroll
        for (int mi = 0; mi < TM; mi++) {
          if (ASPLIT)
            acc[mi][ni] = __builtin_amdgcn_mfma_f32_16x16x32_f16(aLf[mi], bH, acc[mi][ni], 0, 0, 0);
        }
        if (BSPLIT) {
          half8 bL = *(const half8*)&sBl[bc];
#pragma unroll
          for (int mi = 0; mi < TM; mi++)
            acc[mi][ni] = __builtin_amdgcn_mfma_f32_16x16x32_f16(aHf[mi], bL, acc[mi][ni], 0, 0, 0);
        }
#pragma unroll
        for (int mi = 0; mi < TM; mi++)
          acc[mi][ni] = __builtin_amdgcn_mfma_f32_16x16x32_f16(aHf[mi], bH, acc[mi][ni], 0, 0, 0);
      }
      __syncthreads();
    }
  }
  // ---- epilogue
#pragma unroll
  for (int mi = 0; mi < TM; mi++) {
    int rowg = m0 + wrb + mi * 16 + lkg * 4;
#pragma unroll
    for (int j = 0; j < 4; j++) {
      int r = rowg + j;
      if (r < M) {
#pragma unroll
        for (int ni = 0; ni < TN; ni++) {
          int cg = n0 + wcb + ni * 16 + lrow;
          float v = acc[mi][ni][j] * WINV;
          if (BIAS) v += bias[cg];
          if (GELU) v = gelu_f(v);
          if (SOUT == 2) {
            coH[(long)r * N + cg] = to_f16u(v);
          } else if (SOUT == 3) {
            if (cg < 1024) coH[(long)r * 1024 + cg] = to_f16u(v);
            else           vOut[(long)r * 512 + (cg - 1024)] = to_f16u(v);
          } else {
            long idx = (long)r * N + cg;
            if (RESID) C[idx] += v; else C[idx] = v;
          }
        }
      }
    }
  }
}

// ---------------- fused flash spatial attention over a chunk PAIR (32 frames).
__global__ __launch_bounds__(256) void flash_spatial(
    const ushort* __restrict__ qk, const ushort* __restrict__ v2,
    ushort* __restrict__ ctxc)
{
  __shared__ __align__(16) ushort sQ[64*72];
  __shared__ __align__(16) ushort sK[64*72];
  __shared__ __align__(16) ushort sV[64*72];               // V^T: [d][k]
  __shared__ __align__(16) ushort sP[64*72];
  const int tid = threadIdx.x;
  const int wid = tid >> 6, lane = tid & 63;
  const int lr = lane & 15, lg = lane >> 4;
  const int fh = blockIdx.y;                  // 0..255 (32 frames x 8 heads)
  const int fl = fh >> 3, hh = fh & 7;
  const int q0 = blockIdx.x * 64;
  const long rbase = (long)fl * S_;
  const int srow = tid >> 2, sc0 = (tid & 3) << 4;

  {
    int gr = q0 + srow;
    uint4 h0 = make_uint4(0,0,0,0), h1 = h0;
    if (gr < S_) {
      const ushort* sh = qk + (rbase + gr) * 1024 + hh * HD_ + sc0;
      h0 = ((const uint4*)sh)[0]; h1 = ((const uint4*)sh)[1];
    }
    uint4* dh = (uint4*)&sQ[srow*72 + sc0];
    dh[0] = h0; dh[1] = h1;
  }
  __syncthreads();
  half8 qH[2];
  {
    int qrl = wid * 16 + lr;
#pragma unroll
    for (int s = 0; s < 2; s++)
      qH[s] = *(const half8*)&sQ[qrl*72 + s*32 + lg*8];
  }
  f32x4 accS[5][4];
#pragma unroll
  for (int t = 0; t < 5; t++)
#pragma unroll
    for (int kc = 0; kc < 4; kc++) accS[t][kc] = (f32x4){0.f,0.f,0.f,0.f};

#pragma unroll
  for (int t = 0; t < 5; t++) {
    __syncthreads();
    {
      int gr = t*64 + srow;
      uint4 h0 = make_uint4(0,0,0,0), h1 = h0;
      if (gr < S_) {
        const ushort* sh = qk + (rbase + gr) * 1024 + 512 + hh * HD_ + sc0;
        h0 = ((const uint4*)sh)[0]; h1 = ((const uint4*)sh)[1];
      }
      uint4* dh = (uint4*)&sK[srow*72 + sc0];
      dh[0] = h0; dh[1] = h1;
    }
    __syncthreads();
#pragma unroll
    for (int s = 0; s < 2; s++) {
#pragma unroll
      for (int kc = 0; kc < 4; kc++) {
        int off = (kc*16 + lr)*72 + s*32 + lg*8;
        half8 bH = *(const half8*)&sK[off];
        accS[t][kc] = __builtin_amdgcn_mfma_f32_16x16x32_f16(qH[s], bH, accS[t][kc], 0,0,0);
      }
    }
  }

  float m[4] = {-3.0e38f, -3.0e38f, -3.0e38f, -3.0e38f};
#pragma unroll
  for (int t = 0; t < 5; t++)
#pragma unroll
    for (int kc = 0; kc < 4; kc++) {
      int kcol = t*64 + kc*16 + lr;
      if (kcol < S_) {
#pragma unroll
        for (int j = 0; j < 4; j++) m[j] = fmaxf(m[j], accS[t][kc][j] * 0.125f);
      }
    }
#pragma unroll
  for (int mk = 8; mk >= 1; mk >>= 1)
#pragma unroll
    for (int j = 0; j < 4; j++) m[j] = fmaxf(m[j], __shfl_xor(m[j], mk));
  float l[4] = {0.f, 0.f, 0.f, 0.f};
#pragma unroll
  for (int t = 0; t < 5; t++)
#pragma unroll
    for (int kc = 0; kc < 4; kc++) {
      int kcol = t*64 + kc*16 + lr;
#pragma unroll
      for (int j = 0; j < 4; j++) {
        float p = (kcol < S_) ? expf(accS[t][kc][j]*0.125f - m[j]) : 0.f;
        accS[t][kc][j] = p;
        l[j] += p;
      }
    }
#pragma unroll
  for (int mk = 8; mk >= 1; mk >>= 1)
#pragma unroll
    for (int j = 0; j < 4; j++) l[j] += __shfl_xor(l[j], mk);

  f32x4 accO[4];
#pragma unroll
  for (int dc = 0; dc < 4; dc++) accO[dc] = (f32x4){0.f,0.f,0.f,0.f};
#pragma unroll
  for (int t = 0; t < 5; t++) {
#pragma unroll
    for (int kc = 0; kc < 4; kc++)
#pragma unroll
      for (int j = 0; j < 4; j++) {
        int addr = (wid*16 + lg*4 + j)*72 + kc*16 + lr;
        sP[addr] = to_f16u(accS[t][kc][j]);
      }
    __syncthreads();
    {
      int gr = t*64 + srow;
      ushort tmp[16];
      uint4 a = make_uint4(0,0,0,0), b = a;
      if (gr < S_) {
        const ushort* src = v2 + (rbase + gr) * 512 + hh * HD_ + sc0;
        a = ((const uint4*)src)[0]; b = ((const uint4*)src)[1];
      }
      *(uint4*)&tmp[0] = a; *(uint4*)&tmp[8] = b;
#pragma unroll
      for (int e = 0; e < 16; e++) sV[(sc0 + e)*72 + srow] = tmp[e];
    }
    __syncthreads();
#pragma unroll
    for (int s = 0; s < 2; s++) {
      int poff = (wid*16 + lr)*72 + s*32 + lg*8;
      half8 pH = *(const half8*)&sP[poff];
#pragma unroll
      for (int dc = 0; dc < 4; dc++) {
        int voff = (dc*16 + lr)*72 + s*32 + lg*8;
        half8 vH = *(const half8*)&sV[voff];
        accO[dc] = __builtin_amdgcn_mfma_f32_16x16x32_f16(pH, vH, accO[dc], 0,0,0);
      }
    }
  }
#pragma unroll
  for (int j = 0; j < 4; j++) {
    int grow = q0 + wid*16 + lg*4 + j;
    if (grow < S_) {
      float inv = 1.0f / l[j];
#pragma unroll
      for (int dc = 0; dc < 4; dc++) {
        float o = accO[dc][j] * inv;
        long idx = (rbase + grow) * 512 + hh*64 + dc*16 + lr;
        ctxc[idx] = to_f16u(o);
      }
    }
  }
}

// ---------------- temporal causal attention over a chunk pair (2 batches), single-f16 qkv
__global__ __launch_bounds__(64) void temporal_attn(
    const ushort* __restrict__ qk, const ushort* __restrict__ v2,
    ushort* __restrict__ ctxc)
{
  const int gid = blockIdx.x;           // b2*2056 + s*8+h
  const int b2 = gid / (S_ * NH_);
  const int rem = gid - b2 * S_ * NH_;
  const int hh = rem & 7;
  const int s = rem >> 3;
  const int lane = threadIdx.x;
  __shared__ float Qs[16][65];
  __shared__ float Ks[16][65];
  __shared__ float Pm[16][17];
  float v[16];
  const long rbase = (long)b2 * CH + s;
#pragma unroll
  for (int t = 0; t < 16; t++) {
    long row = rbase + (long)t * S_;
    long qoff = row * 1024 + hh * HD_ + lane;
    Qs[t][lane] = from_f16u(qk[qoff]);
    Ks[t][lane] = from_f16u(qk[qoff + 512]);
    v[t] = from_f16u(v2[row * 512 + hh * HD_ + lane]);
  }
  __syncthreads();
  const int rq = lane >> 2, c0 = lane & 3;
  float sc[4];
#pragma unroll
  for (int j = 0; j < 4; j++) {
    int c = c0 + (j << 2);
    if (c <= rq) {
      float d = 0.f;
#pragma unroll
      for (int k = 0; k < 64; k++) d = fmaf(Qs[rq][k], Ks[c][k], d);
      sc[j] = d * 0.125f;
    } else sc[j] = -3.0e38f;
  }
  float mx = fmaxf(fmaxf(sc[0], sc[1]), fmaxf(sc[2], sc[3]));
  mx = fmaxf(mx, __shfl_xor(mx, 1));
  mx = fmaxf(mx, __shfl_xor(mx, 2));
  float sum = 0.f;
#pragma unroll
  for (int j = 0; j < 4; j++) { sc[j] = expf(sc[j] - mx); sum += sc[j]; }
  sum += __shfl_xor(sum, 1);
  sum += __shfl_xor(sum, 2);
  float inv = 1.0f / sum;
#pragma unroll
  for (int j = 0; j < 4; j++) Pm[rq][c0 + (j << 2)] = sc[j] * inv;
  __syncthreads();
#pragma unroll
  for (int t = 0; t < 16; t++) {
    float o = 0.f;
#pragma unroll
    for (int k = 0; k < 16; k++) o = fmaf(Pm[t][k], v[k], o);
    long idx = (rbase + (long)t * S_) * 512 + hh * HD_ + lane;
    ctxc[idx] = to_f16u(o);
  }
}

// ---------------- final LN + projection + VQ argmin + action head
__global__ __launch_bounds__(256) void final_vq(
    const float* __restrict__ tok, const float* __restrict__ lnf_g,
    const float* __restrict__ lnf_b, const float* __restrict__ out_w,
    const float* __restrict__ codebook, const float* __restrict__ action_w,
    float* __restrict__ out)
{
  __shared__ float xs[512];
  __shared__ float red[256];
  __shared__ float zs[64];
  __shared__ float bd[256];
  __shared__ int   bi[256];
  const int b = blockIdx.x / 15, tm = blockIdx.x % 15;
  const int tid = threadIdx.x;
  const float* xr = tok + ((long)(b * T_ + tm + 1) * S_) * D_;   // s = 0
  xs[tid] = xr[tid]; xs[tid + 256] = xr[tid + 256];
  red[tid] = xs[tid] + xs[tid + 256];
  __syncthreads();
  for (int off = 128; off >= 1; off >>= 1) {
    if (tid < off) red[tid] += red[tid + off];
    __syncthreads();
  }
  float mean = red[0] * (1.0f / 512.0f);
  __syncthreads();
  float d0 = xs[tid] - mean, d1 = xs[tid + 256] - mean;
  red[tid] = d0 * d0 + d1 * d1;
  __syncthreads();
  for (int off = 128; off >= 1; off >>= 1) {
    if (tid < off) red[tid] += red[tid + off];
    __syncthreads();
  }
  float rs = rsqrtf(red[0] * (1.0f / 512.0f) + 1e-5f);
  __syncthreads();
  xs[tid]       = d0 * rs * lnf_g[tid]       + lnf_b[tid];
  xs[tid + 256] = d1 * rs * lnf_g[tid + 256] + lnf_b[tid + 256];
  __syncthreads();
  if (tid < 64) {
    float z = 0.f;
    for (int d = 0; d < 512; d++) z = fmaf(xs[d], out_w[d * 64 + tid], z);
    zs[tid] = z;
  }
  __syncthreads();
  float best = 3.0e38f; int bidx = 0;
  for (int c = tid; c < 4096; c += 256) {
    const float* cp = codebook + (long)c * 64;
    float dot = 0.f, cn = 0.f;
#pragma unroll 8
    for (int k = 0; k < 64; k++) { float w = cp[k]; dot = fmaf(zs[k], w, dot); cn = fmaf(w, w, cn); }
    float dist = cn - 2.0f * dot;
    if (dist < best) { best = dist; bidx = c; }
  }
  bd[tid] = best; bi[tid] = bidx;
  __syncthreads();
  for (int off = 128; off >= 1; off >>= 1) {
    if (tid < off) {
      if (bd[tid + off] < bd[tid] || (bd[tid + off] == bd[tid] && bi[tid + off] < bi[tid])) {
        bd[tid] = bd[tid + off]; bi[tid] = bi[tid + off];
      }
    }
    __syncthreads();
  }
  int idx = bi[0];
  if (tid < 16) {
    const float* cp = codebook + (long)idx * 64;
    float o = 0.f;
#pragma unroll
    for (int k = 0; k < 64; k++) o = fmaf(cp[k], action_w[k * 16 + tid], o);
    out[((long)(b * 15 + tm)) * 16 + tid] = o;
  }
}

extern "C" void kernel_launch(void* const* d_in, const int* in_sizes, int n_in,
                              void* d_out, int out_size, void* d_ws, size_t ws_size,
                              hipStream_t stream)
{
  const float* videos       = (const float*)d_in[0];
  const float* patch_w      = (const float*)d_in[1];
  const float* patch_b      = (const float*)d_in[2];
  const float* action_token = (const float*)d_in[3];
  const float* ln1_g  = (const float*)d_in[4];
  const float* ln1_b  = (const float*)d_in[5];
  const float* wqkv_s = (const float*)d_in[6];
  const float* wo_s   = (const float*)d_in[7];
  const float* ln2_g  = (const float*)d_in[8];
  const float* ln2_b  = (const float*)d_in[9];
  const float* wqkv_t = (const float*)d_in[10];
  const float* wo_t   = (const float*)d_in[11];
  const float* ln3_g  = (const float*)d_in[12];
  const float* ln3_b  = (const float*)d_in[13];
  const float* mlp_w1 = (const float*)d_in[14];
  const float* mlp_b1 = (const float*)d_in[15];
  const float* mlp_w2 = (const float*)d_in[16];
  const float* mlp_b2 = (const float*)d_in[17];
  const float* lnf_g  = (const float*)d_in[18];
  const float* lnf_b  = (const float*)d_in[19];
  const float* out_w  = (const float*)d_in[20];
  const float* codebook = (const float*)d_in[21];
  const float* action_w = (const float*)d_in[22];
  float* out = (float*)d_out;

  // ---- workspace layout (floats), total 29,466,624 f = 117.9 MB (< proven 135)
  float* ws    = (float*)d_ws;
  float* tok   = ws;                                  // 16,842,752
  ushort* wt1h = (ushort*)(ws + 16842752);            // 1,048,576 f-eq (hi+lo)
  ushort* wt1l = wt1h + 1048576;
  ushort* wt2h = (ushort*)(ws + 17891328);            // 1,048,576 f-eq
  ushort* wt2l = wt2h + 1048576;
  ushort* aH   = (ushort*)(ws + 18939904);            // PCH x 512 single f16 = 2,105,344 f-eq
  ushort* qk   = (ushort*)(ws + 21045248);            // PCH x 1024 single = 4,210,688 f-eq
  ushort* v2   = (ushort*)(ws + 25255936);            // PCH x 512 single  = 2,105,344 f-eq
  ushort* ctx  = (ushort*)(ws + 27361280);            // PCH x 512 single  = 2,105,344 f-eq
  ushort* mid  = qk;                                  // MLP mid (PCH x 2048) spans qk+v2+ctx

  // ---- patchify fused into embed GEMM (full 3-MFMA, legacy path)
  convert_w<<<dim3(3, 8), 256, 0, stream>>>(patch_w, wt1h, wt1l, 512, 192);
  gemm_mfma<128,4,4,1,true,true,true,false,false,0><<<dim3(257, 4), 256, 0, stream>>>(
      nullptr, nullptr, 0, wt1h, wt1l, 192, patch_b, tok, nullptr, nullptr,
      videos, action_token, NTOK, 512, 192);

  for (int L = 0; L < 4; L++) {
    // ================= spatial attention (4 chunk pairs) =================
    convert_w<<<dim3(8, 24), 256, 0, stream>>>(wqkv_s + (long)L*512*1536, wt1h, wt1l, 1536, 512);
    convert_w<<<dim3(8, 8),  256, 0, stream>>>(wo_s   + (long)L*512*512,  wt2h, wt2l, 512, 512);
    for (int pr = 0; pr < 4; pr++) {
      long r0 = (long)pr * PCH;
      ln_single<<<PCH / 4, 256, 0, stream>>>(tok + r0 * D_, ln1_g + L*512, ln1_b + L*512, aH);
      gemm_mfma<128,4,4,0,false,false,false,false,false,3><<<dim3(65, 12), 256, 0, stream>>>(
          aH, nullptr, 512, wt1h, wt1l, 512, nullptr, nullptr,
          qk, v2, nullptr, nullptr, PCH, 1536, 512);
      flash_spatial<<<dim3(5, 256), 256, 0, stream>>>(qk, v2, ctx);
      gemm_mfma<64,2,4,0,false,true,false,false,true,0><<<dim3(65, 8), 256, 0, stream>>>(
          ctx, nullptr, 512, wt2h, wt2l, 512, nullptr, tok + r0 * D_,
          nullptr, nullptr, nullptr, nullptr, PCH, 512, 512);
    }
    // ================= temporal attention (4 chunk pairs) =================
    convert_w<<<dim3(8, 24), 256, 0, stream>>>(wqkv_t + (long)L*512*1536, wt1h, wt1l, 1536, 512);
    convert_w<<<dim3(8, 8),  256, 0, stream>>>(wo_t   + (long)L*512*512,  wt2h, wt2l, 512, 512);
    for (int pr = 0; pr < 4; pr++) {
      long r0 = (long)pr * PCH;
      ln_single<<<PCH / 4, 256, 0, stream>>>(tok + r0 * D_, ln2_g + L*512, ln2_b + L*512, aH);
      gemm_mfma<128,4,4,0,false,false,false,false,false,3><<<dim3(65, 12), 256, 0, stream>>>(
          aH, nullptr, 512, wt1h, wt1l, 512, nullptr, nullptr,
          qk, v2, nullptr, nullptr, PCH, 1536, 512);
      temporal_attn<<<2 * S_ * NH_, 64, 0, stream>>>(qk, v2, ctx);
      gemm_mfma<64,2,4,0,false,true,false,false,true,0><<<dim3(65, 8), 256, 0, stream>>>(
          ctx, nullptr, 512, wt2h, wt2l, 512, nullptr, tok + r0 * D_,
          nullptr, nullptr, nullptr, nullptr, PCH, 512, 512);
    }
    // ================= MLP (4 M-chunks of 8224 rows) =================
    convert_w<<<dim3(8, 32), 256, 0, stream>>>(mlp_w1 + (long)L*512*2048, wt1h, wt1l, 2048, 512);
    convert_w<<<dim3(32, 8), 256, 0, stream>>>(mlp_w2 + (long)L*2048*512, wt2h, wt2l, 512, 2048);
    for (int c = 0; c < 4; c++) {
      long m0r = (long)c * PCH;
      ln_single<<<PCH / 4, 256, 0, stream>>>(tok + m0r * D_, ln3_g + L*512, ln3_b + L*512, aH);
      gemm_mfma<128,4,4,0,false,false,true,true,false,2><<<dim3(65, 16), 256, 0, stream>>>(
          aH, nullptr, 512, wt1h, wt1l, 512, mlp_b1 + (long)L*2048, nullptr, mid, nullptr,
          nullptr, nullptr, PCH, FFN_, 512);
      gemm_mfma<64,2,4,0,false,true,true,false,true,0><<<dim3(65, 8), 256, 0, stream>>>(
          mid, nullptr, 2048, wt2h, wt2l, 2048, mlp_b2 + (long)L*512, tok + m0r * D_,
          nullptr, nullptr, nullptr, nullptr, PCH, 512, 2048);
    }
  }

  final_vq<<<B_ * (T_ - 1), 256, 0, stream>>>(tok, lnf_g, lnf_b, out_w, codebook, action_w, out);
}

// Round 24
// 4269.173 us; speedup vs baseline: 1.1417x; 1.0562x over previous
//
#include <hip/hip_runtime.h>
#include <hip/hip_bf16.h>

#define B_ 8
#define T_ 16
#define S_ 257
#define D_ 512
#define FFN_ 2048
#define NH_ 8
#define HD_ 64
#define PTD_ 192
#define NTOK (B_*T_*S_)        // 32896
#define CH 4112                // 16 frames * 257 rows per chunk
#define PCH 8224               // chunk pair rows
#define WSCALE 64.0f
#define WINV 0.015625f

typedef unsigned int uint;
typedef unsigned short ushort;
typedef __attribute__((ext_vector_type(8))) _Float16 half8;
typedef __attribute__((ext_vector_type(4))) float f32x4;

__device__ __forceinline__ float warp_rsum(float v){
#pragma unroll
  for (int m = 32; m >= 1; m >>= 1) v += __shfl_xor(v, m);
  return v;
}
__device__ __forceinline__ float gelu_f(float x){
  float x3 = x*x*x;
  return 0.5f*x*(1.0f + tanhf(0.7978845608028654f*(x + 0.044715f*x3)));
}
// split fp32 -> f16 hi + f16 lo (RNE).
__device__ __forceinline__ void split_f16(float f, ushort& h, ushort& l){
  _Float16 hh = (_Float16)f;
  float hf = (float)hh;
  _Float16 ll = (_Float16)(f - hf);
  h = __builtin_bit_cast(ushort, hh);
  l = __builtin_bit_cast(ushort, ll);
}
__device__ __forceinline__ ushort to_f16u(float f){
  return __builtin_bit_cast(ushort, (_Float16)f);
}
__device__ __forceinline__ float from_f16u(ushort u){
  return (float)__builtin_bit_cast(_Float16, u);
}
// async global->LDS 16B (lane-linear LDS dest, per-lane global src)
__device__ __forceinline__ void gload16(const ushort* g, ushort* l){
  __builtin_amdgcn_global_load_lds(
      (const __attribute__((address_space(1))) void*)(g),
      (__attribute__((address_space(3))) void*)(l),
      16, 0, 0);
}

// ---------------- fused LN + single-f16 cast:  aH[row][512] = f16(LN(x[row]))
__global__ __launch_bounds__(256) void ln_single(
    const float* __restrict__ x, const float* __restrict__ g,
    const float* __restrict__ bb, ushort* __restrict__ aH)
{
  int row = blockIdx.x * 4 + (threadIdx.x >> 6);
  int lane = threadIdx.x & 63;
  const float* xr = x + (long)row * D_;
  float4 u0 = *(const float4*)(xr + lane * 8);
  float4 u1 = *(const float4*)(xr + lane * 8 + 4);
  float s = u0.x + u0.y + u0.z + u0.w + u1.x + u1.y + u1.z + u1.w;
  s = warp_rsum(s);
  float mean = s * (1.0f / 512.0f);
  float d[8] = {u0.x - mean, u0.y - mean, u0.z - mean, u0.w - mean,
                u1.x - mean, u1.y - mean, u1.z - mean, u1.w - mean};
  float ss = 0.f;
#pragma unroll
  for (int i = 0; i < 8; i++) ss = fmaf(d[i], d[i], ss);
  ss = warp_rsum(ss);
  float rstd = rsqrtf(ss * (1.0f / 512.0f) + 1e-5f);
  int c = lane * 8;
  float4 g0 = *(const float4*)(g + c), g1 = *(const float4*)(g + c + 4);
  float4 b0 = *(const float4*)(bb + c), b1 = *(const float4*)(bb + c + 4);
  float y[8] = {d[0]*rstd*g0.x + b0.x, d[1]*rstd*g0.y + b0.y,
                d[2]*rstd*g0.z + b0.z, d[3]*rstd*g0.w + b0.w,
                d[4]*rstd*g1.x + b1.x, d[5]*rstd*g1.y + b1.y,
                d[6]*rstd*g1.z + b1.z, d[7]*rstd*g1.w + b1.w};
  ushort h[8];
#pragma unroll
  for (int i = 0; i < 8; i++) h[i] = to_f16u(y[i]);
  uint4 hv = make_uint4((uint)h[0] | ((uint)h[1] << 16), (uint)h[2] | ((uint)h[3] << 16),
                        (uint)h[4] | ((uint)h[5] << 16), (uint)h[6] | ((uint)h[7] << 16));
  *(uint4*)(aH + (long)row * 512 + c) = hv;
}

// ---------------- weight transpose + split:  W[K][N] f32 -> (W*64) as Whi[N][K], Wlo[N][K] f16
__global__ __launch_bounds__(256) void convert_w(
    const float* __restrict__ W, ushort* __restrict__ Whi, ushort* __restrict__ Wlo,
    int N, int K)
{
  __shared__ float Tt[64][65];
  const int tid = threadIdx.x;
  const int k0 = blockIdx.x << 6, n0 = blockIdx.y << 6;
  {
    int kk = tid >> 2, nb = (tid & 3) << 4;
#pragma unroll
    for (int q = 0; q < 4; q++) {
      float4 v = *(const float4*)(W + (long)(k0 + kk) * N + n0 + nb + 4 * q);
      Tt[kk][nb + 4*q + 0] = v.x; Tt[kk][nb + 4*q + 1] = v.y;
      Tt[kk][nb + 4*q + 2] = v.z; Tt[kk][nb + 4*q + 3] = v.w;
    }
  }
  __syncthreads();
  {
    int nn = tid >> 2, kb = (tid & 3) << 4;
    uint hw[8], lw[8];
#pragma unroll
    for (int q = 0; q < 8; q++) {
      float a = Tt[kb + 2*q][nn] * WSCALE, b = Tt[kb + 2*q + 1][nn] * WSCALE;
      ushort ha, la, hb, lb;
      split_f16(a, ha, la); split_f16(b, hb, lb);
      hw[q] = (uint)ha | ((uint)hb << 16); lw[q] = (uint)la | ((uint)lb << 16);
    }
    ushort* dh = Whi + (long)(n0 + nn) * K + k0 + kb;
    ushort* dl = Wlo + (long)(n0 + nn) * K + k0 + kb;
    ((uint4*)dh)[0] = make_uint4(hw[0], hw[1], hw[2], hw[3]);
    ((uint4*)dh)[1] = make_uint4(hw[4], hw[5], hw[6], hw[7]);
    ((uint4*)dl)[0] = make_uint4(lw[0], lw[1], lw[2], lw[3]);
    ((uint4*)dl)[1] = make_uint4(lw[4], lw[5], lw[6], lw[7]);
  }
}

// ---------------- split-f16 MFMA GEMM.
// AMODE 0: BM=128, BK=32, 256 threads, 2-deep gload_lds pipeline with EARLY second
//          barrier: {vmcnt(LPS); bar; ds_read frags -> regs; lgkmcnt(0); bar;
//          stage(t+2 into freed buf); MFMA on regs}.  XCD-chunked bijective remap.
//          LPS = loads/thread/stage: BN=128 -> 4; BN=64 BSPLIT -> 4; BN=64 single -> 3.
// AMODE 1: BM=128, fused patchify (legacy single-buffer, pitch-32 layout).
// LDS per buffer: [rows][4 chunks of 16B], phys chunk = c ^ ((row>>1)&3), pitch 32.
// SOUT 0: fp32 C (opt RESID).  2: single-f16 out.  3: qkv single-f16 out.
template<int BN, int TM, int TN, int AMODE, bool ASPLIT, bool BSPLIT, bool BIAS, bool GELU, bool RESID, int SOUT>
__global__ __launch_bounds__(256) void gemm_mfma(
    const ushort* __restrict__ aHp, const ushort* __restrict__ aLp, int lda,
    const ushort* __restrict__ wtH, const ushort* __restrict__ wtL, int ldb,
    const float* __restrict__ bias, float* __restrict__ C,
    ushort* __restrict__ coH, ushort* __restrict__ vOut,
    const float* __restrict__ videos, const float* __restrict__ atok,
    int M, int N, int K)
{
  constexpr int NWC = BN / (TN * 16);
  constexpr int NBUF = (AMODE == 0) ? 2 : 1;
  __shared__ __align__(16) ushort sAh[NBUF * 128 * 32];
  __shared__ __align__(16) ushort sAl[(AMODE == 1) ? 128 * 32 : 8];
  __shared__ __align__(16) ushort sBh[NBUF * BN * 32];
  __shared__ __align__(16) ushort sBl[BSPLIT ? NBUF * BN * 32 : 8];
  const int tid = threadIdx.x;
  int m0, n0;
  if (AMODE == 0) {
    // bijective XCD-chunked remap (m204): o%8 = XCD under round-robin dispatch
    const int gx = gridDim.x, gy = gridDim.y;
    const int nwg = gx * gy;
    const int o = blockIdx.y * gx + blockIdx.x;
    const int q = nwg >> 3, r = nwg & 7;
    const int xcd = o & 7, idx = o >> 3;
    const int wgid = (xcd < r ? xcd * (q + 1) : r * (q + 1) + (xcd - r) * q) + idx;
    const int mi = wgid / gy, ni = wgid - mi * gy;
    m0 = mi * 128; n0 = ni * BN;
  } else {
    m0 = blockIdx.x * 128; n0 = blockIdx.y * BN;
  }
  const int wid = tid >> 6, lane = tid & 63;
  const int lrow = lane & 15, lkg = lane >> 4;
  const int wr = wid / NWC, wc = wid % NWC;
  const int wrb = wr * TM * 16, wcb = wc * TN * 16;
  f32x4 acc[TM][TN];
#pragma unroll
  for (int mi = 0; mi < TM; mi++)
#pragma unroll
    for (int ni = 0; ni < TN; ni++) acc[mi][ni] = (f32x4){0.f, 0.f, 0.f, 0.f};

  if (AMODE == 0) {
    // ---- 2-deep pipeline, early-barrier register-fragment consume
    const int chunkA0 = tid, chunkA1 = tid + 256;
    auto stage = [&](int k0, int d) {
      {
        int row = chunkA0 >> 2, cp = chunkA0 & 3;
        int csrc = cp ^ ((row >> 1) & 3);
        int ar = m0 + row; if (ar > M - 1) ar = M - 1;
        gload16(aHp + (long)ar * lda + k0 + csrc * 8, &sAh[d * 4096 + chunkA0 * 8]);
      }
      {
        int row = chunkA1 >> 2, cp = chunkA1 & 3;
        int csrc = cp ^ ((row >> 1) & 3);
        int ar = m0 + row; if (ar > M - 1) ar = M - 1;
        gload16(aHp + (long)ar * lda + k0 + csrc * 8, &sAh[d * 4096 + chunkA1 * 8]);
      }
      if (BN == 128) {
#pragma unroll
        for (int i = 0; i < 2; i++) {
          int chunk = tid + 256 * i;
          int row = chunk >> 2, cp = chunk & 3;
          int csrc = cp ^ ((row >> 1) & 3);
          gload16(wtH + (long)(n0 + row) * ldb + k0 + csrc * 8, &sBh[d * 4096 + chunk * 8]);
        }
      } else {
        int chunk = tid;
        int row = chunk >> 2, cp = chunk & 3;
        int csrc = cp ^ ((row >> 1) & 3);
        gload16(wtH + (long)(n0 + row) * ldb + k0 + csrc * 8, &sBh[d * 2048 + chunk * 8]);
        if (BSPLIT)
          gload16(wtL + (long)(n0 + row) * ldb + k0 + csrc * 8, &sBl[d * 2048 + chunk * 8]);
      }
    };
    const int nt = K >> 5;
    stage(0, 0);
    if (nt > 1) stage(32, 1);
    for (int t = 0; t < nt; t++) {
      const int cur = t & 1;
      if (t + 1 < nt) {
        if constexpr (BN == 128 || BSPLIT) {
          asm volatile("s_waitcnt vmcnt(4)" ::: "memory");
        } else {
          asm volatile("s_waitcnt vmcnt(3)" ::: "memory");
        }
      } else {
        asm volatile("s_waitcnt vmcnt(0)" ::: "memory");
      }
      __builtin_amdgcn_s_barrier();
      const int aBase = cur * 4096;
      const int bBase = cur * ((BN == 128) ? 4096 : 2048);
      // ---- read all fragments into registers
      half8 aHf[TM], bHf[TN], bLf[BSPLIT ? TN : 1];
#pragma unroll
      for (int mi = 0; mi < TM; mi++) {
        int ar = wrb + mi * 16 + lrow;
        int ac = (ar * 4 + (lkg ^ ((ar >> 1) & 3))) * 8;
        aHf[mi] = *(const half8*)&sAh[aBase + ac];
      }
#pragma unroll
      for (int ni = 0; ni < TN; ni++) {
        int br = wcb + ni * 16 + lrow;
        int bc = (br * 4 + (lkg ^ ((br >> 1) & 3))) * 8;
        bHf[ni] = *(const half8*)&sBh[bBase + bc];
        if (BSPLIT) bLf[ni] = *(const half8*)&sBl[bBase + bc];
      }
      asm volatile("s_waitcnt lgkmcnt(0)" ::: "memory");
      __builtin_amdgcn_sched_barrier(0);
      __builtin_amdgcn_s_barrier();
      // ---- buffer freed: issue tile t+2 into it NOW (2-iteration issue distance)
      if (t + 2 < nt) stage((t + 2) << 5, cur);
      // ---- MFMA purely on registers (overlaps the in-flight loads)
      __builtin_amdgcn_s_setprio(1);
#pragma unroll
      for (int ni = 0; ni < TN; ni++) {
        if (BSPLIT) {
#pragma unroll
          for (int mi = 0; mi < TM; mi++)
            acc[mi][ni] = __builtin_amdgcn_mfma_f32_16x16x32_f16(aHf[mi], bLf[ni], acc[mi][ni], 0, 0, 0);
        }
#pragma unroll
        for (int mi = 0; mi < TM; mi++)
          acc[mi][ni] = __builtin_amdgcn_mfma_f32_16x16x32_f16(aHf[mi], bHf[ni], acc[mi][ni], 0, 0, 0);
      }
      __builtin_amdgcn_s_setprio(0);
      __builtin_amdgcn_sched_barrier(0);
    }
  } else {
    // ---- legacy single-buffer path (fused patchify embed GEMM)
    const int rowa = tid >> 1, kba = (tid & 1) << 4;
    const int cb0 = (tid & 1) * 2;
    const int swa = (rowa >> 1) & 3;
    int bt_p = 0, s_p = 0;
    { int ar = m0 + rowa; bt_p = ar / 257; s_p = ar - bt_p * 257; }
    for (int k0 = 0; k0 < K; k0 += 32) {
      float4 vr[4];
#pragma unroll
      for (int q = 0; q < 4; q++) vr[q] = make_float4(0.f, 0.f, 0.f, 0.f);
#pragma unroll
      for (int q = 0; q < 4; q++) {
        int e4 = k0 + kba + 4 * q;
        if (s_p == 0) {
          vr[q] = *(const float4*)(atok + e4);
        } else {
          int p = s_p - 1, ph = p >> 4, pw = p & 15;
          int iq = e4 / 24, jc = e4 - iq * 24;
          vr[q] = *(const float4*)(videos + (long)bt_p * 49152 +
                                   (long)(ph * 8 + iq) * 384 + pw * 24 + jc);
        }
      }
      uint hw[8], lw[8];
#pragma unroll
      for (int q = 0; q < 4; q++) {
        ushort h0,l0,h1,l1,h2,l2,h3,l3;
        split_f16(vr[q].x, h0, l0); split_f16(vr[q].y, h1, l1);
        split_f16(vr[q].z, h2, l2); split_f16(vr[q].w, h3, l3);
        hw[2*q]   = (uint)h0 | ((uint)h1 << 16); lw[2*q]   = (uint)l0 | ((uint)l1 << 16);
        hw[2*q+1] = (uint)h2 | ((uint)h3 << 16); lw[2*q+1] = (uint)l2 | ((uint)l3 << 16);
      }
      *(uint4*)&sAh[(rowa * 4 + (cb0 ^ swa)) * 8]       = make_uint4(hw[0], hw[1], hw[2], hw[3]);
      *(uint4*)&sAh[(rowa * 4 + ((cb0 + 1) ^ swa)) * 8] = make_uint4(hw[4], hw[5], hw[6], hw[7]);
      *(uint4*)&sAl[(rowa * 4 + (cb0 ^ swa)) * 8]       = make_uint4(lw[0], lw[1], lw[2], lw[3]);
      *(uint4*)&sAl[(rowa * 4 + ((cb0 + 1) ^ swa)) * 8] = make_uint4(lw[4], lw[5], lw[6], lw[7]);
      {
#pragma unroll
        for (int i = 0; i < 2; i++) {
          int chunk = tid + 256 * i;
          int row = chunk >> 2, cp = chunk & 3;
          int csrc = cp ^ ((row >> 1) & 3);
          gload16(wtH + (long)(n0 + row) * ldb + k0 + csrc * 8, &sBh[chunk * 8]);
          if (BSPLIT)
            gload16(wtL + (long)(n0 + row) * ldb + k0 + csrc * 8, &sBl[chunk * 8]);
        }
      }
      __syncthreads();
      half8 aHf[TM], aLf[TM];
#pragma unroll
      for (int mi = 0; mi < TM; mi++) {
        int ar = wrb + mi * 16 + lrow;
        int ac = (ar * 4 + (lkg ^ ((ar >> 1) & 3))) * 8;
        aHf[mi] = *(const half8*)&sAh[ac];
        if (ASPLIT) aLf[mi] = *(const half8*)&sAl[ac];
      }
#pragma unroll
      for (int ni = 0; ni < TN; ni++) {
        int br = wcb + ni * 16 + lrow;
        int bc = (br * 4 + (lkg ^ ((br >> 1) & 3))) * 8;
        half8 bH = *(const half8*)&sBh[bc];
#pragma unroll
        for (int mi = 0; mi < TM; mi++) {
          if (ASPLIT)
            acc[mi][ni] = __builtin_amdgcn_mfma_f32_16x16x32_f16(aLf[mi], bH, acc[mi][ni], 0, 0, 0);
        }
        if (BSPLIT) {
          half8 bL = *(const half8*)&sBl[bc];
#pragma unroll
          for (int mi = 0; mi < TM; mi++)
            acc[mi][ni] = __builtin_amdgcn_mfma_f32_16x16x32_f16(aHf[mi], bL, acc[mi][ni], 0, 0, 0);
        }
#pragma unroll
        for (int mi = 0; mi < TM; mi++)
          acc[mi][ni] = __builtin_amdgcn_mfma_f32_16x16x32_f16(aHf[mi], bH, acc[mi][ni], 0, 0, 0);
      }
      __syncthreads();
    }
  }
  // ---- epilogue
#pragma unroll
  for (int mi = 0; mi < TM; mi++) {
    int rowg = m0 + wrb + mi * 16 + lkg * 4;
#pragma unroll
    for (int j = 0; j < 4; j++) {
      int r = rowg + j;
      if (r < M) {
#pragma unroll
        for (int ni = 0; ni < TN; ni++) {
          int cg = n0 + wcb + ni * 16 + lrow;
          float v = acc[mi][ni][j] * WINV;
          if (BIAS) v += bias[cg];
          if (GELU) v = gelu_f(v);
          if (SOUT == 2) {
            coH[(long)r * N + cg] = to_f16u(v);
          } else if (SOUT == 3) {
            if (cg < 1024) coH[(long)r * 1024 + cg] = to_f16u(v);
            else           vOut[(long)r * 512 + (cg - 1024)] = to_f16u(v);
          } else {
            long idx = (long)r * N + cg;
            if (RESID) C[idx] += v; else C[idx] = v;
          }
        }
      }
    }
  }
}

// ---------------- fused flash spatial attention over a chunk PAIR (32 frames).
__global__ __launch_bounds__(256) void flash_spatial(
    const ushort* __restrict__ qk, const ushort* __restrict__ v2,
    ushort* __restrict__ ctxc)
{
  __shared__ __align__(16) ushort sQ[64*72];
  __shared__ __align__(16) ushort sK[64*72];
  __shared__ __align__(16) ushort sV[64*72];               // V^T: [d][k]
  __shared__ __align__(16) ushort sP[64*72];
  const int tid = threadIdx.x;
  const int wid = tid >> 6, lane = tid & 63;
  const int lr = lane & 15, lg = lane >> 4;
  const int fh = blockIdx.y;                  // 0..255 (32 frames x 8 heads)
  const int fl = fh >> 3, hh = fh & 7;
  const int q0 = blockIdx.x * 64;
  const long rbase = (long)fl * S_;
  const int srow = tid >> 2, sc0 = (tid & 3) << 4;

  {
    int gr = q0 + srow;
    uint4 h0 = make_uint4(0,0,0,0), h1 = h0;
    if (gr < S_) {
      const ushort* sh = qk + (rbase + gr) * 1024 + hh * HD_ + sc0;
      h0 = ((const uint4*)sh)[0]; h1 = ((const uint4*)sh)[1];
    }
    uint4* dh = (uint4*)&sQ[srow*72 + sc0];
    dh[0] = h0; dh[1] = h1;
  }
  __syncthreads();
  half8 qH[2];
  {
    int qrl = wid * 16 + lr;
#pragma unroll
    for (int s = 0; s < 2; s++)
      qH[s] = *(const half8*)&sQ[qrl*72 + s*32 + lg*8];
  }
  f32x4 accS[5][4];
#pragma unroll
  for (int t = 0; t < 5; t++)
#pragma unroll
    for (int kc = 0; kc < 4; kc++) accS[t][kc] = (f32x4){0.f,0.f,0.f,0.f};

#pragma unroll
  for (int t = 0; t < 5; t++) {
    __syncthreads();
    {
      int gr = t*64 + srow;
      uint4 h0 = make_uint4(0,0,0,0), h1 = h0;
      if (gr < S_) {
        const ushort* sh = qk + (rbase + gr) * 1024 + 512 + hh * HD_ + sc0;
        h0 = ((const uint4*)sh)[0]; h1 = ((const uint4*)sh)[1];
      }
      uint4* dh = (uint4*)&sK[srow*72 + sc0];
      dh[0] = h0; dh[1] = h1;
    }
    __syncthreads();
#pragma unroll
    for (int s = 0; s < 2; s++) {
#pragma unroll
      for (int kc = 0; kc < 4; kc++) {
        int off = (kc*16 + lr)*72 + s*32 + lg*8;
        half8 bH = *(const half8*)&sK[off];
        accS[t][kc] = __builtin_amdgcn_mfma_f32_16x16x32_f16(qH[s], bH, accS[t][kc], 0,0,0);
      }
    }
  }

  float m[4] = {-3.0e38f, -3.0e38f, -3.0e38f, -3.0e38f};
#pragma unroll
  for (int t = 0; t < 5; t++)
#pragma unroll
    for (int kc = 0; kc < 4; kc++) {
      int kcol = t*64 + kc*16 + lr;
      if (kcol < S_) {
#pragma unroll
        for (int j = 0; j < 4; j++) m[j] = fmaxf(m[j], accS[t][kc][j] * 0.125f);
      }
    }
#pragma unroll
  for (int mk = 8; mk >= 1; mk >>= 1)
#pragma unroll
    for (int j = 0; j < 4; j++) m[j] = fmaxf(m[j], __shfl_xor(m[j], mk));
  float l[4] = {0.f, 0.f, 0.f, 0.f};
#pragma unroll
  for (int t = 0; t < 5; t++)
#pragma unroll
    for (int kc = 0; kc < 4; kc++) {
      int kcol = t*64 + kc*16 + lr;
#pragma unroll
      for (int j = 0; j < 4; j++) {
        float p = (kcol < S_) ? expf(accS[t][kc][j]*0.125f - m[j]) : 0.f;
        accS[t][kc][j] = p;
        l[j] += p;
      }
    }
#pragma unroll
  for (int mk = 8; mk >= 1; mk >>= 1)
#pragma unroll
    for (int j = 0; j < 4; j++) l[j] += __shfl_xor(l[j], mk);

  f32x4 accO[4];
#pragma unroll
  for (int dc = 0; dc < 4; dc++) accO[dc] = (f32x4){0.f,0.f,0.f,0.f};
#pragma unroll
  for (int t = 0; t < 5; t++) {
#pragma unroll
    for (int kc = 0; kc < 4; kc++)
#pragma unroll
      for (int j = 0; j < 4; j++) {
        int addr = (wid*16 + lg*4 + j)*72 + kc*16 + lr;
        sP[addr] = to_f16u(accS[t][kc][j]);
      }
    __syncthreads();
    {
      int gr = t*64 + srow;
      ushort tmp[16];
      uint4 a = make_uint4(0,0,0,0), b = a;
      if (gr < S_) {
        const ushort* src = v2 + (rbase + gr) * 512 + hh * HD_ + sc0;
        a = ((const uint4*)src)[0]; b = ((const uint4*)src)[1];
      }
      *(uint4*)&tmp[0] = a; *(uint4*)&tmp[8] = b;
#pragma unroll
      for (int e = 0; e < 16; e++) sV[(sc0 + e)*72 + srow] = tmp[e];
    }
    __syncthreads();
#pragma unroll
    for (int s = 0; s < 2; s++) {
      int poff = (wid*16 + lr)*72 + s*32 + lg*8;
      half8 pH = *(const half8*)&sP[poff];
#pragma unroll
      for (int dc = 0; dc < 4; dc++) {
        int voff = (dc*16 + lr)*72 + s*32 + lg*8;
        half8 vH = *(const half8*)&sV[voff];
        accO[dc] = __builtin_amdgcn_mfma_f32_16x16x32_f16(pH, vH, accO[dc], 0,0,0);
      }
    }
  }
#pragma unroll
  for (int j = 0; j < 4; j++) {
    int grow = q0 + wid*16 + lg*4 + j;
    if (grow < S_) {
      float inv = 1.0f / l[j];
#pragma unroll
      for (int dc = 0; dc < 4; dc++) {
        float o = accO[dc][j] * inv;
        long idx = (rbase + grow) * 512 + hh*64 + dc*16 + lr;
        ctxc[idx] = to_f16u(o);
      }
    }
  }
}

// ---------------- temporal causal attention over a chunk pair (2 batches), single-f16 qkv
__global__ __launch_bounds__(64) void temporal_attn(
    const ushort* __restrict__ qk, const ushort* __restrict__ v2,
    ushort* __restrict__ ctxc)
{
  const int gid = blockIdx.x;           // b2*2056 + s*8+h
  const int b2 = gid / (S_ * NH_);
  const int rem = gid - b2 * S_ * NH_;
  const int hh = rem & 7;
  const int s = rem >> 3;
  const int lane = threadIdx.x;
  __shared__ float Qs[16][65];
  __shared__ float Ks[16][65];
  __shared__ float Pm[16][17];
  float v[16];
  const long rbase = (long)b2 * CH + s;
#pragma unroll
  for (int t = 0; t < 16; t++) {
    long row = rbase + (long)t * S_;
    long qoff = row * 1024 + hh * HD_ + lane;
    Qs[t][lane] = from_f16u(qk[qoff]);
    Ks[t][lane] = from_f16u(qk[qoff + 512]);
    v[t] = from_f16u(v2[row * 512 + hh * HD_ + lane]);
  }
  __syncthreads();
  const int rq = lane >> 2, c0 = lane & 3;
  float sc[4];
#pragma unroll
  for (int j = 0; j < 4; j++) {
    int c = c0 + (j << 2);
    if (c <= rq) {
      float d = 0.f;
#pragma unroll
      for (int k = 0; k < 64; k++) d = fmaf(Qs[rq][k], Ks[c][k], d);
      sc[j] = d * 0.125f;
    } else sc[j] = -3.0e38f;
  }
  float mx = fmaxf(fmaxf(sc[0], sc[1]), fmaxf(sc[2], sc[3]));
  mx = fmaxf(mx, __shfl_xor(mx, 1));
  mx = fmaxf(mx, __shfl_xor(mx, 2));
  float sum = 0.f;
#pragma unroll
  for (int j = 0; j < 4; j++) { sc[j] = expf(sc[j] - mx); sum += sc[j]; }
  sum += __shfl_xor(sum, 1);
  sum += __shfl_xor(sum, 2);
  float inv = 1.0f / sum;
#pragma unroll
  for (int j = 0; j < 4; j++) Pm[rq][c0 + (j << 2)] = sc[j] * inv;
  __syncthreads();
#pragma unroll
  for (int t = 0; t < 16; t++) {
    float o = 0.f;
#pragma unroll
    for (int k = 0; k < 16; k++) o = fmaf(Pm[t][k], v[k], o);
    long idx = (rbase + (long)t * S_) * 512 + hh * HD_ + lane;
    ctxc[idx] = to_f16u(o);
  }
}

// ---------------- final LN + projection + VQ argmin + action head
__global__ __launch_bounds__(256) void final_vq(
    const float* __restrict__ tok, const float* __restrict__ lnf_g,
    const float* __restrict__ lnf_b, const float* __restrict__ out_w,
    const float* __restrict__ codebook, const float* __restrict__ action_w,
    float* __restrict__ out)
{
  __shared__ float xs[512];
  __shared__ float red[256];
  __shared__ float zs[64];
  __shared__ float bd[256];
  __shared__ int   bi[256];
  const int b = blockIdx.x / 15, tm = blockIdx.x % 15;
  const int tid = threadIdx.x;
  const float* xr = tok + ((long)(b * T_ + tm + 1) * S_) * D_;   // s = 0
  xs[tid] = xr[tid]; xs[tid + 256] = xr[tid + 256];
  red[tid] = xs[tid] + xs[tid + 256];
  __syncthreads();
  for (int off = 128; off >= 1; off >>= 1) {
    if (tid < off) red[tid] += red[tid + off];
    __syncthreads();
  }
  float mean = red[0] * (1.0f / 512.0f);
  __syncthreads();
  float d0 = xs[tid] - mean, d1 = xs[tid + 256] - mean;
  red[tid] = d0 * d0 + d1 * d1;
  __syncthreads();
  for (int off = 128; off >= 1; off >>= 1) {
    if (tid < off) red[tid] += red[tid + off];
    __syncthreads();
  }
  float rs = rsqrtf(red[0] * (1.0f / 512.0f) + 1e-5f);
  __syncthreads();
  xs[tid]       = d0 * rs * lnf_g[tid]       + lnf_b[tid];
  xs[tid + 256] = d1 * rs * lnf_g[tid + 256] + lnf_b[tid + 256];
  __syncthreads();
  if (tid < 64) {
    float z = 0.f;
    for (int d = 0; d < 512; d++) z = fmaf(xs[d], out_w[d * 64 + tid], z);
    zs[tid] = z;
  }
  __syncthreads();
  float best = 3.0e38f; int bidx = 0;
  for (int c = tid; c < 4096; c += 256) {
    const float* cp = codebook + (long)c * 64;
    float dot = 0.f, cn = 0.f;
#pragma unroll 8
    for (int k = 0; k < 64; k++) { float w = cp[k]; dot = fmaf(zs[k], w, dot); cn = fmaf(w, w, cn); }
    float dist = cn - 2.0f * dot;
    if (dist < best) { best = dist; bidx = c; }
  }
  bd[tid] = best; bi[tid] = bidx;
  __syncthreads();
  for (int off = 128; off >= 1; off >>= 1) {
    if (tid < off) {
      if (bd[tid + off] < bd[tid] || (bd[tid + off] == bd[tid] && bi[tid + off] < bi[tid])) {
        bd[tid] = bd[tid + off]; bi[tid] = bi[tid + off];
      }
    }
    __syncthreads();
  }
  int idx = bi[0];
  if (tid < 16) {
    const float* cp = codebook + (long)idx * 64;
    float o = 0.f;
#pragma unroll
    for (int k = 0; k < 64; k++) o = fmaf(cp[k], action_w[k * 16 + tid], o);
    out[((long)(b * 15 + tm)) * 16 + tid] = o;
  }
}

extern "C" void kernel_launch(void* const* d_in, const int* in_sizes, int n_in,
                              void* d_out, int out_size, void* d_ws, size_t ws_size,
                              hipStream_t stream)
{
  const float* videos       = (const float*)d_in[0];
  const float* patch_w      = (const float*)d_in[1];
  const float* patch_b      = (const float*)d_in[2];
  const float* action_token = (const float*)d_in[3];
  const float* ln1_g  = (const float*)d_in[4];
  const float* ln1_b  = (const float*)d_in[5];
  const float* wqkv_s = (const float*)d_in[6];
  const float* wo_s   = (const float*)d_in[7];
  const float* ln2_g  = (const float*)d_in[8];
  const float* ln2_b  = (const float*)d_in[9];
  const float* wqkv_t = (const float*)d_in[10];
  const float* wo_t   = (const float*)d_in[11];
  const float* ln3_g  = (const float*)d_in[12];
  const float* ln3_b  = (const float*)d_in[13];
  const float* mlp_w1 = (const float*)d_in[14];
  const float* mlp_b1 = (const float*)d_in[15];
  const float* mlp_w2 = (const float*)d_in[16];
  const float* mlp_b2 = (const float*)d_in[17];
  const float* lnf_g  = (const float*)d_in[18];
  const float* lnf_b  = (const float*)d_in[19];
  const float* out_w  = (const float*)d_in[20];
  const float* codebook = (const float*)d_in[21];
  const float* action_w = (const float*)d_in[22];
  float* out = (float*)d_out;

  // ---- workspace layout (floats), total 29,466,624 f = 117.9 MB (< proven 135)
  float* ws    = (float*)d_ws;
  float* tok   = ws;                                  // 16,842,752
  ushort* wt1h = (ushort*)(ws + 16842752);            // 1,048,576 f-eq (hi+lo)
  ushort* wt1l = wt1h + 1048576;
  ushort* wt2h = (ushort*)(ws + 17891328);            // 1,048,576 f-eq
  ushort* wt2l = wt2h + 1048576;
  ushort* aH   = (ushort*)(ws + 18939904);            // PCH x 512 single f16 = 2,105,344 f-eq
  ushort* qk   = (ushort*)(ws + 21045248);            // PCH x 1024 single = 4,210,688 f-eq
  ushort* v2   = (ushort*)(ws + 25255936);            // PCH x 512 single  = 2,105,344 f-eq
  ushort* ctx  = (ushort*)(ws + 27361280);            // PCH x 512 single  = 2,105,344 f-eq
  ushort* mid  = qk;                                  // MLP mid (PCH x 2048) spans qk+v2+ctx

  // ---- patchify fused into embed GEMM (full 3-MFMA, legacy path)
  convert_w<<<dim3(3, 8), 256, 0, stream>>>(patch_w, wt1h, wt1l, 512, 192);
  gemm_mfma<128,4,4,1,true,true,true,false,false,0><<<dim3(257, 4), 256, 0, stream>>>(
      nullptr, nullptr, 0, wt1h, wt1l, 192, patch_b, tok, nullptr, nullptr,
      videos, action_token, NTOK, 512, 192);

  for (int L = 0; L < 4; L++) {
    // ================= spatial attention (4 chunk pairs) =================
    convert_w<<<dim3(8, 24), 256, 0, stream>>>(wqkv_s + (long)L*512*1536, wt1h, wt1l, 1536, 512);
    convert_w<<<dim3(8, 8),  256, 0, stream>>>(wo_s   + (long)L*512*512,  wt2h, wt2l, 512, 512);
    for (int pr = 0; pr < 4; pr++) {
      long r0 = (long)pr * PCH;
      ln_single<<<PCH / 4, 256, 0, stream>>>(tok + r0 * D_, ln1_g + L*512, ln1_b + L*512, aH);
      gemm_mfma<128,4,4,0,false,false,false,false,false,3><<<dim3(65, 12), 256, 0, stream>>>(
          aH, nullptr, 512, wt1h, wt1l, 512, nullptr, nullptr,
          qk, v2, nullptr, nullptr, PCH, 1536, 512);
      flash_spatial<<<dim3(5, 256), 256, 0, stream>>>(qk, v2, ctx);
      gemm_mfma<64,2,4,0,false,false,false,false,true,0><<<dim3(65, 8), 256, 0, stream>>>(
          ctx, nullptr, 512, wt2h, wt2l, 512, nullptr, tok + r0 * D_,
          nullptr, nullptr, nullptr, nullptr, PCH, 512, 512);
    }
    // ================= temporal attention (4 chunk pairs) =================
    convert_w<<<dim3(8, 24), 256, 0, stream>>>(wqkv_t + (long)L*512*1536, wt1h, wt1l, 1536, 512);
    convert_w<<<dim3(8, 8),  256, 0, stream>>>(wo_t   + (long)L*512*512,  wt2h, wt2l, 512, 512);
    for (int pr = 0; pr < 4; pr++) {
      long r0 = (long)pr * PCH;
      ln_single<<<PCH / 4, 256, 0, stream>>>(tok + r0 * D_, ln2_g + L*512, ln2_b + L*512, aH);
      gemm_mfma<128,4,4,0,false,false,false,false,false,3><<<dim3(65, 12), 256, 0, stream>>>(
          aH, nullptr, 512, wt1h, wt1l, 512, nullptr, nullptr,
          qk, v2, nullptr, nullptr, PCH, 1536, 512);
      temporal_attn<<<2 * S_ * NH_, 64, 0, stream>>>(qk, v2, ctx);
      gemm_mfma<64,2,4,0,false,false,false,false,true,0><<<dim3(65, 8), 256, 0, stream>>>(
          ctx, nullptr, 512, wt2h, wt2l, 512, nullptr, tok + r0 * D_,
          nullptr, nullptr, nullptr, nullptr, PCH, 512, 512);
    }
    // ================= MLP (4 M-chunks of 8224 rows) =================
    convert_w<<<dim3(8, 32), 256, 0, stream>>>(mlp_w1 + (long)L*512*2048, wt1h, wt1l, 2048, 512);
    convert_w<<<dim3(32, 8), 256, 0, stream>>>(mlp_w2 + (long)L*2048*512, wt2h, wt2l, 512, 2048);
    for (int c = 0; c < 4; c++) {
      long m0r = (long)c * PCH;
      ln_single<<<PCH / 4, 256, 0, stream>>>(tok + m0r * D_, ln3_g + L*512, ln3_b + L*512, aH);
      gemm_mfma<128,4,4,0,false,false,true,true,false,2><<<dim3(65, 16), 256, 0, stream>>>(
          aH, nullptr, 512, wt1h, wt1l, 512, mlp_b1 + (long)L*2048, nullptr, mid, nullptr,
          nullptr, nullptr, PCH, FFN_, 512);
      gemm_mfma<64,2,4,0,false,false,true,false,true,0><<<dim3(65, 8), 256, 0, stream>>>(
          mid, nullptr, 2048, wt2h, wt2l, 2048, mlp_b2 + (long)L*512, tok + m0r * D_,
          nullptr, nullptr, nullptr, nullptr, PCH, 512, 2048);
    }
  }

  final_vq<<<B_ * (T_ - 1), 256, 0, stream>>>(tok, lnf_g, lnf_b, out_w, codebook, action_w, out);
}

// Round 25
// 3866.061 us; speedup vs baseline: 1.2608x; 1.1043x over previous
//
#include <hip/hip_runtime.h>
#include <hip/hip_bf16.h>

#define B_ 8
#define T_ 16
#define S_ 257
#define D_ 512
#define FFN_ 2048
#define NH_ 8
#define HD_ 64
#define PTD_ 192
#define NTOK (B_*T_*S_)        // 32896
#define CH 4112                // 16 frames * 257 rows per chunk
#define PCH 8224               // chunk pair rows
#define WSCALE 64.0f
#define WINV 0.015625f

typedef unsigned int uint;
typedef unsigned short ushort;
typedef __attribute__((ext_vector_type(8))) _Float16 half8;
typedef __attribute__((ext_vector_type(4))) float f32x4;

__device__ __forceinline__ float warp_rsum(float v){
#pragma unroll
  for (int m = 32; m >= 1; m >>= 1) v += __shfl_xor(v, m);
  return v;
}
__device__ __forceinline__ float gelu_f(float x){
  float x3 = x*x*x;
  return 0.5f*x*(1.0f + tanhf(0.7978845608028654f*(x + 0.044715f*x3)));
}
// split fp32 -> f16 hi + f16 lo (RNE).
__device__ __forceinline__ void split_f16(float f, ushort& h, ushort& l){
  _Float16 hh = (_Float16)f;
  float hf = (float)hh;
  _Float16 ll = (_Float16)(f - hf);
  h = __builtin_bit_cast(ushort, hh);
  l = __builtin_bit_cast(ushort, ll);
}
__device__ __forceinline__ ushort to_f16u(float f){
  return __builtin_bit_cast(ushort, (_Float16)f);
}
__device__ __forceinline__ float from_f16u(ushort u){
  return (float)__builtin_bit_cast(_Float16, u);
}
// async global->LDS 16B (lane-linear LDS dest, per-lane global src)
__device__ __forceinline__ void gload16(const ushort* g, ushort* l){
  __builtin_amdgcn_global_load_lds(
      (const __attribute__((address_space(1))) void*)(g),
      (__attribute__((address_space(3))) void*)(l),
      16, 0, 0);
}

// ---------------- fused LN + single-f16 cast:  aH[row][512] = f16(LN(x[row]))
__global__ __launch_bounds__(256) void ln_single(
    const float* __restrict__ x, const float* __restrict__ g,
    const float* __restrict__ bb, ushort* __restrict__ aH)
{
  int row = blockIdx.x * 4 + (threadIdx.x >> 6);
  int lane = threadIdx.x & 63;
  const float* xr = x + (long)row * D_;
  float4 u0 = *(const float4*)(xr + lane * 8);
  float4 u1 = *(const float4*)(xr + lane * 8 + 4);
  float s = u0.x + u0.y + u0.z + u0.w + u1.x + u1.y + u1.z + u1.w;
  s = warp_rsum(s);
  float mean = s * (1.0f / 512.0f);
  float d[8] = {u0.x - mean, u0.y - mean, u0.z - mean, u0.w - mean,
                u1.x - mean, u1.y - mean, u1.z - mean, u1.w - mean};
  float ss = 0.f;
#pragma unroll
  for (int i = 0; i < 8; i++) ss = fmaf(d[i], d[i], ss);
  ss = warp_rsum(ss);
  float rstd = rsqrtf(ss * (1.0f / 512.0f) + 1e-5f);
  int c = lane * 8;
  float4 g0 = *(const float4*)(g + c), g1 = *(const float4*)(g + c + 4);
  float4 b0 = *(const float4*)(bb + c), b1 = *(const float4*)(bb + c + 4);
  float y[8] = {d[0]*rstd*g0.x + b0.x, d[1]*rstd*g0.y + b0.y,
                d[2]*rstd*g0.z + b0.z, d[3]*rstd*g0.w + b0.w,
                d[4]*rstd*g1.x + b1.x, d[5]*rstd*g1.y + b1.y,
                d[6]*rstd*g1.z + b1.z, d[7]*rstd*g1.w + b1.w};
  ushort h[8];
#pragma unroll
  for (int i = 0; i < 8; i++) h[i] = to_f16u(y[i]);
  uint4 hv = make_uint4((uint)h[0] | ((uint)h[1] << 16), (uint)h[2] | ((uint)h[3] << 16),
                        (uint)h[4] | ((uint)h[5] << 16), (uint)h[6] | ((uint)h[7] << 16));
  *(uint4*)(aH + (long)row * 512 + c) = hv;
}

// ---------------- weight transpose + split:  W[K][N] f32 -> (W*64) as Whi[N][K], Wlo[N][K] f16
__global__ __launch_bounds__(256) void convert_w(
    const float* __restrict__ W, ushort* __restrict__ Whi, ushort* __restrict__ Wlo,
    int N, int K)
{
  __shared__ float Tt[64][65];
  const int tid = threadIdx.x;
  const int k0 = blockIdx.x << 6, n0 = blockIdx.y << 6;
  {
    int kk = tid >> 2, nb = (tid & 3) << 4;
#pragma unroll
    for (int q = 0; q < 4; q++) {
      float4 v = *(const float4*)(W + (long)(k0 + kk) * N + n0 + nb + 4 * q);
      Tt[kk][nb + 4*q + 0] = v.x; Tt[kk][nb + 4*q + 1] = v.y;
      Tt[kk][nb + 4*q + 2] = v.z; Tt[kk][nb + 4*q + 3] = v.w;
    }
  }
  __syncthreads();
  {
    int nn = tid >> 2, kb = (tid & 3) << 4;
    uint hw[8], lw[8];
#pragma unroll
    for (int q = 0; q < 8; q++) {
      float a = Tt[kb + 2*q][nn] * WSCALE, b = Tt[kb + 2*q + 1][nn] * WSCALE;
      ushort ha, la, hb, lb;
      split_f16(a, ha, la); split_f16(b, hb, lb);
      hw[q] = (uint)ha | ((uint)hb << 16); lw[q] = (uint)la | ((uint)lb << 16);
    }
    ushort* dh = Whi + (long)(n0 + nn) * K + k0 + kb;
    ushort* dl = Wlo + (long)(n0 + nn) * K + k0 + kb;
    ((uint4*)dh)[0] = make_uint4(hw[0], hw[1], hw[2], hw[3]);
    ((uint4*)dh)[1] = make_uint4(hw[4], hw[5], hw[6], hw[7]);
    ((uint4*)dl)[0] = make_uint4(lw[0], lw[1], lw[2], lw[3]);
    ((uint4*)dl)[1] = make_uint4(lw[4], lw[5], lw[6], lw[7]);
  }
}

// ---------------- split-f16 MFMA GEMM.
// AMODE 0: BM x BN tile, BK=32, 256 threads, 2-deep gload_lds pipeline with EARLY second
//          barrier: {vmcnt(LPS); bar; ds_read frags -> regs; lgkmcnt(0); bar;
//          stage(t+2 into freed buf); MFMA on regs}.  XCD-chunked bijective remap.
//          LPS = loads/thread/stage: A (BM==128 ? 2 : 1) + B (BN==128 ? 2 : BSPLIT ? 2 : 1).
// AMODE 1: BM=128, fused patchify (legacy single-buffer, pitch-32 layout).
// LDS per buffer: [rows][4 chunks of 16B], phys chunk = c ^ ((row>>1)&3), pitch 32.
// SOUT 0: fp32 C (opt RESID).  2: single-f16 out.  3: qkv single-f16 out.
template<int BM, int BN, int TM, int TN, int AMODE, bool ASPLIT, bool BSPLIT, bool BIAS, bool GELU, bool RESID, int SOUT>
__global__ __launch_bounds__(256) void gemm_mfma(
    const ushort* __restrict__ aHp, const ushort* __restrict__ aLp, int lda,
    const ushort* __restrict__ wtH, const ushort* __restrict__ wtL, int ldb,
    const float* __restrict__ bias, float* __restrict__ C,
    ushort* __restrict__ coH, ushort* __restrict__ vOut,
    const float* __restrict__ videos, const float* __restrict__ atok,
    int M, int N, int K)
{
  constexpr int NWC = BN / (TN * 16);
  constexpr int NBUF = (AMODE == 0) ? 2 : 1;
  __shared__ __align__(16) ushort sAh[NBUF * BM * 32];
  __shared__ __align__(16) ushort sAl[(AMODE == 1) ? 128 * 32 : 8];
  __shared__ __align__(16) ushort sBh[NBUF * BN * 32];
  __shared__ __align__(16) ushort sBl[BSPLIT ? NBUF * BN * 32 : 8];
  const int tid = threadIdx.x;
  int m0, n0;
  if (AMODE == 0) {
    // bijective XCD-chunked remap (m204): o%8 = XCD under round-robin dispatch
    const int gx = gridDim.x, gy = gridDim.y;
    const int nwg = gx * gy;
    const int o = blockIdx.y * gx + blockIdx.x;
    const int q = nwg >> 3, r = nwg & 7;
    const int xcd = o & 7, idx = o >> 3;
    const int wgid = (xcd < r ? xcd * (q + 1) : r * (q + 1) + (xcd - r) * q) + idx;
    const int mi = wgid / gy, ni = wgid - mi * gy;
    m0 = mi * BM; n0 = ni * BN;
  } else {
    m0 = blockIdx.x * BM; n0 = blockIdx.y * BN;
  }
  const int wid = tid >> 6, lane = tid & 63;
  const int lrow = lane & 15, lkg = lane >> 4;
  const int wr = wid / NWC, wc = wid % NWC;
  const int wrb = wr * TM * 16, wcb = wc * TN * 16;
  f32x4 acc[TM][TN];
#pragma unroll
  for (int mi = 0; mi < TM; mi++)
#pragma unroll
    for (int ni = 0; ni < TN; ni++) acc[mi][ni] = (f32x4){0.f, 0.f, 0.f, 0.f};

  if (AMODE == 0) {
    // ---- 2-deep pipeline, early-barrier register-fragment consume
    auto stage = [&](int k0, int d) {
      {
        int row = tid >> 2, cp = tid & 3;
        int csrc = cp ^ ((row >> 1) & 3);
        int ar = m0 + row; if (ar > M - 1) ar = M - 1;
        gload16(aHp + (long)ar * lda + k0 + csrc * 8, &sAh[d * (BM * 32) + tid * 8]);
      }
      if constexpr (BM == 128) {
        int chunk = tid + 256;
        int row = chunk >> 2, cp = chunk & 3;
        int csrc = cp ^ ((row >> 1) & 3);
        int ar = m0 + row; if (ar > M - 1) ar = M - 1;
        gload16(aHp + (long)ar * lda + k0 + csrc * 8, &sAh[d * (BM * 32) + chunk * 8]);
      }
      if (BN == 128) {
#pragma unroll
        for (int i = 0; i < 2; i++) {
          int chunk = tid + 256 * i;
          int row = chunk >> 2, cp = chunk & 3;
          int csrc = cp ^ ((row >> 1) & 3);
          gload16(wtH + (long)(n0 + row) * ldb + k0 + csrc * 8, &sBh[d * 4096 + chunk * 8]);
        }
      } else {
        int chunk = tid;
        int row = chunk >> 2, cp = chunk & 3;
        int csrc = cp ^ ((row >> 1) & 3);
        gload16(wtH + (long)(n0 + row) * ldb + k0 + csrc * 8, &sBh[d * 2048 + chunk * 8]);
        if (BSPLIT)
          gload16(wtL + (long)(n0 + row) * ldb + k0 + csrc * 8, &sBl[d * 2048 + chunk * 8]);
      }
    };
    const int nt = K >> 5;
    stage(0, 0);
    if (nt > 1) stage(32, 1);
    constexpr int LPS = ((BM == 128) ? 2 : 1) + ((BN == 128) ? 2 : (BSPLIT ? 2 : 1));
    for (int t = 0; t < nt; t++) {
      const int cur = t & 1;
      if (t + 1 < nt) {
        if constexpr (LPS == 4) {
          asm volatile("s_waitcnt vmcnt(4)" ::: "memory");
        } else if constexpr (LPS == 3) {
          asm volatile("s_waitcnt vmcnt(3)" ::: "memory");
        } else {
          asm volatile("s_waitcnt vmcnt(2)" ::: "memory");
        }
      } else {
        asm volatile("s_waitcnt vmcnt(0)" ::: "memory");
      }
      __builtin_amdgcn_s_barrier();
      const int aBase = cur * (BM * 32);
      const int bBase = cur * ((BN == 128) ? 4096 : 2048);
      // ---- read all fragments into registers
      half8 aHf[TM], bHf[TN], bLf[BSPLIT ? TN : 1];
#pragma unroll
      for (int mi = 0; mi < TM; mi++) {
        int ar = wrb + mi * 16 + lrow;
        int ac = (ar * 4 + (lkg ^ ((ar >> 1) & 3))) * 8;
        aHf[mi] = *(const half8*)&sAh[aBase + ac];
      }
#pragma unroll
      for (int ni = 0; ni < TN; ni++) {
        int br = wcb + ni * 16 + lrow;
        int bc = (br * 4 + (lkg ^ ((br >> 1) & 3))) * 8;
        bHf[ni] = *(const half8*)&sBh[bBase + bc];
        if (BSPLIT) bLf[ni] = *(const half8*)&sBl[bBase + bc];
      }
      asm volatile("s_waitcnt lgkmcnt(0)" ::: "memory");
      __builtin_amdgcn_sched_barrier(0);
      __builtin_amdgcn_s_barrier();
      // ---- buffer freed: issue tile t+2 into it NOW (2-iteration issue distance)
      if (t + 2 < nt) stage((t + 2) << 5, cur);
      // ---- MFMA purely on registers (overlaps the in-flight loads)
      __builtin_amdgcn_s_setprio(1);
#pragma unroll
      for (int ni = 0; ni < TN; ni++) {
        if (BSPLIT) {
#pragma unroll
          for (int mi = 0; mi < TM; mi++)
            acc[mi][ni] = __builtin_amdgcn_mfma_f32_16x16x32_f16(aHf[mi], bLf[ni], acc[mi][ni], 0, 0, 0);
        }
#pragma unroll
        for (int mi = 0; mi < TM; mi++)
          acc[mi][ni] = __builtin_amdgcn_mfma_f32_16x16x32_f16(aHf[mi], bHf[ni], acc[mi][ni], 0, 0, 0);
      }
      __builtin_amdgcn_s_setprio(0);
      __builtin_amdgcn_sched_barrier(0);
    }
  } else {
    // ---- legacy single-buffer path (fused patchify embed GEMM)
    const int rowa = tid >> 1, kba = (tid & 1) << 4;
    const int cb0 = (tid & 1) * 2;
    const int swa = (rowa >> 1) & 3;
    int bt_p = 0, s_p = 0;
    { int ar = m0 + rowa; bt_p = ar / 257; s_p = ar - bt_p * 257; }
    for (int k0 = 0; k0 < K; k0 += 32) {
      float4 vr[4];
#pragma unroll
      for (int q = 0; q < 4; q++) vr[q] = make_float4(0.f, 0.f, 0.f, 0.f);
#pragma unroll
      for (int q = 0; q < 4; q++) {
        int e4 = k0 + kba + 4 * q;
        if (s_p == 0) {
          vr[q] = *(const float4*)(atok + e4);
        } else {
          int p = s_p - 1, ph = p >> 4, pw = p & 15;
          int iq = e4 / 24, jc = e4 - iq * 24;
          vr[q] = *(const float4*)(videos + (long)bt_p * 49152 +
                                   (long)(ph * 8 + iq) * 384 + pw * 24 + jc);
        }
      }
      uint hw[8], lw[8];
#pragma unroll
      for (int q = 0; q < 4; q++) {
        ushort h0,l0,h1,l1,h2,l2,h3,l3;
        split_f16(vr[q].x, h0, l0); split_f16(vr[q].y, h1, l1);
        split_f16(vr[q].z, h2, l2); split_f16(vr[q].w, h3, l3);
        hw[2*q]   = (uint)h0 | ((uint)h1 << 16); lw[2*q]   = (uint)l0 | ((uint)l1 << 16);
        hw[2*q+1] = (uint)h2 | ((uint)h3 << 16); lw[2*q+1] = (uint)l2 | ((uint)l3 << 16);
      }
      *(uint4*)&sAh[(rowa * 4 + (cb0 ^ swa)) * 8]       = make_uint4(hw[0], hw[1], hw[2], hw[3]);
      *(uint4*)&sAh[(rowa * 4 + ((cb0 + 1) ^ swa)) * 8] = make_uint4(hw[4], hw[5], hw[6], hw[7]);
      *(uint4*)&sAl[(rowa * 4 + (cb0 ^ swa)) * 8]       = make_uint4(lw[0], lw[1], lw[2], lw[3]);
      *(uint4*)&sAl[(rowa * 4 + ((cb0 + 1) ^ swa)) * 8] = make_uint4(lw[4], lw[5], lw[6], lw[7]);
      {
#pragma unroll
        for (int i = 0; i < 2; i++) {
          int chunk = tid + 256 * i;
          int row = chunk >> 2, cp = chunk & 3;
          int csrc = cp ^ ((row >> 1) & 3);
          gload16(wtH + (long)(n0 + row) * ldb + k0 + csrc * 8, &sBh[chunk * 8]);
          if (BSPLIT)
            gload16(wtL + (long)(n0 + row) * ldb + k0 + csrc * 8, &sBl[chunk * 8]);
        }
      }
      __syncthreads();
      half8 aHf[TM], aLf[TM];
#pragma unroll
      for (int mi = 0; mi < TM; mi++) {
        int ar = wrb + mi * 16 + lrow;
        int ac = (ar * 4 + (lkg ^ ((ar >> 1) & 3))) * 8;
        aHf[mi] = *(const half8*)&sAh[ac];
        if (ASPLIT) aLf[mi] = *(const half8*)&sAl[ac];
      }
#pragma unroll
      for (int ni = 0; ni < TN; ni++) {
        int br = wcb + ni * 16 + lrow;
        int bc = (br * 4 + (lkg ^ ((br >> 1) & 3))) * 8;
        half8 bH = *(const half8*)&sBh[bc];
#pragma unroll
        for (int mi = 0; mi < TM; mi++) {
          if (ASPLIT)
            acc[mi][ni] = __builtin_amdgcn_mfma_f32_16x16x32_f16(aLf[mi], bH, acc[mi][ni], 0, 0, 0);
        }
        if (BSPLIT) {
          half8 bL = *(const half8*)&sBl[bc];
#pragma unroll
          for (int mi = 0; mi < TM; mi++)
            acc[mi][ni] = __builtin_amdgcn_mfma_f32_16x16x32_f16(aHf[mi], bL, acc[mi][ni], 0, 0, 0);
        }
#pragma unroll
        for (int mi = 0; mi < TM; mi++)
          acc[mi][ni] = __builtin_amdgcn_mfma_f32_16x16x32_f16(aHf[mi], bH, acc[mi][ni], 0, 0, 0);
      }
      __syncthreads();
    }
  }
  // ---- epilogue
#pragma unroll
  for (int mi = 0; mi < TM; mi++) {
    int rowg = m0 + wrb + mi * 16 + lkg * 4;
#pragma unroll
    for (int j = 0; j < 4; j++) {
      int r = rowg + j;
      if (r < M) {
#pragma unroll
        for (int ni = 0; ni < TN; ni++) {
          int cg = n0 + wcb + ni * 16 + lrow;
          float v = acc[mi][ni][j] * WINV;
          if (BIAS) v += bias[cg];
          if (GELU) v = gelu_f(v);
          if (SOUT == 2) {
            coH[(long)r * N + cg] = to_f16u(v);
          } else if (SOUT == 3) {
            if (cg < 1024) coH[(long)r * 1024 + cg] = to_f16u(v);
            else           vOut[(long)r * 512 + (cg - 1024)] = to_f16u(v);
          } else {
            long idx = (long)r * N + cg;
            if (RESID) C[idx] += v; else C[idx] = v;
          }
        }
      }
    }
  }
}

// ---------------- fused flash spatial attention over a chunk PAIR (32 frames).
__global__ __launch_bounds__(256) void flash_spatial(
    const ushort* __restrict__ qk, const ushort* __restrict__ v2,
    ushort* __restrict__ ctxc)
{
  __shared__ __align__(16) ushort sQ[64*72];
  __shared__ __align__(16) ushort sK[64*72];
  __shared__ __align__(16) ushort sV[64*72];               // V^T: [d][k]
  __shared__ __align__(16) ushort sP[64*72];
  const int tid = threadIdx.x;
  const int wid = tid >> 6, lane = tid & 63;
  const int lr = lane & 15, lg = lane >> 4;
  const int fh = blockIdx.y;                  // 0..255 (32 frames x 8 heads)
  const int fl = fh >> 3, hh = fh & 7;
  const int q0 = blockIdx.x * 64;
  const long rbase = (long)fl * S_;
  const int srow = tid >> 2, sc0 = (tid & 3) << 4;

  {
    int gr = q0 + srow;
    uint4 h0 = make_uint4(0,0,0,0), h1 = h0;
    if (gr < S_) {
      const ushort* sh = qk + (rbase + gr) * 1024 + hh * HD_ + sc0;
      h0 = ((const uint4*)sh)[0]; h1 = ((const uint4*)sh)[1];
    }
    uint4* dh = (uint4*)&sQ[srow*72 + sc0];
    dh[0] = h0; dh[1] = h1;
  }
  __syncthreads();
  half8 qH[2];
  {
    int qrl = wid * 16 + lr;
#pragma unroll
    for (int s = 0; s < 2; s++)
      qH[s] = *(const half8*)&sQ[qrl*72 + s*32 + lg*8];
  }
  f32x4 accS[5][4];
#pragma unroll
  for (int t = 0; t < 5; t++)
#pragma unroll
    for (int kc = 0; kc < 4; kc++) accS[t][kc] = (f32x4){0.f,0.f,0.f,0.f};

#pragma unroll
  for (int t = 0; t < 5; t++) {
    __syncthreads();
    {
      int gr = t*64 + srow;
      uint4 h0 = make_uint4(0,0,0,0), h1 = h0;
      if (gr < S_) {
        const ushort* sh = qk + (rbase + gr) * 1024 + 512 + hh * HD_ + sc0;
        h0 = ((const uint4*)sh)[0]; h1 = ((const uint4*)sh)[1];
      }
      uint4* dh = (uint4*)&sK[srow*72 + sc0];
      dh[0] = h0; dh[1] = h1;
    }
    __syncthreads();
#pragma unroll
    for (int s = 0; s < 2; s++) {
#pragma unroll
      for (int kc = 0; kc < 4; kc++) {
        int off = (kc*16 + lr)*72 + s*32 + lg*8;
        half8 bH = *(const half8*)&sK[off];
        accS[t][kc] = __builtin_amdgcn_mfma_f32_16x16x32_f16(qH[s], bH, accS[t][kc], 0,0,0);
      }
    }
  }

  float m[4] = {-3.0e38f, -3.0e38f, -3.0e38f, -3.0e38f};
#pragma unroll
  for (int t = 0; t < 5; t++)
#pragma unroll
    for (int kc = 0; kc < 4; kc++) {
      int kcol = t*64 + kc*16 + lr;
      if (kcol < S_) {
#pragma unroll
        for (int j = 0; j < 4; j++) m[j] = fmaxf(m[j], accS[t][kc][j] * 0.125f);
      }
    }
#pragma unroll
  for (int mk = 8; mk >= 1; mk >>= 1)
#pragma unroll
    for (int j = 0; j < 4; j++) m[j] = fmaxf(m[j], __shfl_xor(m[j], mk));
  float l[4] = {0.f, 0.f, 0.f, 0.f};
#pragma unroll
  for (int t = 0; t < 5; t++)
#pragma unroll
    for (int kc = 0; kc < 4; kc++) {
      int kcol = t*64 + kc*16 + lr;
#pragma unroll
      for (int j = 0; j < 4; j++) {
        float p = (kcol < S_) ? expf(accS[t][kc][j]*0.125f - m[j]) : 0.f;
        accS[t][kc][j] = p;
        l[j] += p;
      }
    }
#pragma unroll
  for (int mk = 8; mk >= 1; mk >>= 1)
#pragma unroll
    for (int j = 0; j < 4; j++) l[j] += __shfl_xor(l[j], mk);

  f32x4 accO[4];
#pragma unroll
  for (int dc = 0; dc < 4; dc++) accO[dc] = (f32x4){0.f,0.f,0.f,0.f};
#pragma unroll
  for (int t = 0; t < 5; t++) {
#pragma unroll
    for (int kc = 0; kc < 4; kc++)
#pragma unroll
      for (int j = 0; j < 4; j++) {
        int addr = (wid*16 + lg*4 + j)*72 + kc*16 + lr;
        sP[addr] = to_f16u(accS[t][kc][j]);
      }
    __syncthreads();
    {
      int gr = t*64 + srow;
      ushort tmp[16];
      uint4 a = make_uint4(0,0,0,0), b = a;
      if (gr < S_) {
        const ushort* src = v2 + (rbase + gr) * 512 + hh * HD_ + sc0;
        a = ((const uint4*)src)[0]; b = ((const uint4*)src)[1];
      }
      *(uint4*)&tmp[0] = a; *(uint4*)&tmp[8] = b;
#pragma unroll
      for (int e = 0; e < 16; e++) sV[(sc0 + e)*72 + srow] = tmp[e];
    }
    __syncthreads();
#pragma unroll
    for (int s = 0; s < 2; s++) {
      int poff = (wid*16 + lr)*72 + s*32 + lg*8;
      half8 pH = *(const half8*)&sP[poff];
#pragma unroll
      for (int dc = 0; dc < 4; dc++) {
        int voff = (dc*16 + lr)*72 + s*32 + lg*8;
        half8 vH = *(const half8*)&sV[voff];
        accO[dc] = __builtin_amdgcn_mfma_f32_16x16x32_f16(pH, vH, accO[dc], 0,0,0);
      }
    }
  }
#pragma unroll
  for (int j = 0; j < 4; j++) {
    int grow = q0 + wid*16 + lg*4 + j;
    if (grow < S_) {
      float inv = 1.0f / l[j];
#pragma unroll
      for (int dc = 0; dc < 4; dc++) {
        float o = accO[dc][j] * inv;
        long idx = (rbase + grow) * 512 + hh*64 + dc*16 + lr;
        ctxc[idx] = to_f16u(o);
      }
    }
  }
}

// ---------------- temporal causal attention over a chunk pair (2 batches), single-f16 qkv
__global__ __launch_bounds__(64) void temporal_attn(
    const ushort* __restrict__ qk, const ushort* __restrict__ v2,
    ushort* __restrict__ ctxc)
{
  const int gid = blockIdx.x;           // b2*2056 + s*8+h
  const int b2 = gid / (S_ * NH_);
  const int rem = gid - b2 * S_ * NH_;
  const int hh = rem & 7;
  const int s = rem >> 3;
  const int lane = threadIdx.x;
  __shared__ float Qs[16][65];
  __shared__ float Ks[16][65];
  __shared__ float Pm[16][17];
  float v[16];
  const long rbase = (long)b2 * CH + s;
#pragma unroll
  for (int t = 0; t < 16; t++) {
    long row = rbase + (long)t * S_;
    long qoff = row * 1024 + hh * HD_ + lane;
    Qs[t][lane] = from_f16u(qk[qoff]);
    Ks[t][lane] = from_f16u(qk[qoff + 512]);
    v[t] = from_f16u(v2[row * 512 + hh * HD_ + lane]);
  }
  __syncthreads();
  const int rq = lane >> 2, c0 = lane & 3;
  float sc[4];
#pragma unroll
  for (int j = 0; j < 4; j++) {
    int c = c0 + (j << 2);
    if (c <= rq) {
      float d = 0.f;
#pragma unroll
      for (int k = 0; k < 64; k++) d = fmaf(Qs[rq][k], Ks[c][k], d);
      sc[j] = d * 0.125f;
    } else sc[j] = -3.0e38f;
  }
  float mx = fmaxf(fmaxf(sc[0], sc[1]), fmaxf(sc[2], sc[3]));
  mx = fmaxf(mx, __shfl_xor(mx, 1));
  mx = fmaxf(mx, __shfl_xor(mx, 2));
  float sum = 0.f;
#pragma unroll
  for (int j = 0; j < 4; j++) { sc[j] = expf(sc[j] - mx); sum += sc[j]; }
  sum += __shfl_xor(sum, 1);
  sum += __shfl_xor(sum, 2);
  float inv = 1.0f / sum;
#pragma unroll
  for (int j = 0; j < 4; j++) Pm[rq][c0 + (j << 2)] = sc[j] * inv;
  __syncthreads();
#pragma unroll
  for (int t = 0; t < 16; t++) {
    float o = 0.f;
#pragma unroll
    for (int k = 0; k < 16; k++) o = fmaf(Pm[t][k], v[k], o);
    long idx = (rbase + (long)t * S_) * 512 + hh * HD_ + lane;
    ctxc[idx] = to_f16u(o);
  }
}

// ---------------- final LN + projection + VQ argmin + action head
__global__ __launch_bounds__(256) void final_vq(
    const float* __restrict__ tok, const float* __restrict__ lnf_g,
    const float* __restrict__ lnf_b, const float* __restrict__ out_w,
    const float* __restrict__ codebook, const float* __restrict__ action_w,
    float* __restrict__ out)
{
  __shared__ float xs[512];
  __shared__ float red[256];
  __shared__ float zs[64];
  __shared__ float bd[256];
  __shared__ int   bi[256];
  const int b = blockIdx.x / 15, tm = blockIdx.x % 15;
  const int tid = threadIdx.x;
  const float* xr = tok + ((long)(b * T_ + tm + 1) * S_) * D_;   // s = 0
  xs[tid] = xr[tid]; xs[tid + 256] = xr[tid + 256];
  red[tid] = xs[tid] + xs[tid + 256];
  __syncthreads();
  for (int off = 128; off >= 1; off >>= 1) {
    if (tid < off) red[tid] += red[tid + off];
    __syncthreads();
  }
  float mean = red[0] * (1.0f / 512.0f);
  __syncthreads();
  float d0 = xs[tid] - mean, d1 = xs[tid + 256] - mean;
  red[tid] = d0 * d0 + d1 * d1;
  __syncthreads();
  for (int off = 128; off >= 1; off >>= 1) {
    if (tid < off) red[tid] += red[tid + off];
    __syncthreads();
  }
  float rs = rsqrtf(red[0] * (1.0f / 512.0f) + 1e-5f);
  __syncthreads();
  xs[tid]       = d0 * rs * lnf_g[tid]       + lnf_b[tid];
  xs[tid + 256] = d1 * rs * lnf_g[tid + 256] + lnf_b[tid + 256];
  __syncthreads();
  if (tid < 64) {
    float z = 0.f;
    for (int d = 0; d < 512; d++) z = fmaf(xs[d], out_w[d * 64 + tid], z);
    zs[tid] = z;
  }
  __syncthreads();
  float best = 3.0e38f; int bidx = 0;
  for (int c = tid; c < 4096; c += 256) {
    const float* cp = codebook + (long)c * 64;
    float dot = 0.f, cn = 0.f;
#pragma unroll 8
    for (int k = 0; k < 64; k++) { float w = cp[k]; dot = fmaf(zs[k], w, dot); cn = fmaf(w, w, cn); }
    float dist = cn - 2.0f * dot;
    if (dist < best) { best = dist; bidx = c; }
  }
  bd[tid] = best; bi[tid] = bidx;
  __syncthreads();
  for (int off = 128; off >= 1; off >>= 1) {
    if (tid < off) {
      if (bd[tid + off] < bd[tid] || (bd[tid + off] == bd[tid] && bi[tid + off] < bi[tid])) {
        bd[tid] = bd[tid + off]; bi[tid] = bi[tid + off];
      }
    }
    __syncthreads();
  }
  int idx = bi[0];
  if (tid < 16) {
    const float* cp = codebook + (long)idx * 64;
    float o = 0.f;
#pragma unroll
    for (int k = 0; k < 64; k++) o = fmaf(cp[k], action_w[k * 16 + tid], o);
    out[((long)(b * 15 + tm)) * 16 + tid] = o;
  }
}

extern "C" void kernel_launch(void* const* d_in, const int* in_sizes, int n_in,
                              void* d_out, int out_size, void* d_ws, size_t ws_size,
                              hipStream_t stream)
{
  const float* videos       = (const float*)d_in[0];
  const float* patch_w      = (const float*)d_in[1];
  const float* patch_b      = (const float*)d_in[2];
  const float* action_token = (const float*)d_in[3];
  const float* ln1_g  = (const float*)d_in[4];
  const float* ln1_b  = (const float*)d_in[5];
  const float* wqkv_s = (const float*)d_in[6];
  const float* wo_s   = (const float*)d_in[7];
  const float* ln2_g  = (const float*)d_in[8];
  const float* ln2_b  = (const float*)d_in[9];
  const float* wqkv_t = (const float*)d_in[10];
  const float* wo_t   = (const float*)d_in[11];
  const float* ln3_g  = (const float*)d_in[12];
  const float* ln3_b  = (const float*)d_in[13];
  const float* mlp_w1 = (const float*)d_in[14];
  const float* mlp_b1 = (const float*)d_in[15];
  const float* mlp_w2 = (const float*)d_in[16];
  const float* mlp_b2 = (const float*)d_in[17];
  const float* lnf_g  = (const float*)d_in[18];
  const float* lnf_b  = (const float*)d_in[19];
  const float* out_w  = (const float*)d_in[20];
  const float* codebook = (const float*)d_in[21];
  const float* action_w = (const float*)d_in[22];
  float* out = (float*)d_out;

  // ---- workspace layout (floats), total 29,466,624 f = 117.9 MB (< proven 135)
  float* ws    = (float*)d_ws;
  float* tok   = ws;                                  // 16,842,752
  ushort* wt1h = (ushort*)(ws + 16842752);            // 1,048,576 f-eq (hi+lo)
  ushort* wt1l = wt1h + 1048576;
  ushort* wt2h = (ushort*)(ws + 17891328);            // 1,048,576 f-eq
  ushort* wt2l = wt2h + 1048576;
  ushort* aH   = (ushort*)(ws + 18939904);            // PCH x 512 single f16 = 2,105,344 f-eq
  ushort* qk   = (ushort*)(ws + 21045248);            // PCH x 1024 single = 4,210,688 f-eq
  ushort* v2   = (ushort*)(ws + 25255936);            // PCH x 512 single  = 2,105,344 f-eq
  ushort* ctx  = (ushort*)(ws + 27361280);            // PCH x 512 single  = 2,105,344 f-eq
  ushort* mid  = qk;                                  // MLP mid (PCH x 2048) spans qk+v2+ctx

  // ---- patchify fused into embed GEMM (full 3-MFMA, legacy path)
  convert_w<<<dim3(3, 8), 256, 0, stream>>>(patch_w, wt1h, wt1l, 512, 192);
  gemm_mfma<128,128,4,4,1,true,true,true,false,false,0><<<dim3(257, 4), 256, 0, stream>>>(
      nullptr, nullptr, 0, wt1h, wt1l, 192, patch_b, tok, nullptr, nullptr,
      videos, action_token, NTOK, 512, 192);

  for (int L = 0; L < 4; L++) {
    // ================= spatial attention (4 chunk pairs) =================
    convert_w<<<dim3(8, 24), 256, 0, stream>>>(wqkv_s + (long)L*512*1536, wt1h, wt1l, 1536, 512);
    convert_w<<<dim3(8, 8),  256, 0, stream>>>(wo_s   + (long)L*512*512,  wt2h, wt2l, 512, 512);
    for (int pr = 0; pr < 4; pr++) {
      long r0 = (long)pr * PCH;
      ln_single<<<PCH / 4, 256, 0, stream>>>(tok + r0 * D_, ln1_g + L*512, ln1_b + L*512, aH);
      gemm_mfma<64,128,2,4,0,false,false,false,false,false,3><<<dim3(129, 12), 256, 0, stream>>>(
          aH, nullptr, 512, wt1h, wt1l, 512, nullptr, nullptr,
          qk, v2, nullptr, nullptr, PCH, 1536, 512);
      flash_spatial<<<dim3(5, 256), 256, 0, stream>>>(qk, v2, ctx);
      gemm_mfma<128,64,2,4,0,false,false,false,false,true,0><<<dim3(65, 8), 256, 0, stream>>>(
          ctx, nullptr, 512, wt2h, wt2l, 512, nullptr, tok + r0 * D_,
          nullptr, nullptr, nullptr, nullptr, PCH, 512, 512);
    }
    // ================= temporal attention (4 chunk pairs) =================
    convert_w<<<dim3(8, 24), 256, 0, stream>>>(wqkv_t + (long)L*512*1536, wt1h, wt1l, 1536, 512);
    convert_w<<<dim3(8, 8),  256, 0, stream>>>(wo_t   + (long)L*512*512,  wt2h, wt2l, 512, 512);
    for (int pr = 0; pr < 4; pr++) {
      long r0 = (long)pr * PCH;
      ln_single<<<PCH / 4, 256, 0, stream>>>(tok + r0 * D_, ln2_g + L*512, ln2_b + L*512, aH);
      gemm_mfma<64,128,2,4,0,false,false,false,false,false,3><<<dim3(129, 12), 256, 0, stream>>>(
          aH, nullptr, 512, wt1h, wt1l, 512, nullptr, nullptr,
          qk, v2, nullptr, nullptr, PCH, 1536, 512);
      temporal_attn<<<2 * S_ * NH_, 64, 0, stream>>>(qk, v2, ctx);
      gemm_mfma<128,64,2,4,0,false,false,false,false,true,0><<<dim3(65, 8), 256, 0, stream>>>(
          ctx, nullptr, 512, wt2h, wt2l, 512, nullptr, tok + r0 * D_,
          nullptr, nullptr, nullptr, nullptr, PCH, 512, 512);
    }
    // ================= MLP (4 M-chunks of 8224 rows) =================
    convert_w<<<dim3(8, 32), 256, 0, stream>>>(mlp_w1 + (long)L*512*2048, wt1h, wt1l, 2048, 512);
    convert_w<<<dim3(32, 8), 256, 0, stream>>>(mlp_w2 + (long)L*2048*512, wt2h, wt2l, 512, 2048);
    for (int c = 0; c < 4; c++) {
      long m0r = (long)c * PCH;
      ln_single<<<PCH / 4, 256, 0, stream>>>(tok + m0r * D_, ln3_g + L*512, ln3_b + L*512, aH);
      gemm_mfma<64,128,2,4,0,false,false,true,true,false,2><<<dim3(129, 16), 256, 0, stream>>>(
          aH, nullptr, 512, wt1h, wt1l, 512, mlp_b1 + (long)L*2048, nullptr, mid, nullptr,
          nullptr, nullptr, PCH, FFN_, 512);
      gemm_mfma<128,64,2,4,0,false,false,true,false,true,0><<<dim3(65, 8), 256, 0, stream>>>(
          mid, nullptr, 2048, wt2h, wt2l, 2048, mlp_b2 + (long)L*512, tok + m0r * D_,
          nullptr, nullptr, nullptr, nullptr, PCH, 512, 2048);
    }
  }

  final_vq<<<B_ * (T_ - 1), 256, 0, stream>>>(tok, lnf_g, lnf_b, out_w, codebook, action_w, out);
}

// Round 26
// 3832.482 us; speedup vs baseline: 1.2718x; 1.0088x over previous
//
#include <hip/hip_runtime.h>
#include <hip/hip_bf16.h>

#define B_ 8
#define T_ 16
#define S_ 257
#define D_ 512
#define FFN_ 2048
#define NH_ 8
#define HD_ 64
#define PTD_ 192
#define NTOK (B_*T_*S_)        // 32896
#define CH 4112                // 16 frames * 257 rows per chunk
#define PCH 8224               // chunk pair rows
#define WSCALE 64.0f
#define WINV 0.015625f

typedef unsigned int uint;
typedef unsigned short ushort;
typedef __attribute__((ext_vector_type(8))) _Float16 half8;
typedef __attribute__((ext_vector_type(4))) float f32x4;

__device__ __forceinline__ float warp_rsum(float v){
#pragma unroll
  for (int m = 32; m >= 1; m >>= 1) v += __shfl_xor(v, m);
  return v;
}
__device__ __forceinline__ float gelu_f(float x){
  float x3 = x*x*x;
  return 0.5f*x*(1.0f + tanhf(0.7978845608028654f*(x + 0.044715f*x3)));
}
// split fp32 -> f16 hi + f16 lo (RNE).
__device__ __forceinline__ void split_f16(float f, ushort& h, ushort& l){
  _Float16 hh = (_Float16)f;
  float hf = (float)hh;
  _Float16 ll = (_Float16)(f - hf);
  h = __builtin_bit_cast(ushort, hh);
  l = __builtin_bit_cast(ushort, ll);
}
__device__ __forceinline__ ushort to_f16u(float f){
  return __builtin_bit_cast(ushort, (_Float16)f);
}
__device__ __forceinline__ float from_f16u(ushort u){
  return (float)__builtin_bit_cast(_Float16, u);
}
// async global->LDS 16B (lane-linear LDS dest, per-lane global src)
__device__ __forceinline__ void gload16(const ushort* g, ushort* l){
  __builtin_amdgcn_global_load_lds(
      (const __attribute__((address_space(1))) void*)(g),
      (__attribute__((address_space(3))) void*)(l),
      16, 0, 0);
}

// ---------------- fused LN + single-f16 cast:  aH[row][512] = f16(LN(x[row]))
__global__ __launch_bounds__(256) void ln_single(
    const float* __restrict__ x, const float* __restrict__ g,
    const float* __restrict__ bb, ushort* __restrict__ aH)
{
  int row = blockIdx.x * 4 + (threadIdx.x >> 6);
  int lane = threadIdx.x & 63;
  const float* xr = x + (long)row * D_;
  float4 u0 = *(const float4*)(xr + lane * 8);
  float4 u1 = *(const float4*)(xr + lane * 8 + 4);
  float s = u0.x + u0.y + u0.z + u0.w + u1.x + u1.y + u1.z + u1.w;
  s = warp_rsum(s);
  float mean = s * (1.0f / 512.0f);
  float d[8] = {u0.x - mean, u0.y - mean, u0.z - mean, u0.w - mean,
                u1.x - mean, u1.y - mean, u1.z - mean, u1.w - mean};
  float ss = 0.f;
#pragma unroll
  for (int i = 0; i < 8; i++) ss = fmaf(d[i], d[i], ss);
  ss = warp_rsum(ss);
  float rstd = rsqrtf(ss * (1.0f / 512.0f) + 1e-5f);
  int c = lane * 8;
  float4 g0 = *(const float4*)(g + c), g1 = *(const float4*)(g + c + 4);
  float4 b0 = *(const float4*)(bb + c), b1 = *(const float4*)(bb + c + 4);
  float y[8] = {d[0]*rstd*g0.x + b0.x, d[1]*rstd*g0.y + b0.y,
                d[2]*rstd*g0.z + b0.z, d[3]*rstd*g0.w + b0.w,
                d[4]*rstd*g1.x + b1.x, d[5]*rstd*g1.y + b1.y,
                d[6]*rstd*g1.z + b1.z, d[7]*rstd*g1.w + b1.w};
  ushort h[8];
#pragma unroll
  for (int i = 0; i < 8; i++) h[i] = to_f16u(y[i]);
  uint4 hv = make_uint4((uint)h[0] | ((uint)h[1] << 16), (uint)h[2] | ((uint)h[3] << 16),
                        (uint)h[4] | ((uint)h[5] << 16), (uint)h[6] | ((uint)h[7] << 16));
  *(uint4*)(aH + (long)row * 512 + c) = hv;
}

// ---------------- weight transpose + split:  W[K][N] f32 -> (W*64) as Whi[N][K], Wlo[N][K] f16
__global__ __launch_bounds__(256) void convert_w(
    const float* __restrict__ W, ushort* __restrict__ Whi, ushort* __restrict__ Wlo,
    int N, int K)
{
  __shared__ float Tt[64][65];
  const int tid = threadIdx.x;
  const int k0 = blockIdx.x << 6, n0 = blockIdx.y << 6;
  {
    int kk = tid >> 2, nb = (tid & 3) << 4;
#pragma unroll
    for (int q = 0; q < 4; q++) {
      float4 v = *(const float4*)(W + (long)(k0 + kk) * N + n0 + nb + 4 * q);
      Tt[kk][nb + 4*q + 0] = v.x; Tt[kk][nb + 4*q + 1] = v.y;
      Tt[kk][nb + 4*q + 2] = v.z; Tt[kk][nb + 4*q + 3] = v.w;
    }
  }
  __syncthreads();
  {
    int nn = tid >> 2, kb = (tid & 3) << 4;
    uint hw[8], lw[8];
#pragma unroll
    for (int q = 0; q < 8; q++) {
      float a = Tt[kb + 2*q][nn] * WSCALE, b = Tt[kb + 2*q + 1][nn] * WSCALE;
      ushort ha, la, hb, lb;
      split_f16(a, ha, la); split_f16(b, hb, lb);
      hw[q] = (uint)ha | ((uint)hb << 16); lw[q] = (uint)la | ((uint)lb << 16);
    }
    ushort* dh = Whi + (long)(n0 + nn) * K + k0 + kb;
    ushort* dl = Wlo + (long)(n0 + nn) * K + k0 + kb;
    ((uint4*)dh)[0] = make_uint4(hw[0], hw[1], hw[2], hw[3]);
    ((uint4*)dh)[1] = make_uint4(hw[4], hw[5], hw[6], hw[7]);
    ((uint4*)dl)[0] = make_uint4(lw[0], lw[1], lw[2], lw[3]);
    ((uint4*)dl)[1] = make_uint4(lw[4], lw[5], lw[6], lw[7]);
  }
}

// ---------------- split-f16 MFMA GEMM.
// AMODE 0: BM x BN tile, BK=32, 256 threads, 2-deep gload_lds pipeline with EARLY second
//          barrier: {vmcnt(LPS); bar; ds_read frags -> regs; lgkmcnt(0); bar;
//          stage(t+2 into freed buf); MFMA on regs}.  XCD-chunked bijective remap.
//          LPS = loads/thread/stage: A (BM==128 ? 2 : 1) + B (BN==128 ? 2 : BSPLIT ? 2 : 1).
// AMODE 1: BM=128, fused patchify (legacy single-buffer, pitch-32 layout).
// LDS per buffer: [rows][4 chunks of 16B], phys chunk = c ^ ((row>>1)&3), pitch 32.
// SOUT 0: fp32 C (opt RESID).  2: single-f16 out.  3: qkv single-f16 out.
template<int BM, int BN, int TM, int TN, int AMODE, bool ASPLIT, bool BSPLIT, bool BIAS, bool GELU, bool RESID, int SOUT>
__global__ __launch_bounds__(256) void gemm_mfma(
    const ushort* __restrict__ aHp, const ushort* __restrict__ aLp, int lda,
    const ushort* __restrict__ wtH, const ushort* __restrict__ wtL, int ldb,
    const float* __restrict__ bias, float* __restrict__ C,
    ushort* __restrict__ coH, ushort* __restrict__ vOut,
    const float* __restrict__ videos, const float* __restrict__ atok,
    int M, int N, int K)
{
  constexpr int NWC = BN / (TN * 16);
  constexpr int NBUF = (AMODE == 0) ? 2 : 1;
  __shared__ __align__(16) ushort sAh[NBUF * BM * 32];
  __shared__ __align__(16) ushort sAl[(AMODE == 1) ? 128 * 32 : 8];
  __shared__ __align__(16) ushort sBh[NBUF * BN * 32];
  __shared__ __align__(16) ushort sBl[BSPLIT ? NBUF * BN * 32 : 8];
  const int tid = threadIdx.x;
  int m0, n0;
  if (AMODE == 0) {
    // bijective XCD-chunked remap (m204): o%8 = XCD under round-robin dispatch
    const int gx = gridDim.x, gy = gridDim.y;
    const int nwg = gx * gy;
    const int o = blockIdx.y * gx + blockIdx.x;
    const int q = nwg >> 3, r = nwg & 7;
    const int xcd = o & 7, idx = o >> 3;
    const int wgid = (xcd < r ? xcd * (q + 1) : r * (q + 1) + (xcd - r) * q) + idx;
    const int mi = wgid / gy, ni = wgid - mi * gy;
    m0 = mi * BM; n0 = ni * BN;
  } else {
    m0 = blockIdx.x * BM; n0 = blockIdx.y * BN;
  }
  const int wid = tid >> 6, lane = tid & 63;
  const int lrow = lane & 15, lkg = lane >> 4;
  const int wr = wid / NWC, wc = wid % NWC;
  const int wrb = wr * TM * 16, wcb = wc * TN * 16;
  f32x4 acc[TM][TN];
#pragma unroll
  for (int mi = 0; mi < TM; mi++)
#pragma unroll
    for (int ni = 0; ni < TN; ni++) acc[mi][ni] = (f32x4){0.f, 0.f, 0.f, 0.f};

  if (AMODE == 0) {
    // ---- 2-deep pipeline, early-barrier register-fragment consume
    auto stage = [&](int k0, int d) {
      {
        int row = tid >> 2, cp = tid & 3;
        int csrc = cp ^ ((row >> 1) & 3);
        int ar = m0 + row; if (ar > M - 1) ar = M - 1;
        gload16(aHp + (long)ar * lda + k0 + csrc * 8, &sAh[d * (BM * 32) + tid * 8]);
      }
      if constexpr (BM == 128) {
        int chunk = tid + 256;
        int row = chunk >> 2, cp = chunk & 3;
        int csrc = cp ^ ((row >> 1) & 3);
        int ar = m0 + row; if (ar > M - 1) ar = M - 1;
        gload16(aHp + (long)ar * lda + k0 + csrc * 8, &sAh[d * (BM * 32) + chunk * 8]);
      }
      if (BN == 128) {
#pragma unroll
        for (int i = 0; i < 2; i++) {
          int chunk = tid + 256 * i;
          int row = chunk >> 2, cp = chunk & 3;
          int csrc = cp ^ ((row >> 1) & 3);
          gload16(wtH + (long)(n0 + row) * ldb + k0 + csrc * 8, &sBh[d * 4096 + chunk * 8]);
        }
      } else {
        int chunk = tid;
        int row = chunk >> 2, cp = chunk & 3;
        int csrc = cp ^ ((row >> 1) & 3);
        gload16(wtH + (long)(n0 + row) * ldb + k0 + csrc * 8, &sBh[d * 2048 + chunk * 8]);
        if (BSPLIT)
          gload16(wtL + (long)(n0 + row) * ldb + k0 + csrc * 8, &sBl[d * 2048 + chunk * 8]);
      }
    };
    const int nt = K >> 5;
    stage(0, 0);
    if (nt > 1) stage(32, 1);
    constexpr int LPS = ((BM == 128) ? 2 : 1) + ((BN == 128) ? 2 : (BSPLIT ? 2 : 1));
    for (int t = 0; t < nt; t++) {
      const int cur = t & 1;
      if (t + 1 < nt) {
        if constexpr (LPS == 4) {
          asm volatile("s_waitcnt vmcnt(4)" ::: "memory");
        } else if constexpr (LPS == 3) {
          asm volatile("s_waitcnt vmcnt(3)" ::: "memory");
        } else {
          asm volatile("s_waitcnt vmcnt(2)" ::: "memory");
        }
      } else {
        asm volatile("s_waitcnt vmcnt(0)" ::: "memory");
      }
      __builtin_amdgcn_s_barrier();
      const int aBase = cur * (BM * 32);
      const int bBase = cur * ((BN == 128) ? 4096 : 2048);
      // ---- read all fragments into registers
      half8 aHf[TM], bHf[TN], bLf[BSPLIT ? TN : 1];
#pragma unroll
      for (int mi = 0; mi < TM; mi++) {
        int ar = wrb + mi * 16 + lrow;
        int ac = (ar * 4 + (lkg ^ ((ar >> 1) & 3))) * 8;
        aHf[mi] = *(const half8*)&sAh[aBase + ac];
      }
#pragma unroll
      for (int ni = 0; ni < TN; ni++) {
        int br = wcb + ni * 16 + lrow;
        int bc = (br * 4 + (lkg ^ ((br >> 1) & 3))) * 8;
        bHf[ni] = *(const half8*)&sBh[bBase + bc];
        if (BSPLIT) bLf[ni] = *(const half8*)&sBl[bBase + bc];
      }
      asm volatile("s_waitcnt lgkmcnt(0)" ::: "memory");
      __builtin_amdgcn_sched_barrier(0);
      __builtin_amdgcn_s_barrier();
      // ---- buffer freed: issue tile t+2 into it NOW (2-iteration issue distance)
      if (t + 2 < nt) stage((t + 2) << 5, cur);
      // ---- MFMA purely on registers (overlaps the in-flight loads)
      __builtin_amdgcn_s_setprio(1);
#pragma unroll
      for (int ni = 0; ni < TN; ni++) {
        if (BSPLIT) {
#pragma unroll
          for (int mi = 0; mi < TM; mi++)
            acc[mi][ni] = __builtin_amdgcn_mfma_f32_16x16x32_f16(aHf[mi], bLf[ni], acc[mi][ni], 0, 0, 0);
        }
#pragma unroll
        for (int mi = 0; mi < TM; mi++)
          acc[mi][ni] = __builtin_amdgcn_mfma_f32_16x16x32_f16(aHf[mi], bHf[ni], acc[mi][ni], 0, 0, 0);
      }
      __builtin_amdgcn_s_setprio(0);
      __builtin_amdgcn_sched_barrier(0);
    }
  } else {
    // ---- legacy single-buffer path (fused patchify embed GEMM)
    const int rowa = tid >> 1, kba = (tid & 1) << 4;
    const int cb0 = (tid & 1) * 2;
    const int swa = (rowa >> 1) & 3;
    int bt_p = 0, s_p = 0;
    { int ar = m0 + rowa; bt_p = ar / 257; s_p = ar - bt_p * 257; }
    for (int k0 = 0; k0 < K; k0 += 32) {
      float4 vr[4];
#pragma unroll
      for (int q = 0; q < 4; q++) vr[q] = make_float4(0.f, 0.f, 0.f, 0.f);
#pragma unroll
      for (int q = 0; q < 4; q++) {
        int e4 = k0 + kba + 4 * q;
        if (s_p == 0) {
          vr[q] = *(const float4*)(atok + e4);
        } else {
          int p = s_p - 1, ph = p >> 4, pw = p & 15;
          int iq = e4 / 24, jc = e4 - iq * 24;
          vr[q] = *(const float4*)(videos + (long)bt_p * 49152 +
                                   (long)(ph * 8 + iq) * 384 + pw * 24 + jc);
        }
      }
      uint hw[8], lw[8];
#pragma unroll
      for (int q = 0; q < 4; q++) {
        ushort h0,l0,h1,l1,h2,l2,h3,l3;
        split_f16(vr[q].x, h0, l0); split_f16(vr[q].y, h1, l1);
        split_f16(vr[q].z, h2, l2); split_f16(vr[q].w, h3, l3);
        hw[2*q]   = (uint)h0 | ((uint)h1 << 16); lw[2*q]   = (uint)l0 | ((uint)l1 << 16);
        hw[2*q+1] = (uint)h2 | ((uint)h3 << 16); lw[2*q+1] = (uint)l2 | ((uint)l3 << 16);
      }
      *(uint4*)&sAh[(rowa * 4 + (cb0 ^ swa)) * 8]       = make_uint4(hw[0], hw[1], hw[2], hw[3]);
      *(uint4*)&sAh[(rowa * 4 + ((cb0 + 1) ^ swa)) * 8] = make_uint4(hw[4], hw[5], hw[6], hw[7]);
      *(uint4*)&sAl[(rowa * 4 + (cb0 ^ swa)) * 8]       = make_uint4(lw[0], lw[1], lw[2], lw[3]);
      *(uint4*)&sAl[(rowa * 4 + ((cb0 + 1) ^ swa)) * 8] = make_uint4(lw[4], lw[5], lw[6], lw[7]);
      {
#pragma unroll
        for (int i = 0; i < 2; i++) {
          int chunk = tid + 256 * i;
          int row = chunk >> 2, cp = chunk & 3;
          int csrc = cp ^ ((row >> 1) & 3);
          gload16(wtH + (long)(n0 + row) * ldb + k0 + csrc * 8, &sBh[chunk * 8]);
          if (BSPLIT)
            gload16(wtL + (long)(n0 + row) * ldb + k0 + csrc * 8, &sBl[chunk * 8]);
        }
      }
      __syncthreads();
      half8 aHf[TM], aLf[TM];
#pragma unroll
      for (int mi = 0; mi < TM; mi++) {
        int ar = wrb + mi * 16 + lrow;
        int ac = (ar * 4 + (lkg ^ ((ar >> 1) & 3))) * 8;
        aHf[mi] = *(const half8*)&sAh[ac];
        if (ASPLIT) aLf[mi] = *(const half8*)&sAl[ac];
      }
#pragma unroll
      for (int ni = 0; ni < TN; ni++) {
        int br = wcb + ni * 16 + lrow;
        int bc = (br * 4 + (lkg ^ ((br >> 1) & 3))) * 8;
        half8 bH = *(const half8*)&sBh[bc];
#pragma unroll
        for (int mi = 0; mi < TM; mi++) {
          if (ASPLIT)
            acc[mi][ni] = __builtin_amdgcn_mfma_f32_16x16x32_f16(aLf[mi], bH, acc[mi][ni], 0, 0, 0);
        }
        if (BSPLIT) {
          half8 bL = *(const half8*)&sBl[bc];
#pragma unroll
          for (int mi = 0; mi < TM; mi++)
            acc[mi][ni] = __builtin_amdgcn_mfma_f32_16x16x32_f16(aHf[mi], bL, acc[mi][ni], 0, 0, 0);
        }
#pragma unroll
        for (int mi = 0; mi < TM; mi++)
          acc[mi][ni] = __builtin_amdgcn_mfma_f32_16x16x32_f16(aHf[mi], bH, acc[mi][ni], 0, 0, 0);
      }
      __syncthreads();
    }
  }
  // ---- epilogue
#pragma unroll
  for (int mi = 0; mi < TM; mi++) {
    int rowg = m0 + wrb + mi * 16 + lkg * 4;
#pragma unroll
    for (int j = 0; j < 4; j++) {
      int r = rowg + j;
      if (r < M) {
#pragma unroll
        for (int ni = 0; ni < TN; ni++) {
          int cg = n0 + wcb + ni * 16 + lrow;
          float v = acc[mi][ni][j] * WINV;
          if (BIAS) v += bias[cg];
          if (GELU) v = gelu_f(v);
          if (SOUT == 2) {
            coH[(long)r * N + cg] = to_f16u(v);
          } else if (SOUT == 3) {
            if (cg < 1024) coH[(long)r * 1024 + cg] = to_f16u(v);
            else           vOut[(long)r * 512 + (cg - 1024)] = to_f16u(v);
          } else {
            long idx = (long)r * N + cg;
            if (RESID) C[idx] += v; else C[idx] = v;
          }
        }
      }
    }
  }
}

// ---------------- fused flash spatial attention over a chunk PAIR (32 frames).
__global__ __launch_bounds__(256) void flash_spatial(
    const ushort* __restrict__ qk, const ushort* __restrict__ v2,
    ushort* __restrict__ ctxc)
{
  __shared__ __align__(16) ushort sQ[64*72];
  __shared__ __align__(16) ushort sK[64*72];
  __shared__ __align__(16) ushort sV[64*72];               // V^T: [d][k]
  __shared__ __align__(16) ushort sP[64*72];
  const int tid = threadIdx.x;
  const int wid = tid >> 6, lane = tid & 63;
  const int lr = lane & 15, lg = lane >> 4;
  const int fh = blockIdx.y;                  // 0..255 (32 frames x 8 heads)
  const int fl = fh >> 3, hh = fh & 7;
  const int q0 = blockIdx.x * 64;
  const long rbase = (long)fl * S_;
  const int srow = tid >> 2, sc0 = (tid & 3) << 4;

  {
    int gr = q0 + srow;
    uint4 h0 = make_uint4(0,0,0,0), h1 = h0;
    if (gr < S_) {
      const ushort* sh = qk + (rbase + gr) * 1024 + hh * HD_ + sc0;
      h0 = ((const uint4*)sh)[0]; h1 = ((const uint4*)sh)[1];
    }
    uint4* dh = (uint4*)&sQ[srow*72 + sc0];
    dh[0] = h0; dh[1] = h1;
  }
  __syncthreads();
  half8 qH[2];
  {
    int qrl = wid * 16 + lr;
#pragma unroll
    for (int s = 0; s < 2; s++)
      qH[s] = *(const half8*)&sQ[qrl*72 + s*32 + lg*8];
  }
  f32x4 accS[5][4];
#pragma unroll
  for (int t = 0; t < 5; t++)
#pragma unroll
    for (int kc = 0; kc < 4; kc++) accS[t][kc] = (f32x4){0.f,0.f,0.f,0.f};

#pragma unroll
  for (int t = 0; t < 5; t++) {
    __syncthreads();
    {
      int gr = t*64 + srow;
      uint4 h0 = make_uint4(0,0,0,0), h1 = h0;
      if (gr < S_) {
        const ushort* sh = qk + (rbase + gr) * 1024 + 512 + hh * HD_ + sc0;
        h0 = ((const uint4*)sh)[0]; h1 = ((const uint4*)sh)[1];
      }
      uint4* dh = (uint4*)&sK[srow*72 + sc0];
      dh[0] = h0; dh[1] = h1;
    }
    __syncthreads();
#pragma unroll
    for (int s = 0; s < 2; s++) {
#pragma unroll
      for (int kc = 0; kc < 4; kc++) {
        int off = (kc*16 + lr)*72 + s*32 + lg*8;
        half8 bH = *(const half8*)&sK[off];
        accS[t][kc] = __builtin_amdgcn_mfma_f32_16x16x32_f16(qH[s], bH, accS[t][kc], 0,0,0);
      }
    }
  }

  float m[4] = {-3.0e38f, -3.0e38f, -3.0e38f, -3.0e38f};
#pragma unroll
  for (int t = 0; t < 5; t++)
#pragma unroll
    for (int kc = 0; kc < 4; kc++) {
      int kcol = t*64 + kc*16 + lr;
      if (kcol < S_) {
#pragma unroll
        for (int j = 0; j < 4; j++) m[j] = fmaxf(m[j], accS[t][kc][j] * 0.125f);
      }
    }
#pragma unroll
  for (int mk = 8; mk >= 1; mk >>= 1)
#pragma unroll
    for (int j = 0; j < 4; j++) m[j] = fmaxf(m[j], __shfl_xor(m[j], mk));
  float l[4] = {0.f, 0.f, 0.f, 0.f};
#pragma unroll
  for (int t = 0; t < 5; t++)
#pragma unroll
    for (int kc = 0; kc < 4; kc++) {
      int kcol = t*64 + kc*16 + lr;
#pragma unroll
      for (int j = 0; j < 4; j++) {
        float p = (kcol < S_) ? expf(accS[t][kc][j]*0.125f - m[j]) : 0.f;
        accS[t][kc][j] = p;
        l[j] += p;
      }
    }
#pragma unroll
  for (int mk = 8; mk >= 1; mk >>= 1)
#pragma unroll
    for (int j = 0; j < 4; j++) l[j] += __shfl_xor(l[j], mk);

  f32x4 accO[4];
#pragma unroll
  for (int dc = 0; dc < 4; dc++) accO[dc] = (f32x4){0.f,0.f,0.f,0.f};
#pragma unroll
  for (int t = 0; t < 5; t++) {
#pragma unroll
    for (int kc = 0; kc < 4; kc++)
#pragma unroll
      for (int j = 0; j < 4; j++) {
        int addr = (wid*16 + lg*4 + j)*72 + kc*16 + lr;
        sP[addr] = to_f16u(accS[t][kc][j]);
      }
    __syncthreads();
    {
      int gr = t*64 + srow;
      ushort tmp[16];
      uint4 a = make_uint4(0,0,0,0), b = a;
      if (gr < S_) {
        const ushort* src = v2 + (rbase + gr) * 512 + hh * HD_ + sc0;
        a = ((const uint4*)src)[0]; b = ((const uint4*)src)[1];
      }
      *(uint4*)&tmp[0] = a; *(uint4*)&tmp[8] = b;
#pragma unroll
      for (int e = 0; e < 16; e++) sV[(sc0 + e)*72 + srow] = tmp[e];
    }
    __syncthreads();
#pragma unroll
    for (int s = 0; s < 2; s++) {
      int poff = (wid*16 + lr)*72 + s*32 + lg*8;
      half8 pH = *(const half8*)&sP[poff];
#pragma unroll
      for (int dc = 0; dc < 4; dc++) {
        int voff = (dc*16 + lr)*72 + s*32 + lg*8;
        half8 vH = *(const half8*)&sV[voff];
        accO[dc] = __builtin_amdgcn_mfma_f32_16x16x32_f16(pH, vH, accO[dc], 0,0,0);
      }
    }
  }
#pragma unroll
  for (int j = 0; j < 4; j++) {
    int grow = q0 + wid*16 + lg*4 + j;
    if (grow < S_) {
      float inv = 1.0f / l[j];
#pragma unroll
      for (int dc = 0; dc < 4; dc++) {
        float o = accO[dc][j] * inv;
        long idx = (rbase + grow) * 512 + hh*64 + dc*16 + lr;
        ctxc[idx] = to_f16u(o);
      }
    }
  }
}

// ---------------- temporal causal attention over a chunk pair (2 batches), single-f16 qkv
__global__ __launch_bounds__(64) void temporal_attn(
    const ushort* __restrict__ qk, const ushort* __restrict__ v2,
    ushort* __restrict__ ctxc)
{
  const int gid = blockIdx.x;           // b2*2056 + s*8+h
  const int b2 = gid / (S_ * NH_);
  const int rem = gid - b2 * S_ * NH_;
  const int hh = rem & 7;
  const int s = rem >> 3;
  const int lane = threadIdx.x;
  __shared__ float Qs[16][65];
  __shared__ float Ks[16][65];
  __shared__ float Pm[16][17];
  float v[16];
  const long rbase = (long)b2 * CH + s;
#pragma unroll
  for (int t = 0; t < 16; t++) {
    long row = rbase + (long)t * S_;
    long qoff = row * 1024 + hh * HD_ + lane;
    Qs[t][lane] = from_f16u(qk[qoff]);
    Ks[t][lane] = from_f16u(qk[qoff + 512]);
    v[t] = from_f16u(v2[row * 512 + hh * HD_ + lane]);
  }
  __syncthreads();
  const int rq = lane >> 2, c0 = lane & 3;
  float sc[4];
#pragma unroll
  for (int j = 0; j < 4; j++) {
    int c = c0 + (j << 2);
    if (c <= rq) {
      float d = 0.f;
#pragma unroll
      for (int k = 0; k < 64; k++) d = fmaf(Qs[rq][k], Ks[c][k], d);
      sc[j] = d * 0.125f;
    } else sc[j] = -3.0e38f;
  }
  float mx = fmaxf(fmaxf(sc[0], sc[1]), fmaxf(sc[2], sc[3]));
  mx = fmaxf(mx, __shfl_xor(mx, 1));
  mx = fmaxf(mx, __shfl_xor(mx, 2));
  float sum = 0.f;
#pragma unroll
  for (int j = 0; j < 4; j++) { sc[j] = expf(sc[j] - mx); sum += sc[j]; }
  sum += __shfl_xor(sum, 1);
  sum += __shfl_xor(sum, 2);
  float inv = 1.0f / sum;
#pragma unroll
  for (int j = 0; j < 4; j++) Pm[rq][c0 + (j << 2)] = sc[j] * inv;
  __syncthreads();
#pragma unroll
  for (int t = 0; t < 16; t++) {
    float o = 0.f;
#pragma unroll
    for (int k = 0; k < 16; k++) o = fmaf(Pm[t][k], v[k], o);
    long idx = (rbase + (long)t * S_) * 512 + hh * HD_ + lane;
    ctxc[idx] = to_f16u(o);
  }
}

// ---------------- final LN + projection + VQ argmin + action head (1024 threads)
__global__ __launch_bounds__(1024) void final_vq(
    const float* __restrict__ tok, const float* __restrict__ lnf_g,
    const float* __restrict__ lnf_b, const float* __restrict__ out_w,
    const float* __restrict__ codebook, const float* __restrict__ action_w,
    float* __restrict__ out)
{
  __shared__ float xs[512];
  __shared__ float red[16];
  __shared__ float zp[1024];
  __shared__ float zs[64];
  __shared__ float bd[16];
  __shared__ int   bi[16];
  __shared__ int   bsel;
  const int b = blockIdx.x / 15, tm = blockIdx.x % 15;
  const int tid = threadIdx.x;
  const int wv = tid >> 6, lane = tid & 63;
  const float* xr = tok + ((long)(b * T_ + tm + 1) * S_) * D_;   // s = 0
  float x0 = (tid < 512) ? xr[tid] : 0.f;
  float s = warp_rsum(x0);
  if (lane == 0) red[wv] = s;
  __syncthreads();
  float tot = 0.f;
#pragma unroll
  for (int w = 0; w < 16; w++) tot += red[w];
  float mean = tot * (1.0f / 512.0f);
  float dv = (tid < 512) ? (x0 - mean) : 0.f;
  __syncthreads();
  float ss = warp_rsum(dv * dv);
  if (lane == 0) red[wv] = ss;
  __syncthreads();
  float vtot = 0.f;
#pragma unroll
  for (int w = 0; w < 16; w++) vtot += red[w];
  float rstd = rsqrtf(vtot * (1.0f / 512.0f) + 1e-5f);
  if (tid < 512) xs[tid] = dv * rstd * lnf_g[tid] + lnf_b[tid];
  __syncthreads();
  // z projection: output o = tid&63, partial p = tid>>6 over d in [p*32, p*32+32)
  {
    int o = tid & 63, p = tid >> 6;
    int d0 = p * 32;
    float z = 0.f;
#pragma unroll 8
    for (int k = 0; k < 32; k++) z = fmaf(xs[d0 + k], out_w[(long)(d0 + k) * 64 + o], z);
    zp[tid] = z;
  }
  __syncthreads();
  if (tid < 64) {
    float z = 0.f;
#pragma unroll
    for (int p = 0; p < 16; p++) z += zp[p * 64 + tid];
    zs[tid] = z;
  }
  __syncthreads();
  // codebook scan: 4 codes/thread, float4 loads, scalar-identical accumulation order
  float best = 3.0e38f; int bidx = 0;
  for (int c = tid; c < 4096; c += 1024) {
    const float4* cp = (const float4*)(codebook + (long)c * 64);
    float dot = 0.f, cn = 0.f;
#pragma unroll
    for (int k = 0; k < 16; k++) {
      float4 w = cp[k];
      dot = fmaf(zs[4*k + 0], w.x, dot); cn = fmaf(w.x, w.x, cn);
      dot = fmaf(zs[4*k + 1], w.y, dot); cn = fmaf(w.y, w.y, cn);
      dot = fmaf(zs[4*k + 2], w.z, dot); cn = fmaf(w.z, w.z, cn);
      dot = fmaf(zs[4*k + 3], w.w, dot); cn = fmaf(w.w, w.w, cn);
    }
    float dist = cn - 2.0f * dot;
    if (dist < best) { best = dist; bidx = c; }
  }
  // wave argmin (ties -> smaller index, matching argmin semantics)
#pragma unroll
  for (int mk = 32; mk >= 1; mk >>= 1) {
    float ob = __shfl_xor(best, mk);
    int   oi = __shfl_xor(bidx, mk);
    if (ob < best || (ob == best && oi < bidx)) { best = ob; bidx = oi; }
  }
  if (lane == 0) { bd[wv] = best; bi[wv] = bidx; }
  __syncthreads();
  if (tid == 0) {
    float bb = bd[0]; int ii = bi[0];
#pragma unroll
    for (int w = 1; w < 16; w++)
      if (bd[w] < bb || (bd[w] == bb && bi[w] < ii)) { bb = bd[w]; ii = bi[w]; }
    bsel = ii;
  }
  __syncthreads();
  int idx = bsel;
  if (tid < 16) {
    const float* cp = codebook + (long)idx * 64;
    float o = 0.f;
#pragma unroll
    for (int k = 0; k < 64; k++) o = fmaf(cp[k], action_w[k * 16 + tid], o);
    out[((long)(b * 15 + tm)) * 16 + tid] = o;
  }
}

extern "C" void kernel_launch(void* const* d_in, const int* in_sizes, int n_in,
                              void* d_out, int out_size, void* d_ws, size_t ws_size,
                              hipStream_t stream)
{
  const float* videos       = (const float*)d_in[0];
  const float* patch_w      = (const float*)d_in[1];
  const float* patch_b      = (const float*)d_in[2];
  const float* action_token = (const float*)d_in[3];
  const float* ln1_g  = (const float*)d_in[4];
  const float* ln1_b  = (const float*)d_in[5];
  const float* wqkv_s = (const float*)d_in[6];
  const float* wo_s   = (const float*)d_in[7];
  const float* ln2_g  = (const float*)d_in[8];
  const float* ln2_b  = (const float*)d_in[9];
  const float* wqkv_t = (const float*)d_in[10];
  const float* wo_t   = (const float*)d_in[11];
  const float* ln3_g  = (const float*)d_in[12];
  const float* ln3_b  = (const float*)d_in[13];
  const float* mlp_w1 = (const float*)d_in[14];
  const float* mlp_b1 = (const float*)d_in[15];
  const float* mlp_w2 = (const float*)d_in[16];
  const float* mlp_b2 = (const float*)d_in[17];
  const float* lnf_g  = (const float*)d_in[18];
  const float* lnf_b  = (const float*)d_in[19];
  const float* out_w  = (const float*)d_in[20];
  const float* codebook = (const float*)d_in[21];
  const float* action_w = (const float*)d_in[22];
  float* out = (float*)d_out;

  // ---- workspace layout (floats), total 29,466,624 f = 117.9 MB (< proven 135)
  float* ws    = (float*)d_ws;
  float* tok   = ws;                                  // 16,842,752
  ushort* wt1h = (ushort*)(ws + 16842752);            // 1,048,576 f-eq (hi+lo)
  ushort* wt1l = wt1h + 1048576;
  ushort* wt2h = (ushort*)(ws + 17891328);            // 1,048,576 f-eq
  ushort* wt2l = wt2h + 1048576;
  ushort* aH   = (ushort*)(ws + 18939904);            // PCH x 512 single f16 = 2,105,344 f-eq
  ushort* qk   = (ushort*)(ws + 21045248);            // PCH x 1024 single = 4,210,688 f-eq
  ushort* v2   = (ushort*)(ws + 25255936);            // PCH x 512 single  = 2,105,344 f-eq
  ushort* ctx  = (ushort*)(ws + 27361280);            // PCH x 512 single  = 2,105,344 f-eq
  ushort* mid  = qk;                                  // MLP mid (PCH x 2048) spans qk+v2+ctx

  // ---- patchify fused into embed GEMM (full 3-MFMA, legacy path)
  convert_w<<<dim3(3, 8), 256, 0, stream>>>(patch_w, wt1h, wt1l, 512, 192);
  gemm_mfma<128,128,4,4,1,true,true,true,false,false,0><<<dim3(257, 4), 256, 0, stream>>>(
      nullptr, nullptr, 0, wt1h, wt1l, 192, patch_b, tok, nullptr, nullptr,
      videos, action_token, NTOK, 512, 192);

  for (int L = 0; L < 4; L++) {
    // ================= spatial attention (4 chunk pairs) =================
    convert_w<<<dim3(8, 24), 256, 0, stream>>>(wqkv_s + (long)L*512*1536, wt1h, wt1l, 1536, 512);
    convert_w<<<dim3(8, 8),  256, 0, stream>>>(wo_s   + (long)L*512*512,  wt2h, wt2l, 512, 512);
    for (int pr = 0; pr < 4; pr++) {
      long r0 = (long)pr * PCH;
      ln_single<<<PCH / 4, 256, 0, stream>>>(tok + r0 * D_, ln1_g + L*512, ln1_b + L*512, aH);
      gemm_mfma<64,128,2,4,0,false,false,false,false,false,3><<<dim3(129, 12), 256, 0, stream>>>(
          aH, nullptr, 512, wt1h, wt1l, 512, nullptr, nullptr,
          qk, v2, nullptr, nullptr, PCH, 1536, 512);
      flash_spatial<<<dim3(5, 256), 256, 0, stream>>>(qk, v2, ctx);
      gemm_mfma<64,64,1,4,0,false,false,false,false,true,0><<<dim3(129, 8), 256, 0, stream>>>(
          ctx, nullptr, 512, wt2h, wt2l, 512, nullptr, tok + r0 * D_,
          nullptr, nullptr, nullptr, nullptr, PCH, 512, 512);
    }
    // ================= temporal attention (4 chunk pairs) =================
    convert_w<<<dim3(8, 24), 256, 0, stream>>>(wqkv_t + (long)L*512*1536, wt1h, wt1l, 1536, 512);
    convert_w<<<dim3(8, 8),  256, 0, stream>>>(wo_t   + (long)L*512*512,  wt2h, wt2l, 512, 512);
    for (int pr = 0; pr < 4; pr++) {
      long r0 = (long)pr * PCH;
      ln_single<<<PCH / 4, 256, 0, stream>>>(tok + r0 * D_, ln2_g + L*512, ln2_b + L*512, aH);
      gemm_mfma<64,128,2,4,0,false,false,false,false,false,3><<<dim3(129, 12), 256, 0, stream>>>(
          aH, nullptr, 512, wt1h, wt1l, 512, nullptr, nullptr,
          qk, v2, nullptr, nullptr, PCH, 1536, 512);
      temporal_attn<<<2 * S_ * NH_, 64, 0, stream>>>(qk, v2, ctx);
      gemm_mfma<64,64,1,4,0,false,false,false,false,true,0><<<dim3(129, 8), 256, 0, stream>>>(
          ctx, nullptr, 512, wt2h, wt2l, 512, nullptr, tok + r0 * D_,
          nullptr, nullptr, nullptr, nullptr, PCH, 512, 512);
    }
    // ================= MLP (4 M-chunks of 8224 rows) =================
    convert_w<<<dim3(8, 32), 256, 0, stream>>>(mlp_w1 + (long)L*512*2048, wt1h, wt1l, 2048, 512);
    convert_w<<<dim3(32, 8), 256, 0, stream>>>(mlp_w2 + (long)L*2048*512, wt2h, wt2l, 512, 2048);
    for (int c = 0; c < 4; c++) {
      long m0r = (long)c * PCH;
      ln_single<<<PCH / 4, 256, 0, stream>>>(tok + m0r * D_, ln3_g + L*512, ln3_b + L*512, aH);
      gemm_mfma<64,128,2,4,0,false,false,true,true,false,2><<<dim3(129, 16), 256, 0, stream>>>(
          aH, nullptr, 512, wt1h, wt1l, 512, mlp_b1 + (long)L*2048, nullptr, mid, nullptr,
          nullptr, nullptr, PCH, FFN_, 512);
      gemm_mfma<64,64,1,4,0,false,false,true,false,true,0><<<dim3(129, 8), 256, 0, stream>>>(
          mid, nullptr, 2048, wt2h, wt2l, 2048, mlp_b2 + (long)L*512, tok + m0r * D_,
          nullptr, nullptr, nullptr, nullptr, PCH, 512, 2048);
    }
  }

  final_vq<<<B_ * (T_ - 1), 1024, 0, stream>>>(tok, lnf_g, lnf_b, out_w, codebook, action_w, out);
}

// Round 27
// 3703.909 us; speedup vs baseline: 1.3160x; 1.0347x over previous
//
#include <hip/hip_runtime.h>
#include <hip/hip_bf16.h>

#define B_ 8
#define T_ 16
#define S_ 257
#define D_ 512
#define FFN_ 2048
#define NH_ 8
#define HD_ 64
#define PTD_ 192
#define NTOK (B_*T_*S_)        // 32896
#define CH 4112                // 16 frames * 257 rows per chunk
#define PCH 8224               // chunk pair rows
#define WSCALE 64.0f
#define WINV 0.015625f

typedef unsigned int uint;
typedef unsigned short ushort;
typedef __attribute__((ext_vector_type(8))) _Float16 half8;
typedef __attribute__((ext_vector_type(4))) float f32x4;

__device__ __forceinline__ float warp_rsum(float v){
#pragma unroll
  for (int m = 32; m >= 1; m >>= 1) v += __shfl_xor(v, m);
  return v;
}
__device__ __forceinline__ float gelu_f(float x){
  float x3 = x*x*x;
  return 0.5f*x*(1.0f + tanhf(0.7978845608028654f*(x + 0.044715f*x3)));
}
// split fp32 -> f16 hi + f16 lo (RNE).
__device__ __forceinline__ void split_f16(float f, ushort& h, ushort& l){
  _Float16 hh = (_Float16)f;
  float hf = (float)hh;
  _Float16 ll = (_Float16)(f - hf);
  h = __builtin_bit_cast(ushort, hh);
  l = __builtin_bit_cast(ushort, ll);
}
__device__ __forceinline__ ushort to_f16u(float f){
  return __builtin_bit_cast(ushort, (_Float16)f);
}
__device__ __forceinline__ float from_f16u(ushort u){
  return (float)__builtin_bit_cast(_Float16, u);
}
// async global->LDS 16B (lane-linear LDS dest, per-lane global src)
__device__ __forceinline__ void gload16(const ushort* g, ushort* l){
  __builtin_amdgcn_global_load_lds(
      (const __attribute__((address_space(1))) void*)(g),
      (__attribute__((address_space(3))) void*)(l),
      16, 0, 0);
}

// ---------------- fused LN + single-f16 cast:  aH[row][512] = f16(LN(x[row]))
__global__ __launch_bounds__(256) void ln_single(
    const float* __restrict__ x, const float* __restrict__ g,
    const float* __restrict__ bb, ushort* __restrict__ aH)
{
  int row = blockIdx.x * 4 + (threadIdx.x >> 6);
  int lane = threadIdx.x & 63;
  const float* xr = x + (long)row * D_;
  float4 u0 = *(const float4*)(xr + lane * 8);
  float4 u1 = *(const float4*)(xr + lane * 8 + 4);
  float s = u0.x + u0.y + u0.z + u0.w + u1.x + u1.y + u1.z + u1.w;
  s = warp_rsum(s);
  float mean = s * (1.0f / 512.0f);
  float d[8] = {u0.x - mean, u0.y - mean, u0.z - mean, u0.w - mean,
                u1.x - mean, u1.y - mean, u1.z - mean, u1.w - mean};
  float ss = 0.f;
#pragma unroll
  for (int i = 0; i < 8; i++) ss = fmaf(d[i], d[i], ss);
  ss = warp_rsum(ss);
  float rstd = rsqrtf(ss * (1.0f / 512.0f) + 1e-5f);
  int c = lane * 8;
  float4 g0 = *(const float4*)(g + c), g1 = *(const float4*)(g + c + 4);
  float4 b0 = *(const float4*)(bb + c), b1 = *(const float4*)(bb + c + 4);
  float y[8] = {d[0]*rstd*g0.x + b0.x, d[1]*rstd*g0.y + b0.y,
                d[2]*rstd*g0.z + b0.z, d[3]*rstd*g0.w + b0.w,
                d[4]*rstd*g1.x + b1.x, d[5]*rstd*g1.y + b1.y,
                d[6]*rstd*g1.z + b1.z, d[7]*rstd*g1.w + b1.w};
  ushort h[8];
#pragma unroll
  for (int i = 0; i < 8; i++) h[i] = to_f16u(y[i]);
  uint4 hv = make_uint4((uint)h[0] | ((uint)h[1] << 16), (uint)h[2] | ((uint)h[3] << 16),
                        (uint)h[4] | ((uint)h[5] << 16), (uint)h[6] | ((uint)h[7] << 16));
  *(uint4*)(aH + (long)row * 512 + c) = hv;
}

// ---------------- weight transpose + split:  W[K][N] f32 -> (W*64) as Whi[N][K], Wlo[N][K] f16
__global__ __launch_bounds__(256) void convert_w(
    const float* __restrict__ W, ushort* __restrict__ Whi, ushort* __restrict__ Wlo,
    int N, int K)
{
  __shared__ float Tt[64][65];
  const int tid = threadIdx.x;
  const int k0 = blockIdx.x << 6, n0 = blockIdx.y << 6;
  {
    int kk = tid >> 2, nb = (tid & 3) << 4;
#pragma unroll
    for (int q = 0; q < 4; q++) {
      float4 v = *(const float4*)(W + (long)(k0 + kk) * N + n0 + nb + 4 * q);
      Tt[kk][nb + 4*q + 0] = v.x; Tt[kk][nb + 4*q + 1] = v.y;
      Tt[kk][nb + 4*q + 2] = v.z; Tt[kk][nb + 4*q + 3] = v.w;
    }
  }
  __syncthreads();
  {
    int nn = tid >> 2, kb = (tid & 3) << 4;
    uint hw[8], lw[8];
#pragma unroll
    for (int q = 0; q < 8; q++) {
      float a = Tt[kb + 2*q][nn] * WSCALE, b = Tt[kb + 2*q + 1][nn] * WSCALE;
      ushort ha, la, hb, lb;
      split_f16(a, ha, la); split_f16(b, hb, lb);
      hw[q] = (uint)ha | ((uint)hb << 16); lw[q] = (uint)la | ((uint)lb << 16);
    }
    ushort* dh = Whi + (long)(n0 + nn) * K + k0 + kb;
    ushort* dl = Wlo + (long)(n0 + nn) * K + k0 + kb;
    ((uint4*)dh)[0] = make_uint4(hw[0], hw[1], hw[2], hw[3]);
    ((uint4*)dh)[1] = make_uint4(hw[4], hw[5], hw[6], hw[7]);
    ((uint4*)dl)[0] = make_uint4(lw[0], lw[1], lw[2], lw[3]);
    ((uint4*)dl)[1] = make_uint4(lw[4], lw[5], lw[6], lw[7]);
  }
}

// ---------------- split-f16 MFMA GEMM.
// AMODE 0: BM x BN tile, BK=32, 256 threads, 2-deep gload_lds pipeline with EARLY second
//          barrier: {vmcnt(LPS); bar; ds_read frags -> regs; lgkmcnt(0); bar;
//          stage(t+2 into freed buf); MFMA on regs}.  XCD-chunked bijective remap.
//          LPS = loads/thread/stage: A (BM==128 ? 2 : 1) + B (BN==128 ? 2 : BSPLIT ? 2 : 1).
// AMODE 1: BM=128, fused patchify (legacy single-buffer, pitch-32 layout).
// LDS per buffer: [rows][4 chunks of 16B], phys chunk = c ^ ((row>>1)&3), pitch 32.
// SOUT 0: fp32 C (opt RESID).  2: single-f16 out.  3: qkv single-f16 out.
template<int BM, int BN, int TM, int TN, int AMODE, bool ASPLIT, bool BSPLIT, bool BIAS, bool GELU, bool RESID, int SOUT>
__global__ __launch_bounds__(256) void gemm_mfma(
    const ushort* __restrict__ aHp, const ushort* __restrict__ aLp, int lda,
    const ushort* __restrict__ wtH, const ushort* __restrict__ wtL, int ldb,
    const float* __restrict__ bias, float* __restrict__ C,
    ushort* __restrict__ coH, ushort* __restrict__ vOut,
    const float* __restrict__ videos, const float* __restrict__ atok,
    int M, int N, int K)
{
  constexpr int NWC = BN / (TN * 16);
  constexpr int NBUF = (AMODE == 0) ? 2 : 1;
  __shared__ __align__(16) ushort sAh[NBUF * BM * 32];
  __shared__ __align__(16) ushort sAl[(AMODE == 1) ? 128 * 32 : 8];
  __shared__ __align__(16) ushort sBh[NBUF * BN * 32];
  __shared__ __align__(16) ushort sBl[BSPLIT ? NBUF * BN * 32 : 8];
  const int tid = threadIdx.x;
  int m0, n0;
  if (AMODE == 0) {
    // bijective XCD-chunked remap (m204): o%8 = XCD under round-robin dispatch
    const int gx = gridDim.x, gy = gridDim.y;
    const int nwg = gx * gy;
    const int o = blockIdx.y * gx + blockIdx.x;
    const int q = nwg >> 3, r = nwg & 7;
    const int xcd = o & 7, idx = o >> 3;
    const int wgid = (xcd < r ? xcd * (q + 1) : r * (q + 1) + (xcd - r) * q) + idx;
    const int mi = wgid / gy, ni = wgid - mi * gy;
    m0 = mi * BM; n0 = ni * BN;
  } else {
    m0 = blockIdx.x * BM; n0 = blockIdx.y * BN;
  }
  const int wid = tid >> 6, lane = tid & 63;
  const int lrow = lane & 15, lkg = lane >> 4;
  const int wr = wid / NWC, wc = wid % NWC;
  const int wrb = wr * TM * 16, wcb = wc * TN * 16;
  f32x4 acc[TM][TN];
#pragma unroll
  for (int mi = 0; mi < TM; mi++)
#pragma unroll
    for (int ni = 0; ni < TN; ni++) acc[mi][ni] = (f32x4){0.f, 0.f, 0.f, 0.f};

  if (AMODE == 0) {
    // ---- 2-deep pipeline, early-barrier register-fragment consume
    auto stage = [&](int k0, int d) {
      {
        int row = tid >> 2, cp = tid & 3;
        int csrc = cp ^ ((row >> 1) & 3);
        int ar = m0 + row; if (ar > M - 1) ar = M - 1;
        gload16(aHp + (long)ar * lda + k0 + csrc * 8, &sAh[d * (BM * 32) + tid * 8]);
      }
      if constexpr (BM == 128) {
        int chunk = tid + 256;
        int row = chunk >> 2, cp = chunk & 3;
        int csrc = cp ^ ((row >> 1) & 3);
        int ar = m0 + row; if (ar > M - 1) ar = M - 1;
        gload16(aHp + (long)ar * lda + k0 + csrc * 8, &sAh[d * (BM * 32) + chunk * 8]);
      }
      if (BN == 128) {
#pragma unroll
        for (int i = 0; i < 2; i++) {
          int chunk = tid + 256 * i;
          int row = chunk >> 2, cp = chunk & 3;
          int csrc = cp ^ ((row >> 1) & 3);
          gload16(wtH + (long)(n0 + row) * ldb + k0 + csrc * 8, &sBh[d * 4096 + chunk * 8]);
        }
      } else {
        int chunk = tid;
        int row = chunk >> 2, cp = chunk & 3;
        int csrc = cp ^ ((row >> 1) & 3);
        gload16(wtH + (long)(n0 + row) * ldb + k0 + csrc * 8, &sBh[d * 2048 + chunk * 8]);
        if (BSPLIT)
          gload16(wtL + (long)(n0 + row) * ldb + k0 + csrc * 8, &sBl[d * 2048 + chunk * 8]);
      }
    };
    const int nt = K >> 5;
    stage(0, 0);
    if (nt > 1) stage(32, 1);
    constexpr int LPS = ((BM == 128) ? 2 : 1) + ((BN == 128) ? 2 : (BSPLIT ? 2 : 1));
    for (int t = 0; t < nt; t++) {
      const int cur = t & 1;
      if (t + 1 < nt) {
        if constexpr (LPS == 4) {
          asm volatile("s_waitcnt vmcnt(4)" ::: "memory");
        } else if constexpr (LPS == 3) {
          asm volatile("s_waitcnt vmcnt(3)" ::: "memory");
        } else {
          asm volatile("s_waitcnt vmcnt(2)" ::: "memory");
        }
      } else {
        asm volatile("s_waitcnt vmcnt(0)" ::: "memory");
      }
      __builtin_amdgcn_s_barrier();
      const int aBase = cur * (BM * 32);
      const int bBase = cur * ((BN == 128) ? 4096 : 2048);
      // ---- read all fragments into registers
      half8 aHf[TM], bHf[TN], bLf[BSPLIT ? TN : 1];
#pragma unroll
      for (int mi = 0; mi < TM; mi++) {
        int ar = wrb + mi * 16 + lrow;
        int ac = (ar * 4 + (lkg ^ ((ar >> 1) & 3))) * 8;
        aHf[mi] = *(const half8*)&sAh[aBase + ac];
      }
#pragma unroll
      for (int ni = 0; ni < TN; ni++) {
        int br = wcb + ni * 16 + lrow;
        int bc = (br * 4 + (lkg ^ ((br >> 1) & 3))) * 8;
        bHf[ni] = *(const half8*)&sBh[bBase + bc];
        if (BSPLIT) bLf[ni] = *(const half8*)&sBl[bBase + bc];
      }
      asm volatile("s_waitcnt lgkmcnt(0)" ::: "memory");
      __builtin_amdgcn_sched_barrier(0);
      __builtin_amdgcn_s_barrier();
      // ---- buffer freed: issue tile t+2 into it NOW (2-iteration issue distance)
      if (t + 2 < nt) stage((t + 2) << 5, cur);
      // ---- MFMA purely on registers (overlaps the in-flight loads)
      __builtin_amdgcn_s_setprio(1);
#pragma unroll
      for (int ni = 0; ni < TN; ni++) {
        if (BSPLIT) {
#pragma unroll
          for (int mi = 0; mi < TM; mi++)
            acc[mi][ni] = __builtin_amdgcn_mfma_f32_16x16x32_f16(aHf[mi], bLf[ni], acc[mi][ni], 0, 0, 0);
        }
#pragma unroll
        for (int mi = 0; mi < TM; mi++)
          acc[mi][ni] = __builtin_amdgcn_mfma_f32_16x16x32_f16(aHf[mi], bHf[ni], acc[mi][ni], 0, 0, 0);
      }
      __builtin_amdgcn_s_setprio(0);
      __builtin_amdgcn_sched_barrier(0);
    }
  } else {
    // ---- legacy single-buffer path (fused patchify embed GEMM)
    const int rowa = tid >> 1, kba = (tid & 1) << 4;
    const int cb0 = (tid & 1) * 2;
    const int swa = (rowa >> 1) & 3;
    int bt_p = 0, s_p = 0;
    { int ar = m0 + rowa; bt_p = ar / 257; s_p = ar - bt_p * 257; }
    for (int k0 = 0; k0 < K; k0 += 32) {
      float4 vr[4];
#pragma unroll
      for (int q = 0; q < 4; q++) vr[q] = make_float4(0.f, 0.f, 0.f, 0.f);
#pragma unroll
      for (int q = 0; q < 4; q++) {
        int e4 = k0 + kba + 4 * q;
        if (s_p == 0) {
          vr[q] = *(const float4*)(atok + e4);
        } else {
          int p = s_p - 1, ph = p >> 4, pw = p & 15;
          int iq = e4 / 24, jc = e4 - iq * 24;
          vr[q] = *(const float4*)(videos + (long)bt_p * 49152 +
                                   (long)(ph * 8 + iq) * 384 + pw * 24 + jc);
        }
      }
      uint hw[8], lw[8];
#pragma unroll
      for (int q = 0; q < 4; q++) {
        ushort h0,l0,h1,l1,h2,l2,h3,l3;
        split_f16(vr[q].x, h0, l0); split_f16(vr[q].y, h1, l1);
        split_f16(vr[q].z, h2, l2); split_f16(vr[q].w, h3, l3);
        hw[2*q]   = (uint)h0 | ((uint)h1 << 16); lw[2*q]   = (uint)l0 | ((uint)l1 << 16);
        hw[2*q+1] = (uint)h2 | ((uint)h3 << 16); lw[2*q+1] = (uint)l2 | ((uint)l3 << 16);
      }
      *(uint4*)&sAh[(rowa * 4 + (cb0 ^ swa)) * 8]       = make_uint4(hw[0], hw[1], hw[2], hw[3]);
      *(uint4*)&sAh[(rowa * 4 + ((cb0 + 1) ^ swa)) * 8] = make_uint4(hw[4], hw[5], hw[6], hw[7]);
      *(uint4*)&sAl[(rowa * 4 + (cb0 ^ swa)) * 8]       = make_uint4(lw[0], lw[1], lw[2], lw[3]);
      *(uint4*)&sAl[(rowa * 4 + ((cb0 + 1) ^ swa)) * 8] = make_uint4(lw[4], lw[5], lw[6], lw[7]);
      {
#pragma unroll
        for (int i = 0; i < 2; i++) {
          int chunk = tid + 256 * i;
          int row = chunk >> 2, cp = chunk & 3;
          int csrc = cp ^ ((row >> 1) & 3);
          gload16(wtH + (long)(n0 + row) * ldb + k0 + csrc * 8, &sBh[chunk * 8]);
          if (BSPLIT)
            gload16(wtL + (long)(n0 + row) * ldb + k0 + csrc * 8, &sBl[chunk * 8]);
        }
      }
      __syncthreads();
      half8 aHf[TM], aLf[TM];
#pragma unroll
      for (int mi = 0; mi < TM; mi++) {
        int ar = wrb + mi * 16 + lrow;
        int ac = (ar * 4 + (lkg ^ ((ar >> 1) & 3))) * 8;
        aHf[mi] = *(const half8*)&sAh[ac];
        if (ASPLIT) aLf[mi] = *(const half8*)&sAl[ac];
      }
#pragma unroll
      for (int ni = 0; ni < TN; ni++) {
        int br = wcb + ni * 16 + lrow;
        int bc = (br * 4 + (lkg ^ ((br >> 1) & 3))) * 8;
        half8 bH = *(const half8*)&sBh[bc];
#pragma unroll
        for (int mi = 0; mi < TM; mi++) {
          if (ASPLIT)
            acc[mi][ni] = __builtin_amdgcn_mfma_f32_16x16x32_f16(aLf[mi], bH, acc[mi][ni], 0, 0, 0);
        }
        if (BSPLIT) {
          half8 bL = *(const half8*)&sBl[bc];
#pragma unroll
          for (int mi = 0; mi < TM; mi++)
            acc[mi][ni] = __builtin_amdgcn_mfma_f32_16x16x32_f16(aHf[mi], bL, acc[mi][ni], 0, 0, 0);
        }
#pragma unroll
        for (int mi = 0; mi < TM; mi++)
          acc[mi][ni] = __builtin_amdgcn_mfma_f32_16x16x32_f16(aHf[mi], bH, acc[mi][ni], 0, 0, 0);
      }
      __syncthreads();
    }
  }
  // ---- epilogue
#pragma unroll
  for (int mi = 0; mi < TM; mi++) {
    int rowg = m0 + wrb + mi * 16 + lkg * 4;
#pragma unroll
    for (int j = 0; j < 4; j++) {
      int r = rowg + j;
      if (r < M) {
#pragma unroll
        for (int ni = 0; ni < TN; ni++) {
          int cg = n0 + wcb + ni * 16 + lrow;
          float v = acc[mi][ni][j] * WINV;
          if (BIAS) v += bias[cg];
          if (GELU) v = gelu_f(v);
          if (SOUT == 2) {
            coH[(long)r * N + cg] = to_f16u(v);
          } else if (SOUT == 3) {
            if (cg < 1024) coH[(long)r * 1024 + cg] = to_f16u(v);
            else           vOut[(long)r * 512 + (cg - 1024)] = to_f16u(v);
          } else {
            long idx = (long)r * N + cg;
            if (RESID) C[idx] += v; else C[idx] = v;
          }
        }
      }
    }
  }
}

// ---------------- fused flash spatial attention over a chunk PAIR (32 frames).
// 1-D grid 1280: o -> fh = ((o&7)<<5)|((o>>3)&31), q-tile = o>>8.
// Same fh -> same XCD (o%8 invariant) so the 5 q-tile blocks share K/V in that XCD's L2.
// K[t+1]/V[t+1] are register-prefetched one tile ahead (issue-distance mechanism, r21).
__global__ __launch_bounds__(256) void flash_spatial(
    const ushort* __restrict__ qk, const ushort* __restrict__ v2,
    ushort* __restrict__ ctxc)
{
  __shared__ __align__(16) ushort sQ[64*72];
  __shared__ __align__(16) ushort sK[64*72];
  __shared__ __align__(16) ushort sV[64*72];               // V^T: [d][k]
  __shared__ __align__(16) ushort sP[64*72];
  const int tid = threadIdx.x;
  const int wid = tid >> 6, lane = tid & 63;
  const int lr = lane & 15, lg = lane >> 4;
  const int o = blockIdx.x;                   // 0..1279
  const int fh = ((o & 7) << 5) | ((o >> 3) & 31);   // frame*8+head, XCD-affine
  const int fl = fh >> 3, hh = fh & 7;
  const int q0 = (o >> 8) * 64;
  const long rbase = (long)fl * S_;
  const int srow = tid >> 2, sc0 = (tid & 3) << 4;

  {
    int gr = q0 + srow;
    uint4 h0 = make_uint4(0,0,0,0), h1 = h0;
    if (gr < S_) {
      const ushort* sh = qk + (rbase + gr) * 1024 + hh * HD_ + sc0;
      h0 = ((const uint4*)sh)[0]; h1 = ((const uint4*)sh)[1];
    }
    uint4* dh = (uint4*)&sQ[srow*72 + sc0];
    dh[0] = h0; dh[1] = h1;
  }
  // ---- prefetch K[0] into registers
  uint4 kh0[2], kh1[2];
  {
    kh0[0] = make_uint4(0,0,0,0); kh1[0] = kh0[0];
    if (srow < S_) {
      const ushort* sh = qk + (rbase + srow) * 1024 + 512 + hh * HD_ + sc0;
      kh0[0] = ((const uint4*)sh)[0]; kh1[0] = ((const uint4*)sh)[1];
    }
  }
  __syncthreads();
  half8 qH[2];
  {
    int qrl = wid * 16 + lr;
#pragma unroll
    for (int s = 0; s < 2; s++)
      qH[s] = *(const half8*)&sQ[qrl*72 + s*32 + lg*8];
  }
  f32x4 accS[5][4];
#pragma unroll
  for (int t = 0; t < 5; t++)
#pragma unroll
    for (int kc = 0; kc < 4; kc++) accS[t][kc] = (f32x4){0.f,0.f,0.f,0.f};

#pragma unroll
  for (int t = 0; t < 5; t++) {
    // issue K[t+1] loads (latency hidden under this tile's barriers + MFMA)
    if (t < 4) {
      int nb = (t + 1) & 1;
      int gr = (t + 1) * 64 + srow;
      kh0[nb] = make_uint4(0,0,0,0); kh1[nb] = kh0[nb];
      if (gr < S_) {
        const ushort* sh = qk + (rbase + gr) * 1024 + 512 + hh * HD_ + sc0;
        kh0[nb] = ((const uint4*)sh)[0]; kh1[nb] = ((const uint4*)sh)[1];
      }
    }
    __syncthreads();                         // sK free (prev MFMA done)
    {
      uint4* dh = (uint4*)&sK[srow*72 + sc0];
      dh[0] = kh0[t & 1]; dh[1] = kh1[t & 1];
    }
    __syncthreads();                         // sK ready
#pragma unroll
    for (int s = 0; s < 2; s++) {
#pragma unroll
      for (int kc = 0; kc < 4; kc++) {
        int off = (kc*16 + lr)*72 + s*32 + lg*8;
        half8 bH = *(const half8*)&sK[off];
        accS[t][kc] = __builtin_amdgcn_mfma_f32_16x16x32_f16(qH[s], bH, accS[t][kc], 0,0,0);
      }
    }
  }

  // ---- prefetch V[0] (latency hidden under softmax)
  uint4 vh0[2], vh1[2];
  {
    vh0[0] = make_uint4(0,0,0,0); vh1[0] = vh0[0];
    if (srow < S_) {
      const ushort* src = v2 + (rbase + srow) * 512 + hh * HD_ + sc0;
      vh0[0] = ((const uint4*)src)[0]; vh1[0] = ((const uint4*)src)[1];
    }
  }

  float m[4] = {-3.0e38f, -3.0e38f, -3.0e38f, -3.0e38f};
#pragma unroll
  for (int t = 0; t < 5; t++)
#pragma unroll
    for (int kc = 0; kc < 4; kc++) {
      int kcol = t*64 + kc*16 + lr;
      if (kcol < S_) {
#pragma unroll
        for (int j = 0; j < 4; j++) m[j] = fmaxf(m[j], accS[t][kc][j] * 0.125f);
      }
    }
#pragma unroll
  for (int mk = 8; mk >= 1; mk >>= 1)
#pragma unroll
    for (int j = 0; j < 4; j++) m[j] = fmaxf(m[j], __shfl_xor(m[j], mk));
  float l[4] = {0.f, 0.f, 0.f, 0.f};
#pragma unroll
  for (int t = 0; t < 5; t++)
#pragma unroll
    for (int kc = 0; kc < 4; kc++) {
      int kcol = t*64 + kc*16 + lr;
#pragma unroll
      for (int j = 0; j < 4; j++) {
        float p = (kcol < S_) ? expf(accS[t][kc][j]*0.125f - m[j]) : 0.f;
        accS[t][kc][j] = p;
        l[j] += p;
      }
    }
#pragma unroll
  for (int mk = 8; mk >= 1; mk >>= 1)
#pragma unroll
    for (int j = 0; j < 4; j++) l[j] += __shfl_xor(l[j], mk);

  f32x4 accO[4];
#pragma unroll
  for (int dc = 0; dc < 4; dc++) accO[dc] = (f32x4){0.f,0.f,0.f,0.f};
#pragma unroll
  for (int t = 0; t < 5; t++) {
    // issue V[t+1] loads
    if (t < 4) {
      int nb = (t + 1) & 1;
      int gr = (t + 1) * 64 + srow;
      vh0[nb] = make_uint4(0,0,0,0); vh1[nb] = vh0[nb];
      if (gr < S_) {
        const ushort* src = v2 + (rbase + gr) * 512 + hh * HD_ + sc0;
        vh0[nb] = ((const uint4*)src)[0]; vh1[nb] = ((const uint4*)src)[1];
      }
    }
    // P tile (wave-private rows; same-wave W->R ordered by lgkmcnt)
#pragma unroll
    for (int kc = 0; kc < 4; kc++)
#pragma unroll
      for (int j = 0; j < 4; j++) {
        int addr = (wid*16 + lg*4 + j)*72 + kc*16 + lr;
        sP[addr] = to_f16u(accS[t][kc][j]);
      }
    __syncthreads();                         // sV free (prev MFMA done)
    {
      ushort tmp[16];
      *(uint4*)&tmp[0] = vh0[t & 1]; *(uint4*)&tmp[8] = vh1[t & 1];
#pragma unroll
      for (int e = 0; e < 16; e++) sV[(sc0 + e)*72 + srow] = tmp[e];
    }
    __syncthreads();                         // sV ready
#pragma unroll
    for (int s = 0; s < 2; s++) {
      int poff = (wid*16 + lr)*72 + s*32 + lg*8;
      half8 pH = *(const half8*)&sP[poff];
#pragma unroll
      for (int dc = 0; dc < 4; dc++) {
        int voff = (dc*16 + lr)*72 + s*32 + lg*8;
        half8 vH = *(const half8*)&sV[voff];
        accO[dc] = __builtin_amdgcn_mfma_f32_16x16x32_f16(pH, vH, accO[dc], 0,0,0);
      }
    }
  }
#pragma unroll
  for (int j = 0; j < 4; j++) {
    int grow = q0 + wid*16 + lg*4 + j;
    if (grow < S_) {
      float inv = 1.0f / l[j];
#pragma unroll
      for (int dc = 0; dc < 4; dc++) {
        float o2 = accO[dc][j] * inv;
        long idx = (rbase + grow) * 512 + hh*64 + dc*16 + lr;
        ctxc[idx] = to_f16u(o2);
      }
    }
  }
}

// ---------------- temporal causal attention over a chunk pair (2 batches), single-f16 qkv
__global__ __launch_bounds__(64) void temporal_attn(
    const ushort* __restrict__ qk, const ushort* __restrict__ v2,
    ushort* __restrict__ ctxc)
{
  const int gid = blockIdx.x;           // b2*2056 + s*8+h
  const int b2 = gid / (S_ * NH_);
  const int rem = gid - b2 * S_ * NH_;
  const int hh = rem & 7;
  const int s = rem >> 3;
  const int lane = threadIdx.x;
  __shared__ float Qs[16][65];
  __shared__ float Ks[16][65];
  __shared__ float Pm[16][17];
  float v[16];
  const long rbase = (long)b2 * CH + s;
#pragma unroll
  for (int t = 0; t < 16; t++) {
    long row = rbase + (long)t * S_;
    long qoff = row * 1024 + hh * HD_ + lane;
    Qs[t][lane] = from_f16u(qk[qoff]);
    Ks[t][lane] = from_f16u(qk[qoff + 512]);
    v[t] = from_f16u(v2[row * 512 + hh * HD_ + lane]);
  }
  __syncthreads();
  const int rq = lane >> 2, c0 = lane & 3;
  float sc[4];
#pragma unroll
  for (int j = 0; j < 4; j++) {
    int c = c0 + (j << 2);
    if (c <= rq) {
      float d = 0.f;
#pragma unroll
      for (int k = 0; k < 64; k++) d = fmaf(Qs[rq][k], Ks[c][k], d);
      sc[j] = d * 0.125f;
    } else sc[j] = -3.0e38f;
  }
  float mx = fmaxf(fmaxf(sc[0], sc[1]), fmaxf(sc[2], sc[3]));
  mx = fmaxf(mx, __shfl_xor(mx, 1));
  mx = fmaxf(mx, __shfl_xor(mx, 2));
  float sum = 0.f;
#pragma unroll
  for (int j = 0; j < 4; j++) { sc[j] = expf(sc[j] - mx); sum += sc[j]; }
  sum += __shfl_xor(sum, 1);
  sum += __shfl_xor(sum, 2);
  float inv = 1.0f / sum;
#pragma unroll
  for (int j = 0; j < 4; j++) Pm[rq][c0 + (j << 2)] = sc[j] * inv;
  __syncthreads();
#pragma unroll
  for (int t = 0; t < 16; t++) {
    float o = 0.f;
#pragma unroll
    for (int k = 0; k < 16; k++) o = fmaf(Pm[t][k], v[k], o);
    long idx = (rbase + (long)t * S_) * 512 + hh * HD_ + lane;
    ctxc[idx] = to_f16u(o);
  }
}

// ---------------- final LN + projection + VQ argmin + action head (1024 threads)
__global__ __launch_bounds__(1024) void final_vq(
    const float* __restrict__ tok, const float* __restrict__ lnf_g,
    const float* __restrict__ lnf_b, const float* __restrict__ out_w,
    const float* __restrict__ codebook, const float* __restrict__ action_w,
    float* __restrict__ out)
{
  __shared__ float xs[512];
  __shared__ float red[16];
  __shared__ float zp[1024];
  __shared__ float zs[64];
  __shared__ float bd[16];
  __shared__ int   bi[16];
  __shared__ int   bsel;
  const int b = blockIdx.x / 15, tm = blockIdx.x % 15;
  const int tid = threadIdx.x;
  const int wv = tid >> 6, lane = tid & 63;
  const float* xr = tok + ((long)(b * T_ + tm + 1) * S_) * D_;   // s = 0
  float x0 = (tid < 512) ? xr[tid] : 0.f;
  float s = warp_rsum(x0);
  if (lane == 0) red[wv] = s;
  __syncthreads();
  float tot = 0.f;
#pragma unroll
  for (int w = 0; w < 16; w++) tot += red[w];
  float mean = tot * (1.0f / 512.0f);
  float dv = (tid < 512) ? (x0 - mean) : 0.f;
  __syncthreads();
  float ss = warp_rsum(dv * dv);
  if (lane == 0) red[wv] = ss;
  __syncthreads();
  float vtot = 0.f;
#pragma unroll
  for (int w = 0; w < 16; w++) vtot += red[w];
  float rstd = rsqrtf(vtot * (1.0f / 512.0f) + 1e-5f);
  if (tid < 512) xs[tid] = dv * rstd * lnf_g[tid] + lnf_b[tid];
  __syncthreads();
  // z projection: output o = tid&63, partial p = tid>>6 over d in [p*32, p*32+32)
  {
    int o = tid & 63, p = tid >> 6;
    int d0 = p * 32;
    float z = 0.f;
#pragma unroll 8
    for (int k = 0; k < 32; k++) z = fmaf(xs[d0 + k], out_w[(long)(d0 + k) * 64 + o], z);
    zp[tid] = z;
  }
  __syncthreads();
  if (tid < 64) {
    float z = 0.f;
#pragma unroll
    for (int p = 0; p < 16; p++) z += zp[p * 64 + tid];
    zs[tid] = z;
  }
  __syncthreads();
  // codebook scan: 4 codes/thread, float4 loads, scalar-identical accumulation order
  float best = 3.0e38f; int bidx = 0;
  for (int c = tid; c < 4096; c += 1024) {
    const float4* cp = (const float4*)(codebook + (long)c * 64);
    float dot = 0.f, cn = 0.f;
#pragma unroll
    for (int k = 0; k < 16; k++) {
      float4 w = cp[k];
      dot = fmaf(zs[4*k + 0], w.x, dot); cn = fmaf(w.x, w.x, cn);
      dot = fmaf(zs[4*k + 1], w.y, dot); cn = fmaf(w.y, w.y, cn);
      dot = fmaf(zs[4*k + 2], w.z, dot); cn = fmaf(w.z, w.z, cn);
      dot = fmaf(zs[4*k + 3], w.w, dot); cn = fmaf(w.w, w.w, cn);
    }
    float dist = cn - 2.0f * dot;
    if (dist < best) { best = dist; bidx = c; }
  }
  // wave argmin (ties -> smaller index, matching argmin semantics)
#pragma unroll
  for (int mk = 32; mk >= 1; mk >>= 1) {
    float ob = __shfl_xor(best, mk);
    int   oi = __shfl_xor(bidx, mk);
    if (ob < best || (ob == best && oi < bidx)) { best = ob; bidx = oi; }
  }
  if (lane == 0) { bd[wv] = best; bi[wv] = bidx; }
  __syncthreads();
  if (tid == 0) {
    float bb = bd[0]; int ii = bi[0];
#pragma unroll
    for (int w = 1; w < 16; w++)
      if (bd[w] < bb || (bd[w] == bb && bi[w] < ii)) { bb = bd[w]; ii = bi[w]; }
    bsel = ii;
  }
  __syncthreads();
  int idx = bsel;
  if (tid < 16) {
    const float* cp = codebook + (long)idx * 64;
    float o = 0.f;
#pragma unroll
    for (int k = 0; k < 64; k++) o = fmaf(cp[k], action_w[k * 16 + tid], o);
    out[((long)(b * 15 + tm)) * 16 + tid] = o;
  }
}

extern "C" void kernel_launch(void* const* d_in, const int* in_sizes, int n_in,
                              void* d_out, int out_size, void* d_ws, size_t ws_size,
                              hipStream_t stream)
{
  const float* videos       = (const float*)d_in[0];
  const float* patch_w      = (const float*)d_in[1];
  const float* patch_b      = (const float*)d_in[2];
  const float* action_token = (const float*)d_in[3];
  const float* ln1_g  = (const float*)d_in[4];
  const float* ln1_b  = (const float*)d_in[5];
  const float* wqkv_s = (const float*)d_in[6];
  const float* wo_s   = (const float*)d_in[7];
  const float* ln2_g  = (const float*)d_in[8];
  const float* ln2_b  = (const float*)d_in[9];
  const float* wqkv_t = (const float*)d_in[10];
  const float* wo_t   = (const float*)d_in[11];
  const float* ln3_g  = (const float*)d_in[12];
  const float* ln3_b  = (const float*)d_in[13];
  const float* mlp_w1 = (const float*)d_in[14];
  const float* mlp_b1 = (const float*)d_in[15];
  const float* mlp_w2 = (const float*)d_in[16];
  const float* mlp_b2 = (const float*)d_in[17];
  const float* lnf_g  = (const float*)d_in[18];
  const float* lnf_b  = (const float*)d_in[19];
  const float* out_w  = (const float*)d_in[20];
  const float* codebook = (const float*)d_in[21];
  const float* action_w = (const float*)d_in[22];
  float* out = (float*)d_out;

  // ---- workspace layout (floats), total 29,466,624 f = 117.9 MB (< proven 135)
  float* ws    = (float*)d_ws;
  float* tok   = ws;                                  // 16,842,752
  ushort* wt1h = (ushort*)(ws + 16842752);            // 1,048,576 f-eq (hi+lo)
  ushort* wt1l = wt1h + 1048576;
  ushort* wt2h = (ushort*)(ws + 17891328);            // 1,048,576 f-eq
  ushort* wt2l = wt2h + 1048576;
  ushort* aH   = (ushort*)(ws + 18939904);            // PCH x 512 single f16 = 2,105,344 f-eq
  ushort* qk   = (ushort*)(ws + 21045248);            // PCH x 1024 single = 4,210,688 f-eq
  ushort* v2   = (ushort*)(ws + 25255936);            // PCH x 512 single  = 2,105,344 f-eq
  ushort* ctx  = (ushort*)(ws + 27361280);            // PCH x 512 single  = 2,105,344 f-eq
  ushort* mid  = qk;                                  // MLP mid (PCH x 2048) spans qk+v2+ctx

  // ---- patchify fused into embed GEMM (full 3-MFMA, legacy path)
  convert_w<<<dim3(3, 8), 256, 0, stream>>>(patch_w, wt1h, wt1l, 512, 192);
  gemm_mfma<128,128,4,4,1,true,true,true,false,false,0><<<dim3(257, 4), 256, 0, stream>>>(
      nullptr, nullptr, 0, wt1h, wt1l, 192, patch_b, tok, nullptr, nullptr,
      videos, action_token, NTOK, 512, 192);

  for (int L = 0; L < 4; L++) {
    // ================= spatial attention (4 chunk pairs) =================
    convert_w<<<dim3(8, 24), 256, 0, stream>>>(wqkv_s + (long)L*512*1536, wt1h, wt1l, 1536, 512);
    convert_w<<<dim3(8, 8),  256, 0, stream>>>(wo_s   + (long)L*512*512,  wt2h, wt2l, 512, 512);
    for (int pr = 0; pr < 4; pr++) {
      long r0 = (long)pr * PCH;
      ln_single<<<PCH / 4, 256, 0, stream>>>(tok + r0 * D_, ln1_g + L*512, ln1_b + L*512, aH);
      gemm_mfma<64,128,2,4,0,false,false,false,false,false,3><<<dim3(129, 12), 256, 0, stream>>>(
          aH, nullptr, 512, wt1h, wt1l, 512, nullptr, nullptr,
          qk, v2, nullptr, nullptr, PCH, 1536, 512);
      flash_spatial<<<dim3(1280), 256, 0, stream>>>(qk, v2, ctx);
      gemm_mfma<64,64,1,4,0,false,false,false,false,true,0><<<dim3(129, 8), 256, 0, stream>>>(
          ctx, nullptr, 512, wt2h, wt2l, 512, nullptr, tok + r0 * D_,
          nullptr, nullptr, nullptr, nullptr, PCH, 512, 512);
    }
    // ================= temporal attention (4 chunk pairs) =================
    convert_w<<<dim3(8, 24), 256, 0, stream>>>(wqkv_t + (long)L*512*1536, wt1h, wt1l, 1536, 512);
    convert_w<<<dim3(8, 8),  256, 0, stream>>>(wo_t   + (long)L*512*512,  wt2h, wt2l, 512, 512);
    for (int pr = 0; pr < 4; pr++) {
      long r0 = (long)pr * PCH;
      ln_single<<<PCH / 4, 256, 0, stream>>>(tok + r0 * D_, ln2_g + L*512, ln2_b + L*512, aH);
      gemm_mfma<64,128,2,4,0,false,false,false,false,false,3><<<dim3(129, 12), 256, 0, stream>>>(
          aH, nullptr, 512, wt1h, wt1l, 512, nullptr, nullptr,
          qk, v2, nullptr, nullptr, PCH, 1536, 512);
      temporal_attn<<<2 * S_ * NH_, 64, 0, stream>>>(qk, v2, ctx);
      gemm_mfma<64,64,1,4,0,false,false,false,false,true,0><<<dim3(129, 8), 256, 0, stream>>>(
          ctx, nullptr, 512, wt2h, wt2l, 512, nullptr, tok + r0 * D_,
          nullptr, nullptr, nullptr, nullptr, PCH, 512, 512);
    }
    // ================= MLP (4 M-chunks of 8224 rows) =================
    convert_w<<<dim3(8, 32), 256, 0, stream>>>(mlp_w1 + (long)L*512*2048, wt1h, wt1l, 2048, 512);
    convert_w<<<dim3(32, 8), 256, 0, stream>>>(mlp_w2 + (long)L*2048*512, wt2h, wt2l, 512, 2048);
    for (int c = 0; c < 4; c++) {
      long m0r = (long)c * PCH;
      ln_single<<<PCH / 4, 256, 0, stream>>>(tok + m0r * D_, ln3_g + L*512, ln3_b + L*512, aH);
      gemm_mfma<64,128,2,4,0,false,false,true,true,false,2><<<dim3(129, 16), 256, 0, stream>>>(
          aH, nullptr, 512, wt1h, wt1l, 512, mlp_b1 + (long)L*2048, nullptr, mid, nullptr,
          nullptr, nullptr, PCH, FFN_, 512);
      gemm_mfma<64,64,1,4,0,false,false,true,false,true,0><<<dim3(129, 8), 256, 0, stream>>>(
          mid, nullptr, 2048, wt2h, wt2l, 2048, mlp_b2 + (long)L*512, tok + m0r * D_,
          nullptr, nullptr, nullptr, nullptr, PCH, 512, 2048);
    }
  }

  final_vq<<<B_ * (T_ - 1), 1024, 0, stream>>>(tok, lnf_g, lnf_b, out_w, codebook, action_w, out);
}